// Round 4
// baseline (6976.086 us; speedup 1.0000x reference)
//
#include <hip/hip_runtime.h>

#define NN 50000
#define NE 1600000
#define NGR 64
#define XD 32
#define HID 128
#define NF 128
#define NG 50
#define GD 16
#define NL 6
#define SH 64
#define EPSF 1e-5f

typedef __bf16 bf16_t;
typedef bf16_t bf16x8 __attribute__((ext_vector_type(8)));
typedef float f32x4 __attribute__((ext_vector_type(4)));

// ================= CSR build (once; col constant across layers) ============
__global__ __launch_bounds__(256) void k_hist(const int* __restrict__ col,
                                              int* __restrict__ hist) {
  for (int e = blockIdx.x * 256 + threadIdx.x; e < NE; e += gridDim.x * 256)
    atomicAdd(&hist[col[e]], 1);
}

__global__ __launch_bounds__(1024) void k_scan(int* __restrict__ hist,
                                               int* __restrict__ rowptr) {
  const int tid = threadIdx.x;
  const int CH = 49;
  const int base = tid * CH;
  int s = 0;
  for (int i = 0; i < CH; ++i) {
    int idx = base + i;
    if (idx < NN) s += hist[idx];
  }
  __shared__ int part[1024];
  part[tid] = s;
  __syncthreads();
  for (int off = 1; off < 1024; off <<= 1) {
    int v = (tid >= off) ? part[tid - off] : 0;
    __syncthreads();
    part[tid] += v;
    __syncthreads();
  }
  int run = part[tid] - s;
  for (int i = 0; i < CH; ++i) {
    int idx = base + i;
    if (idx < NN) {
      int c = hist[idx];
      rowptr[idx] = run;
      hist[idx] = run;
      run += c;
    }
  }
  if (tid == 0) rowptr[NN] = NE;
}

__global__ __launch_bounds__(256) void k_scatter(const int* __restrict__ col,
                                                 int* __restrict__ cursor,
                                                 int* __restrict__ perm) {
  for (int e = blockIdx.x * 256 + threadIdx.x; e < NE; e += gridDim.x * 256) {
    int pos = atomicAdd(&cursor[col[e]], 1);
    perm[pos] = e;
  }
}

// ================= permuted per-edge data ==================================
__global__ __launch_bounds__(256) void k_preedge(const int* __restrict__ perm,
    const float* __restrict__ eattr, const int* __restrict__ row,
    const int* __restrict__ col, float* __restrict__ dperm,
    int* __restrict__ rowperm, int* __restrict__ destperm) {
  int p = blockIdx.x * 256 + threadIdx.x;
  if (p < NE) {
    int pe = perm[p];
    float ax = eattr[(size_t)pe * 3], ay = eattr[(size_t)pe * 3 + 1], az = eattr[(size_t)pe * 3 + 2];
    dperm[p] = sqrtf(ax * ax + ay * ay + az * az);
    rowperm[p] = row[pe];
    destperm[p] = col[pe];
  }
}

// ================= weight prep: transpose, K-pad, split hi/lo ==============
__global__ __launch_bounds__(256) void k_prepw(const float* __restrict__ Wf1,
    const float* __restrict__ Wf2, const float* __restrict__ Wd1,
    const float* __restrict__ Wd2,
    bf16_t* __restrict__ W1Thi, bf16_t* __restrict__ W1Tlo,
    bf16_t* __restrict__ W2Thi, bf16_t* __restrict__ W2Tlo,
    bf16_t* __restrict__ Wd1Thi, bf16_t* __restrict__ Wd1Tlo,
    bf16_t* __restrict__ Wd2Thi, bf16_t* __restrict__ Wd2Tlo) {
  const int S0 = NL * 128 * 64;
  const int S1 = NL * 128 * 128;
  int idx = blockIdx.x * 256 + threadIdx.x;
  if (idx < S0) {
    int l = idx / (128 * 64);
    int r = idx - l * (128 * 64);
    int c = r >> 6, k = r & 63;
    float v = (k < NG) ? Wf1[(size_t)l * NG * NF + (size_t)k * NF + c] : 0.f;
    bf16_t hv = (bf16_t)v;
    W1Thi[idx] = hv;
    W1Tlo[idx] = (bf16_t)(v - (float)hv);
  } else if (idx < S0 + 3 * S1) {
    int j = idx - S0;
    int which = j / S1;       // 0: Wf2, 1: Wd1, 2: Wd2
    int jj = j - which * S1;
    int l = jj / (128 * 128);
    int r = jj - l * (128 * 128);
    int c = r >> 7, k = r & 127;
    const float* W = (which == 0) ? Wf2 : (which == 1) ? Wd1 : Wd2;
    float v = W[(size_t)l * 128 * 128 + (size_t)k * 128 + c];
    bf16_t hv = (bf16_t)v;
    bf16_t lv = (bf16_t)(v - (float)hv);
    if (which == 0)      { W2Thi[jj] = hv;  W2Tlo[jj] = lv; }
    else if (which == 1) { Wd1Thi[jj] = hv; Wd1Tlo[jj] = lv; }
    else                 { Wd2Thi[jj] = hv; Wd2Tlo[jj] = lv; }
  }
}

// ================= node encoder ============================================
__global__ __launch_bounds__(256) void k_enc1(const float* __restrict__ x,
    const float* __restrict__ We1, const float* __restrict__ be1,
    float* __restrict__ t, float* __restrict__ stats) {
  int c = threadIdx.x & 127;
  int half = threadIdx.x >> 7;
  float b = be1[c];
  float psum = 0.f, psq = 0.f;
  for (int n = blockIdx.x * 2 + half; n < NN; n += gridDim.x * 2) {
    const float* xr = x + (size_t)n * XD;
    float v = b;
#pragma unroll
    for (int k = 0; k < XD; ++k) v = fmaf(xr[k], We1[k * HID + c], v);
    t[(size_t)n * HID + c] = v;
    psum += v; psq += v * v;
  }
  __shared__ float s0[256], s1[256];
  s0[threadIdx.x] = psum; s1[threadIdx.x] = psq;
  __syncthreads();
  if (threadIdx.x < 128) {
    atomicAdd(&stats[threadIdx.x], s0[threadIdx.x] + s0[threadIdx.x + 128]);
    atomicAdd(&stats[128 + threadIdx.x], s1[threadIdx.x] + s1[threadIdx.x + 128]);
  }
}

__global__ __launch_bounds__(128) void k_bn_fin(const float* __restrict__ gamma,
    const float* __restrict__ beta, float* __restrict__ stats, int C, float invn) {
  int c = threadIdx.x;
  if (c < C) {
    float mean = stats[c] * invn;
    float var = stats[128 + c] * invn - mean * mean;
    float a = gamma[c] * rsqrtf(var + EPSF);
    stats[256 + c] = a;
    stats[384 + c] = beta[c] - mean * a;
  }
}

__global__ __launch_bounds__(128) void k_enc2(const float* __restrict__ t,
    const float* __restrict__ stats, const float* __restrict__ We2,
    const float* __restrict__ be2, float* __restrict__ h) {
  __shared__ float r[HID];
  int c = threadIdx.x;
  float a = stats[256 + c], b = stats[384 + c];
  float bias = be2[c];
  for (int n = blockIdx.x; n < NN; n += gridDim.x) {
    float v = fmaf(t[(size_t)n * HID + c], a, b);
    r[c] = fmaxf(v, 0.f);
    __syncthreads();
    float acc = bias;
#pragma unroll 8
    for (int k = 0; k < HID; ++k) acc = fmaf(r[k], We2[k * HID + c], acc);
    h[(size_t)n * HID + c] = acc;
    __syncthreads();
  }
}

// ================= gaussian smearing (ea output) ===========================
__global__ __launch_bounds__(256) void k_smear(const float* __restrict__ eattr,
    float* __restrict__ ea) {
  int idx = blockIdx.x * 256 + threadIdx.x;
  if (idx >= NE * NG) return;
  int e = idx / NG;
  int g = idx - e * NG;
  float ax = eattr[(size_t)e * 3], ay = eattr[(size_t)e * 3 + 1], az = eattr[(size_t)e * 3 + 2];
  float d = sqrtf(ax * ax + ay * ay + az * az);
  float off = (10.0f / 49.0f) * (float)g;
  float z = d - off;
  ea[idx] = __expf(-12.005f * z * z);
}

// ================= MFMA edge kernel v4 =====================================
// Block = 4 waves = 16 dest nodes. Per 16-edge tile: meta in regs (shfl
// broadcast), h gather issued at tile start, gaussians computed coop once
// per block into LDS A-frag tile, GEMM1 (8 MFMA, A-hi only), f1 split,
// GEMM2 (24 MFMA, 3-term), single-dst shfl-reduce epilogue.
__global__ __launch_bounds__(256) void k_edge4(
    const float* __restrict__ dperm, const int* __restrict__ rowperm,
    const int* __restrict__ destperm, const int* __restrict__ rowptr,
    const float* __restrict__ h,
    const bf16_t* __restrict__ W1Thi, const bf16_t* __restrict__ W1Tlo,
    const bf16_t* __restrict__ W2Thi, const bf16_t* __restrict__ W2Tlo,
    const float* __restrict__ bf1, const float* __restrict__ bf2,
    float* __restrict__ agg) {
  __shared__ float agg_s[16][HID];
  __shared__ __align__(16) bf16_t A_s[2][64][8];
  __shared__ __align__(16) bf16_t f1hi_s[16][136];
  __shared__ __align__(16) bf16_t f1lo_s[16][136];

  const int tid = threadIdx.x;
  const int lane = tid & 63;
  const int w = tid >> 6;
  const int lm = lane & 15;
  const int lk = lane >> 4;
  const int colbase = w * 32;
  const int nb = blockIdx.x * 16;
  const int eS = rowptr[nb], eE = rowptr[nb + 16];

  for (int i = tid; i < 16 * HID; i += 256) ((float*)agg_s)[i] = 0.f;

  // B fragments (registers, once)
  bf16x8 B1[2][2][2];
#pragma unroll
  for (int cf = 0; cf < 2; ++cf)
#pragma unroll
    for (int s = 0; s < 2; ++s) {
      int c = colbase + cf * 16 + lm;
      int k0 = s * 32 + lk * 8;
      B1[cf][s][0] = *(const bf16x8*)(W1Thi + (size_t)c * 64 + k0);
      B1[cf][s][1] = *(const bf16x8*)(W1Tlo + (size_t)c * 64 + k0);
    }
  bf16x8 B2[2][4][2];
#pragma unroll
  for (int cf = 0; cf < 2; ++cf)
#pragma unroll
    for (int s = 0; s < 4; ++s) {
      int c = colbase + cf * 16 + lm;
      int k0 = s * 32 + lk * 8;
      B2[cf][s][0] = *(const bf16x8*)(W2Thi + (size_t)c * 128 + k0);
      B2[cf][s][1] = *(const bf16x8*)(W2Tlo + (size_t)c * 128 + k0);
    }
  float bias1[2], bias2[2];
#pragma unroll
  for (int cf = 0; cf < 2; ++cf) {
    bias1[cf] = bf1[colbase + cf * 16 + lm];
    bias2[cf] = bf2[colbase + cf * 16 + lm];
  }

  // coop A_s mapping for this thread
  const int cs = tid >> 7;             // k-step 0/1
  const int cl = (tid >> 1) & 63;      // target lane slot
  const int ci0 = (tid & 1) * 4;       // elem 0..3 or 4..7
  const int cedge = cl & 15;
  const int ckg = cl >> 4;

  for (int et = eS; et < eE; et += 16) {
    const int nval = min(16, eE - et);
    // ---- meta loads into regs (lanes 0..15 of every wave, redundant) ----
    float dreg = 0.f; int rowreg = 0, dstreg = 0;
    if (lane < nval) {
      int p = et + lane;
      dreg = dperm[p];
      rowreg = rowperm[p];
      dstreg = destperm[p];
    }
    // ---- h gather issued now (in flight across exp + GEMM1 + barriers) ----
    float hv[2][4];
#pragma unroll
    for (int j = 0; j < 4; ++j) {
      int e = lk * 4 + j;
      int r = __shfl(rowreg, e);
#pragma unroll
      for (int cf = 0; cf < 2; ++cf) {
        int c = colbase + cf * 16 + lm;
        hv[cf][j] = (e < nval) ? h[(size_t)r * HID + c] : 0.f;
      }
    }
    __syncthreads();  // s0: prev tile's A_s/f1 readers done
    // ---- coop gaussian A-frag tile (1024 values / block) ----
    {
      float dv = __shfl(dreg, cedge);
      bool ev = cedge < nval;
#pragma unroll
      for (int ii = 0; ii < 4; ++ii) {
        int g = cs * 32 + ckg * 8 + ci0 + ii;
        float v = 0.f;
        if (ev && g < NG) {
          float z = dv - 0.2040816327f * (float)g;
          v = __expf(-12.005f * z * z);
        }
        A_s[cs][cl][ci0 + ii] = (bf16_t)v;
      }
    }
    __syncthreads();  // s1: A_s ready
    // ---- GEMM1 (A-hi only, B split-2): 8 MFMA ----
    f32x4 acc1[2];
    acc1[0] = (f32x4){0.f, 0.f, 0.f, 0.f};
    acc1[1] = (f32x4){0.f, 0.f, 0.f, 0.f};
#pragma unroll
    for (int s = 0; s < 2; ++s) {
      bf16x8 A1 = *(const bf16x8*)&A_s[s][lane][0];
#pragma unroll
      for (int cf = 0; cf < 2; ++cf) {
        acc1[cf] = __builtin_amdgcn_mfma_f32_16x16x32_bf16(A1, B1[cf][s][0], acc1[cf], 0, 0, 0);
        acc1[cf] = __builtin_amdgcn_mfma_f32_16x16x32_bf16(A1, B1[cf][s][1], acc1[cf], 0, 0, 0);
      }
    }
    // ---- relu + split -> f1 LDS ----
#pragma unroll
    for (int cf = 0; cf < 2; ++cf)
#pragma unroll
      for (int j = 0; j < 4; ++j) {
        int r = lk * 4 + j;
        int c = colbase + cf * 16 + lm;
        float v = fmaxf(acc1[cf][j] + bias1[cf], 0.f);
        bf16_t hvv = (bf16_t)v;
        f1hi_s[r][c] = hvv;
        f1lo_s[r][c] = (bf16_t)(v - (float)hvv);
      }
    __syncthreads();  // s2: f1 ready
    // ---- GEMM2 (3-term): 24 MFMA ----
    f32x4 acc2[2];
    acc2[0] = (f32x4){0.f, 0.f, 0.f, 0.f};
    acc2[1] = (f32x4){0.f, 0.f, 0.f, 0.f};
#pragma unroll
    for (int s = 0; s < 4; ++s) {
      bf16x8 Ahi = *(const bf16x8*)&f1hi_s[lm][s * 32 + lk * 8];
      bf16x8 Alo = *(const bf16x8*)&f1lo_s[lm][s * 32 + lk * 8];
#pragma unroll
      for (int cf = 0; cf < 2; ++cf) {
        acc2[cf] = __builtin_amdgcn_mfma_f32_16x16x32_bf16(Ahi, B2[cf][s][0], acc2[cf], 0, 0, 0);
        acc2[cf] = __builtin_amdgcn_mfma_f32_16x16x32_bf16(Ahi, B2[cf][s][1], acc2[cf], 0, 0, 0);
        acc2[cf] = __builtin_amdgcn_mfma_f32_16x16x32_bf16(Alo, B2[cf][s][0], acc2[cf], 0, 0, 0);
      }
    }
    // ---- epilogue: msg = W*h, accumulate into agg_s ----
    int dfirst = __shfl(dstreg, 0) - nb;
    int dlast = __shfl(dstreg, nval - 1) - nb;
    if (dfirst == dlast) {
      // whole tile -> one dest: cross-lane reduce, plain LDS add
#pragma unroll
      for (int cf = 0; cf < 2; ++cf) {
        float v = 0.f;
#pragma unroll
        for (int j = 0; j < 4; ++j) v += (acc2[cf][j] + bias2[cf]) * hv[cf][j];
        v += __shfl_xor(v, 16);
        v += __shfl_xor(v, 32);
        if (lk == 0) agg_s[dfirst][colbase + cf * 16 + lm] += v;
      }
    } else {
      int de[4];
#pragma unroll
      for (int j = 0; j < 4; ++j) de[j] = __shfl(dstreg, lk * 4 + j) - nb;
#pragma unroll
      for (int cf = 0; cf < 2; ++cf) {
        int c = colbase + cf * 16 + lm;
        float racc = 0.f;
        int cur = -1;
#pragma unroll
        for (int j = 0; j < 4; ++j) {
          int e = lk * 4 + j;
          if (e < nval) {
            float msg = (acc2[cf][j] + bias2[cf]) * hv[cf][j];
            if (de[j] != cur) {
              if (cur >= 0) atomicAdd(&agg_s[cur][c], racc);
              racc = 0.f;
              cur = de[j];
            }
            racc += msg;
          }
        }
        if (cur >= 0) atomicAdd(&agg_s[cur][c], racc);
      }
    }
  }
  __syncthreads();
  for (int i = tid; i < 16 * 32; i += 256) {
    int le = i >> 5, cj = (i & 31) * 4;
    *(float4*)(agg + (size_t)(nb + le) * HID + cj) = *(const float4*)&agg_s[le][cj];
  }
}

// ================= MFMA node update ========================================
// Block = 16 nodes, 4 waves x 32 cols. h += relu(agg@Wd1+bd1)@Wd2+bd2
__global__ __launch_bounds__(256) void k_node2(
    const float* __restrict__ agg,
    const bf16_t* __restrict__ Wd1Thi, const bf16_t* __restrict__ Wd1Tlo,
    const bf16_t* __restrict__ Wd2Thi, const bf16_t* __restrict__ Wd2Tlo,
    const float* __restrict__ bd1, const float* __restrict__ bd2,
    float* __restrict__ h) {
  __shared__ __align__(16) bf16_t aghi[16][136];
  __shared__ __align__(16) bf16_t aglo[16][136];
  __shared__ __align__(16) bf16_t t1hi[16][136];
  __shared__ __align__(16) bf16_t t1lo[16][136];

  const int tid = threadIdx.x;
  const int lane = tid & 63;
  const int w = tid >> 6;
  const int lm = lane & 15;
  const int lk = lane >> 4;
  const int colbase = w * 32;
  const int nb = blockIdx.x * 16;

  bf16x8 B1[2][4][2], B2[2][4][2];
#pragma unroll
  for (int cf = 0; cf < 2; ++cf)
#pragma unroll
    for (int s = 0; s < 4; ++s) {
      int c = colbase + cf * 16 + lm;
      int k0 = s * 32 + lk * 8;
      B1[cf][s][0] = *(const bf16x8*)(Wd1Thi + (size_t)c * 128 + k0);
      B1[cf][s][1] = *(const bf16x8*)(Wd1Tlo + (size_t)c * 128 + k0);
      B2[cf][s][0] = *(const bf16x8*)(Wd2Thi + (size_t)c * 128 + k0);
      B2[cf][s][1] = *(const bf16x8*)(Wd2Tlo + (size_t)c * 128 + k0);
    }
  float bias1[2], bias2[2];
#pragma unroll
  for (int cf = 0; cf < 2; ++cf) {
    bias1[cf] = bd1[colbase + cf * 16 + lm];
    bias2[cf] = bd2[colbase + cf * 16 + lm];
  }

  // load + split agg tile
  for (int idx = tid; idx < 16 * 128; idx += 256) {
    int r = idx >> 7, k = idx & 127;
    float v = agg[(size_t)(nb + r) * HID + k];
    bf16_t hv = (bf16_t)v;
    aghi[r][k] = hv;
    aglo[r][k] = (bf16_t)(v - (float)hv);
  }
  __syncthreads();

  // GEMM1: 24 MFMA
  f32x4 acc1[2];
  acc1[0] = (f32x4){0.f, 0.f, 0.f, 0.f};
  acc1[1] = (f32x4){0.f, 0.f, 0.f, 0.f};
#pragma unroll
  for (int s = 0; s < 4; ++s) {
    bf16x8 Ahi = *(const bf16x8*)&aghi[lm][s * 32 + lk * 8];
    bf16x8 Alo = *(const bf16x8*)&aglo[lm][s * 32 + lk * 8];
#pragma unroll
    for (int cf = 0; cf < 2; ++cf) {
      acc1[cf] = __builtin_amdgcn_mfma_f32_16x16x32_bf16(Ahi, B1[cf][s][0], acc1[cf], 0, 0, 0);
      acc1[cf] = __builtin_amdgcn_mfma_f32_16x16x32_bf16(Ahi, B1[cf][s][1], acc1[cf], 0, 0, 0);
      acc1[cf] = __builtin_amdgcn_mfma_f32_16x16x32_bf16(Alo, B1[cf][s][0], acc1[cf], 0, 0, 0);
    }
  }
#pragma unroll
  for (int cf = 0; cf < 2; ++cf)
#pragma unroll
    for (int j = 0; j < 4; ++j) {
      int r = lk * 4 + j;
      int c = colbase + cf * 16 + lm;
      float v = fmaxf(acc1[cf][j] + bias1[cf], 0.f);
      bf16_t hv = (bf16_t)v;
      t1hi[r][c] = hv;
      t1lo[r][c] = (bf16_t)(v - (float)hv);
    }
  __syncthreads();

  // GEMM2: 24 MFMA
  f32x4 acc2[2];
  acc2[0] = (f32x4){0.f, 0.f, 0.f, 0.f};
  acc2[1] = (f32x4){0.f, 0.f, 0.f, 0.f};
#pragma unroll
  for (int s = 0; s < 4; ++s) {
    bf16x8 Ahi = *(const bf16x8*)&t1hi[lm][s * 32 + lk * 8];
    bf16x8 Alo = *(const bf16x8*)&t1lo[lm][s * 32 + lk * 8];
#pragma unroll
    for (int cf = 0; cf < 2; ++cf) {
      acc2[cf] = __builtin_amdgcn_mfma_f32_16x16x32_bf16(Ahi, B2[cf][s][0], acc2[cf], 0, 0, 0);
      acc2[cf] = __builtin_amdgcn_mfma_f32_16x16x32_bf16(Ahi, B2[cf][s][1], acc2[cf], 0, 0, 0);
      acc2[cf] = __builtin_amdgcn_mfma_f32_16x16x32_bf16(Alo, B2[cf][s][0], acc2[cf], 0, 0, 0);
    }
  }
  // h +=
#pragma unroll
  for (int cf = 0; cf < 2; ++cf)
#pragma unroll
    for (int j = 0; j < 4; ++j) {
      int r = nb + lk * 4 + j;
      int c = colbase + cf * 16 + lm;
      h[(size_t)r * HID + c] += acc2[cf][j] + bias2[cf];
    }
}

// ================= global MLP ==============================================
__global__ __launch_bounds__(128) void k_global(const float* __restrict__ u,
    const float* __restrict__ Wg1, const float* __restrict__ bg1,
    const float* __restrict__ gg1, const float* __restrict__ btg1,
    const float* __restrict__ Wg2, const float* __restrict__ bg2,
    float* __restrict__ u_p) {
  __shared__ float t_s[NGR][HID];
  int c = threadIdx.x;
  for (int g = 0; g < NGR; ++g) {
    float v = bg1[c];
#pragma unroll
    for (int k = 0; k < GD; ++k) v = fmaf(u[(size_t)g * GD + k], Wg1[k * HID + c], v);
    t_s[g][c] = v;
  }
  float sum = 0.f, sq = 0.f;
  for (int g = 0; g < NGR; ++g) { float v = t_s[g][c]; sum += v; sq += v * v; }
  float mean = sum * (1.f / NGR);
  float var = sq * (1.f / NGR) - mean * mean;
  float a = gg1[c] * rsqrtf(var + EPSF);
  float b = btg1[c] - mean * a;
  for (int g = 0; g < NGR; ++g) t_s[g][c] = fmaxf(fmaf(t_s[g][c], a, b), 0.f);
  __syncthreads();
  for (int g = 0; g < NGR; ++g) {
    float acc = bg2[c];
#pragma unroll 8
    for (int k = 0; k < HID; ++k) acc = fmaf(t_s[g][k], Wg2[k * HID + c], acc);
    u_p[(size_t)g * HID + c] = acc;
  }
}

// ================= shift head ==============================================
__global__ __launch_bounds__(256) void k_shift1(
    const float* __restrict__ h, const float* __restrict__ u_p,
    const int* __restrict__ batch, const float* __restrict__ Ws1,
    const float* __restrict__ bs1, float* __restrict__ t1, float* __restrict__ stats) {
  __shared__ float s_in[16][2 * HID];
  const int c = threadIdx.x & 63;
  const int ng = threadIdx.x >> 6;
  float psum = 0.f, psq = 0.f;
  for (int tile = blockIdx.x; tile < NN / 16; tile += gridDim.x) {
    const int nb = tile * 16;
    for (int i = threadIdx.x; i < 16 * HID; i += 256) {
      int ln = i >> 7, k = i & 127;
      s_in[ln][k] = h[(size_t)(nb + ln) * HID + k];
      s_in[ln][HID + k] = u_p[(size_t)batch[nb + ln] * HID + k];
    }
    __syncthreads();
    float acc[4];
#pragma unroll
    for (int j = 0; j < 4; ++j) acc[j] = bs1[c];
    for (int k = 0; k < 2 * HID; ++k) {
      float w = Ws1[k * SH + c];
#pragma unroll
      for (int j = 0; j < 4; ++j) acc[j] = fmaf(s_in[ng * 4 + j][k], w, acc[j]);
    }
#pragma unroll
    for (int j = 0; j < 4; ++j) {
      t1[(size_t)(nb + ng * 4 + j) * SH + c] = acc[j];
      psum += acc[j]; psq += acc[j] * acc[j];
    }
    __syncthreads();
  }
  __shared__ float rs[256], rq[256];
  rs[threadIdx.x] = psum; rq[threadIdx.x] = psq;
  __syncthreads();
  if (threadIdx.x < 64) {
    int c2 = threadIdx.x;
    atomicAdd(&stats[c2], rs[c2] + rs[c2 + 64] + rs[c2 + 128] + rs[c2 + 192]);
    atomicAdd(&stats[128 + c2], rq[c2] + rq[c2 + 64] + rq[c2 + 128] + rq[c2 + 192]);
  }
}

__global__ __launch_bounds__(256) void k_shift2(
    const float* __restrict__ t1, float* __restrict__ stats,
    const float* __restrict__ Ws2, const float* __restrict__ bs2,
    float* __restrict__ t2) {
  __shared__ float r_s[16][SH];
  const int c = threadIdx.x & 63;
  const int ng = threadIdx.x >> 6;
  float psum = 0.f, psq = 0.f;
  for (int tile = blockIdx.x; tile < NN / 16; tile += gridDim.x) {
    const int nb = tile * 16;
    for (int i = threadIdx.x; i < 16 * SH; i += 256) {
      int ln = i >> 6, k = i & 63;
      float v = fmaf(t1[(size_t)(nb + ln) * SH + k], stats[256 + k], stats[384 + k]);
      r_s[ln][k] = fmaxf(v, 0.f);
    }
    __syncthreads();
    float acc[4];
#pragma unroll
    for (int j = 0; j < 4; ++j) acc[j] = bs2[c];
    for (int k = 0; k < SH; ++k) {
      float w = Ws2[k * SH + c];
#pragma unroll
      for (int j = 0; j < 4; ++j) acc[j] = fmaf(r_s[ng * 4 + j][k], w, acc[j]);
    }
#pragma unroll
    for (int j = 0; j < 4; ++j) {
      t2[(size_t)(nb + ng * 4 + j) * SH + c] = acc[j];
      psum += acc[j]; psq += acc[j] * acc[j];
    }
    __syncthreads();
  }
  __shared__ float rs[256], rq[256];
  rs[threadIdx.x] = psum; rq[threadIdx.x] = psq;
  __syncthreads();
  if (threadIdx.x < 64) {
    int c2 = threadIdx.x;
    atomicAdd(&stats[c2], rs[c2] + rs[c2 + 64] + rs[c2 + 128] + rs[c2 + 192]);
    atomicAdd(&stats[128 + c2], rq[c2] + rq[c2 + 64] + rq[c2 + 128] + rq[c2 + 192]);
  }
}

__global__ __launch_bounds__(256) void k_shift3(
    const float* __restrict__ t2, const float* __restrict__ stats,
    const float* __restrict__ Ws3, const float* __restrict__ bs3,
    float* __restrict__ shifts) {
  int lane = threadIdx.x & 63;
  int n = blockIdx.x * 4 + (threadIdx.x >> 6);
  if (n >= NN) return;
  float a = stats[256 + lane], b = stats[384 + lane];
  float r = fmaxf(fmaf(t2[(size_t)n * SH + lane], a, b), 0.f);
  float v = r * Ws3[lane];
#pragma unroll
  for (int off = 32; off; off >>= 1) v += __shfl_down(v, off);
  if (lane == 0) shifts[n] = v + bs3[0];
}

extern "C" void kernel_launch(void* const* d_in, const int* in_sizes, int n_in,
                              void* d_out, int out_size, void* d_ws, size_t ws_size,
                              hipStream_t stream) {
  const float* x     = (const float*)d_in[0];
  const int*   ei    = (const int*)d_in[1];
  const float* eattr = (const float*)d_in[2];
  const int*   batch = (const int*)d_in[3];
  const float* u     = (const float*)d_in[4];
  const float* We1 = (const float*)d_in[5];  const float* be1 = (const float*)d_in[6];
  const float* ge1 = (const float*)d_in[7];  const float* bte1 = (const float*)d_in[8];
  const float* We2 = (const float*)d_in[9];  const float* be2 = (const float*)d_in[10];
  const float* Wf1 = (const float*)d_in[11]; const float* bf1 = (const float*)d_in[12];
  const float* Wf2 = (const float*)d_in[13]; const float* bf2 = (const float*)d_in[14];
  const float* Wd1 = (const float*)d_in[15]; const float* bd1 = (const float*)d_in[16];
  const float* Wd2 = (const float*)d_in[17]; const float* bd2 = (const float*)d_in[18];
  const float* Wg1 = (const float*)d_in[19]; const float* bg1 = (const float*)d_in[20];
  const float* gg1 = (const float*)d_in[21]; const float* btg1 = (const float*)d_in[22];
  const float* Wg2 = (const float*)d_in[23]; const float* bg2 = (const float*)d_in[24];
  const float* Ws1 = (const float*)d_in[25]; const float* bs1 = (const float*)d_in[26];
  const float* gs1 = (const float*)d_in[27]; const float* bts1 = (const float*)d_in[28];
  const float* Ws2 = (const float*)d_in[29]; const float* bs2 = (const float*)d_in[30];
  const float* gs2 = (const float*)d_in[31]; const float* bts2 = (const float*)d_in[32];
  const float* Ws3 = (const float*)d_in[33]; const float* bs3 = (const float*)d_in[34];

  float* out    = (float*)d_out;
  float* shifts = out;                    // [NN]
  float* h      = out + NN;               // [NN,HID]
  float* ea     = out + NN + NN * HID;    // [NE,NG]
  float* u_p    = out + NN + NN * HID + (size_t)NE * NG;  // [NGR,HID]

  // workspace layout
  char* wsb = (char*)d_ws;
  size_t off = 0;
  auto alloc = [&](size_t bytes) { void* p = wsb + off; off = (off + bytes + 255) & ~(size_t)255; return p; };
  float*  stats    = (float*)alloc(512 * sizeof(float));
  int*    hist     = (int*)alloc((size_t)NN * sizeof(int));
  int*    rowptr   = (int*)alloc((size_t)(NN + 1) * sizeof(int));
  int*    perm     = (int*)alloc((size_t)NE * sizeof(int));
  float*  dperm    = (float*)alloc((size_t)NE * sizeof(float));
  int*    rowperm  = (int*)alloc((size_t)NE * sizeof(int));
  int*    destperm = (int*)alloc((size_t)NE * sizeof(int));
  bf16_t* W1Thi    = (bf16_t*)alloc((size_t)NL * 128 * 64 * sizeof(bf16_t));
  bf16_t* W1Tlo    = (bf16_t*)alloc((size_t)NL * 128 * 64 * sizeof(bf16_t));
  bf16_t* W2Thi    = (bf16_t*)alloc((size_t)NL * 128 * 128 * sizeof(bf16_t));
  bf16_t* W2Tlo    = (bf16_t*)alloc((size_t)NL * 128 * 128 * sizeof(bf16_t));
  bf16_t* Wd1Thi   = (bf16_t*)alloc((size_t)NL * 128 * 128 * sizeof(bf16_t));
  bf16_t* Wd1Tlo   = (bf16_t*)alloc((size_t)NL * 128 * 128 * sizeof(bf16_t));
  bf16_t* Wd2Thi   = (bf16_t*)alloc((size_t)NL * 128 * 128 * sizeof(bf16_t));
  bf16_t* Wd2Tlo   = (bf16_t*)alloc((size_t)NL * 128 * 128 * sizeof(bf16_t));
  float*  buf1     = (float*)alloc((size_t)NN * HID * sizeof(float));
  float* t1 = buf1;
  float* t2 = buf1 + (size_t)NN * SH;

  const int* row = ei;        // source j
  const int* col = ei + NE;   // target i

  // ---- CSR build + permuted edge data + weight prep
  hipMemsetAsync(hist, 0, (size_t)NN * sizeof(int), stream);
  k_hist<<<512, 256, 0, stream>>>(col, hist);
  k_scan<<<1, 1024, 0, stream>>>(hist, rowptr);
  k_scatter<<<512, 256, 0, stream>>>(col, hist, perm);
  k_preedge<<<(NE + 255) / 256, 256, 0, stream>>>(perm, eattr, row, col,
                                                  dperm, rowperm, destperm);
  {
    const int total = NL * 128 * 64 + 3 * NL * 128 * 128;
    k_prepw<<<(total + 255) / 256, 256, 0, stream>>>(
        Wf1, Wf2, Wd1, Wd2, W1Thi, W1Tlo, W2Thi, W2Tlo,
        Wd1Thi, Wd1Tlo, Wd2Thi, Wd2Tlo);
  }

  // ---- node encoder
  hipMemsetAsync(stats, 0, 256 * sizeof(float), stream);
  k_enc1<<<512, 256, 0, stream>>>(x, We1, be1, buf1, stats);
  k_bn_fin<<<1, 128, 0, stream>>>(ge1, bte1, stats, 128, 1.f / NN);
  k_enc2<<<2048, 128, 0, stream>>>(buf1, stats, We2, be2, h);

  // ---- gaussian smearing (ea output)
  k_smear<<<(NE * NG + 255) / 256, 256, 0, stream>>>(eattr, ea);

  // ---- interaction layers
  for (int l = 0; l < NL; ++l) {
    k_edge4<<<NN / 16, 256, 0, stream>>>(
        dperm, rowperm, destperm, rowptr, h,
        W1Thi + (size_t)l * 128 * 64, W1Tlo + (size_t)l * 128 * 64,
        W2Thi + (size_t)l * 128 * 128, W2Tlo + (size_t)l * 128 * 128,
        bf1 + (size_t)l * NF, bf2 + (size_t)l * NF, buf1);
    k_node2<<<NN / 16, 256, 0, stream>>>(
        buf1,
        Wd1Thi + (size_t)l * 128 * 128, Wd1Tlo + (size_t)l * 128 * 128,
        Wd2Thi + (size_t)l * 128 * 128, Wd2Tlo + (size_t)l * 128 * 128,
        bd1 + (size_t)l * HID, bd2 + (size_t)l * HID, h);
  }

  // ---- global MLP
  k_global<<<1, 128, 0, stream>>>(u, Wg1, bg1, gg1, btg1, Wg2, bg2, u_p);

  // ---- shift head
  hipMemsetAsync(stats, 0, 256 * sizeof(float), stream);
  k_shift1<<<1024, 256, 0, stream>>>(h, u_p, batch, Ws1, bs1, t1, stats);
  k_bn_fin<<<1, 128, 0, stream>>>(gs1, bts1, stats, 64, 1.f / NN);
  hipMemsetAsync(stats, 0, 256 * sizeof(float), stream);
  k_shift2<<<1024, 256, 0, stream>>>(t1, stats, Ws2, bs2, t2);
  k_bn_fin<<<1, 128, 0, stream>>>(gs2, bts2, stats, 64, 1.f / NN);
  k_shift3<<<(NN + 3) / 4, 256, 0, stream>>>(t2, stats, Ws3, bs3, shifts);
}

// Round 5
// 4273.658 us; speedup vs baseline: 1.6323x; 1.6323x over previous
//
#include <hip/hip_runtime.h>

#define NN 50000
#define NE 1600000
#define NGR 64
#define XD 32
#define HID 128
#define NF 128
#define NG 50
#define GD 16
#define NL 6
#define SH 64
#define EPSF 1e-5f

typedef __bf16 bf16_t;
typedef bf16_t bf16x8 __attribute__((ext_vector_type(8)));
typedef float f32x4 __attribute__((ext_vector_type(4)));

// ================= CSR build (once; col constant across layers) ============
__global__ __launch_bounds__(256) void k_hist(const int* __restrict__ col,
                                              int* __restrict__ hist) {
  for (int e = blockIdx.x * 256 + threadIdx.x; e < NE; e += gridDim.x * 256)
    atomicAdd(&hist[col[e]], 1);
}

__global__ __launch_bounds__(1024) void k_scan(int* __restrict__ hist,
                                               int* __restrict__ rowptr) {
  const int tid = threadIdx.x;
  const int CH = 49;
  const int base = tid * CH;
  int s = 0;
  for (int i = 0; i < CH; ++i) {
    int idx = base + i;
    if (idx < NN) s += hist[idx];
  }
  __shared__ int part[1024];
  part[tid] = s;
  __syncthreads();
  for (int off = 1; off < 1024; off <<= 1) {
    int v = (tid >= off) ? part[tid - off] : 0;
    __syncthreads();
    part[tid] += v;
    __syncthreads();
  }
  int run = part[tid] - s;
  for (int i = 0; i < CH; ++i) {
    int idx = base + i;
    if (idx < NN) {
      int c = hist[idx];
      rowptr[idx] = run;
      hist[idx] = run;
      run += c;
    }
  }
  if (tid == 0) rowptr[NN] = NE;
}

__global__ __launch_bounds__(256) void k_scatter(const int* __restrict__ col,
                                                 int* __restrict__ cursor,
                                                 int* __restrict__ perm) {
  for (int e = blockIdx.x * 256 + threadIdx.x; e < NE; e += gridDim.x * 256) {
    int pos = atomicAdd(&cursor[col[e]], 1);
    perm[pos] = e;
  }
}

// ================= permuted per-edge data ==================================
__global__ __launch_bounds__(256) void k_preedge(const int* __restrict__ perm,
    const float* __restrict__ eattr, const int* __restrict__ row,
    const int* __restrict__ col, float* __restrict__ dperm,
    int* __restrict__ rowperm, int* __restrict__ destperm) {
  int p = blockIdx.x * 256 + threadIdx.x;
  if (p < NE) {
    int pe = perm[p];
    float ax = eattr[(size_t)pe * 3], ay = eattr[(size_t)pe * 3 + 1], az = eattr[(size_t)pe * 3 + 2];
    dperm[p] = sqrtf(ax * ax + ay * ay + az * az);
    rowperm[p] = row[pe];
    destperm[p] = col[pe];
  }
}

// ================= weight prep: transpose, K-pad, split hi/lo ==============
__global__ __launch_bounds__(256) void k_prepw(const float* __restrict__ Wf1,
    const float* __restrict__ Wf2, const float* __restrict__ Wd1,
    const float* __restrict__ Wd2,
    bf16_t* __restrict__ W1Thi, bf16_t* __restrict__ W1Tlo,
    bf16_t* __restrict__ W2Thi, bf16_t* __restrict__ W2Tlo,
    bf16_t* __restrict__ Wd1Thi, bf16_t* __restrict__ Wd1Tlo,
    bf16_t* __restrict__ Wd2Thi, bf16_t* __restrict__ Wd2Tlo) {
  const int S0 = NL * 128 * 64;
  const int S1 = NL * 128 * 128;
  int idx = blockIdx.x * 256 + threadIdx.x;
  if (idx < S0) {
    int l = idx / (128 * 64);
    int r = idx - l * (128 * 64);
    int c = r >> 6, k = r & 63;
    float v = (k < NG) ? Wf1[(size_t)l * NG * NF + (size_t)k * NF + c] : 0.f;
    bf16_t hv = (bf16_t)v;
    W1Thi[idx] = hv;
    W1Tlo[idx] = (bf16_t)(v - (float)hv);
  } else if (idx < S0 + 3 * S1) {
    int j = idx - S0;
    int which = j / S1;       // 0: Wf2, 1: Wd1, 2: Wd2
    int jj = j - which * S1;
    int l = jj / (128 * 128);
    int r = jj - l * (128 * 128);
    int c = r >> 7, k = r & 127;
    const float* W = (which == 0) ? Wf2 : (which == 1) ? Wd1 : Wd2;
    float v = W[(size_t)l * 128 * 128 + (size_t)k * 128 + c];
    bf16_t hv = (bf16_t)v;
    bf16_t lv = (bf16_t)(v - (float)hv);
    if (which == 0)      { W2Thi[jj] = hv;  W2Tlo[jj] = lv; }
    else if (which == 1) { Wd1Thi[jj] = hv; Wd1Tlo[jj] = lv; }
    else                 { Wd2Thi[jj] = hv; Wd2Tlo[jj] = lv; }
  }
}

// ================= node encoder ============================================
__global__ __launch_bounds__(256) void k_enc1(const float* __restrict__ x,
    const float* __restrict__ We1, const float* __restrict__ be1,
    float* __restrict__ t, float* __restrict__ stats) {
  int c = threadIdx.x & 127;
  int half = threadIdx.x >> 7;
  float b = be1[c];
  float psum = 0.f, psq = 0.f;
  for (int n = blockIdx.x * 2 + half; n < NN; n += gridDim.x * 2) {
    const float* xr = x + (size_t)n * XD;
    float v = b;
#pragma unroll
    for (int k = 0; k < XD; ++k) v = fmaf(xr[k], We1[k * HID + c], v);
    t[(size_t)n * HID + c] = v;
    psum += v; psq += v * v;
  }
  __shared__ float s0[256], s1[256];
  s0[threadIdx.x] = psum; s1[threadIdx.x] = psq;
  __syncthreads();
  if (threadIdx.x < 128) {
    atomicAdd(&stats[threadIdx.x], s0[threadIdx.x] + s0[threadIdx.x + 128]);
    atomicAdd(&stats[128 + threadIdx.x], s1[threadIdx.x] + s1[threadIdx.x + 128]);
  }
}

__global__ __launch_bounds__(128) void k_bn_fin(const float* __restrict__ gamma,
    const float* __restrict__ beta, float* __restrict__ stats, int C, float invn) {
  int c = threadIdx.x;
  if (c < C) {
    float mean = stats[c] * invn;
    float var = stats[128 + c] * invn - mean * mean;
    float a = gamma[c] * rsqrtf(var + EPSF);
    stats[256 + c] = a;
    stats[384 + c] = beta[c] - mean * a;
  }
}

__global__ __launch_bounds__(128) void k_enc2(const float* __restrict__ t,
    const float* __restrict__ stats, const float* __restrict__ We2,
    const float* __restrict__ be2, float* __restrict__ h) {
  __shared__ float r[HID];
  int c = threadIdx.x;
  float a = stats[256 + c], b = stats[384 + c];
  float bias = be2[c];
  for (int n = blockIdx.x; n < NN; n += gridDim.x) {
    float v = fmaf(t[(size_t)n * HID + c], a, b);
    r[c] = fmaxf(v, 0.f);
    __syncthreads();
    float acc = bias;
#pragma unroll 8
    for (int k = 0; k < HID; ++k) acc = fmaf(r[k], We2[k * HID + c], acc);
    h[(size_t)n * HID + c] = acc;
    __syncthreads();
  }
}

// ================= gaussian smearing (ea output) ===========================
__global__ __launch_bounds__(256) void k_smear(const float* __restrict__ eattr,
    float* __restrict__ ea) {
  int idx = blockIdx.x * 256 + threadIdx.x;
  if (idx >= NE * NG) return;
  int e = idx / NG;
  int g = idx - e * NG;
  float ax = eattr[(size_t)e * 3], ay = eattr[(size_t)e * 3 + 1], az = eattr[(size_t)e * 3 + 2];
  float d = sqrtf(ax * ax + ay * ay + az * az);
  float off = (10.0f / 49.0f) * (float)g;
  float z = d - off;
  ea[idx] = __expf(-12.005f * z * z);
}

// ================= MFMA edge kernel v5: 8 waves x 16 cols ==================
// Register-resident weights (12 frags = 48 VGPR/lane). Per 16-edge tile:
// h gather first (in flight across 2 barriers + GEMM1), coop gaussians
// (2 exp/thread), GEMM1 4 MFMA, f1 split, GEMM2 12 MFMA, CSR epilogue.
__global__ __launch_bounds__(512) void k_edge5(
    const float* __restrict__ dperm, const int* __restrict__ rowperm,
    const int* __restrict__ destperm, const int* __restrict__ rowptr,
    const float* __restrict__ h,
    const bf16_t* __restrict__ W1Thi, const bf16_t* __restrict__ W1Tlo,
    const bf16_t* __restrict__ W2Thi, const bf16_t* __restrict__ W2Tlo,
    const float* __restrict__ bf1, const float* __restrict__ bf2,
    float* __restrict__ agg) {
  __shared__ float agg_s[16][HID];
  __shared__ __align__(16) bf16_t A_s[2][64][8];
  __shared__ __align__(16) bf16_t f1hi_s[16][136];
  __shared__ __align__(16) bf16_t f1lo_s[16][136];

  const int tid = threadIdx.x;
  const int lane = tid & 63;
  const int w = tid >> 6;          // wave 0..7
  const int lm = lane & 15;
  const int lk = lane >> 4;
  const int colbase = w * 16;      // 16 cols per wave
  const int nb = blockIdx.x * 16;
  const int eS = rowptr[nb], eE = rowptr[nb + 16];

  for (int i = tid; i < 16 * HID; i += 512) ((float*)agg_s)[i] = 0.f;

  // ---- register-resident B fragments (loaded once) ----
  const int cc = colbase + lm;
  bf16x8 B1[2][2];
#pragma unroll
  for (int s = 0; s < 2; ++s) {
    int k0 = s * 32 + lk * 8;
    B1[s][0] = *(const bf16x8*)(W1Thi + (size_t)cc * 64 + k0);
    B1[s][1] = *(const bf16x8*)(W1Tlo + (size_t)cc * 64 + k0);
  }
  bf16x8 B2[4][2];
#pragma unroll
  for (int s = 0; s < 4; ++s) {
    int k0 = s * 32 + lk * 8;
    B2[s][0] = *(const bf16x8*)(W2Thi + (size_t)cc * 128 + k0);
    B2[s][1] = *(const bf16x8*)(W2Tlo + (size_t)cc * 128 + k0);
  }
  const float bias1 = bf1[cc];
  const float bias2 = bf2[cc];

  // coop A_s mapping: 1024 values / 512 threads = 2 each
  const int lin = tid * 2;
  const int cs = lin >> 9;
  const int rem = lin & 511;
  const int cl = rem >> 3;
  const int ci0 = rem & 7;
  const int cedge = cl & 15;
  const int ckg = cl >> 4;

  for (int et = eS; et < eE; et += 16) {
    const int nval = min(16, eE - et);
    // ---- meta into regs (lanes 0..15 of every wave) ----
    float dreg = 0.f; int rowreg = 0, dstreg = 0;
    if (lane < nval) {
      int p = et + lane;
      dreg = dperm[p];
      rowreg = rowperm[p];
      dstreg = destperm[p];
    }
    // ---- h gather issued now ----
    float hv[4];
#pragma unroll
    for (int j = 0; j < 4; ++j) {
      int e = lk * 4 + j;
      int r = __shfl(rowreg, e);
      hv[j] = (e < nval) ? h[(size_t)r * HID + cc] : 0.f;
    }
    __syncthreads();  // s0: prev tile's A_s/f1 consumers done
    // ---- coop gaussians (2 exp/thread) ----
    {
      float dv = __shfl(dreg, cedge);
      bool ev = cedge < nval;
#pragma unroll
      for (int ii = 0; ii < 2; ++ii) {
        int g = cs * 32 + ckg * 8 + ci0 + ii;
        float v = 0.f;
        if (ev && g < NG) {
          float z = dv - 0.2040816327f * (float)g;
          v = __expf(-12.005f * z * z);
        }
        A_s[cs][cl][ci0 + ii] = (bf16_t)v;
      }
    }
    __syncthreads();  // s1: A_s ready
    // ---- GEMM1 (A-hi only, B split-2): 4 MFMA ----
    f32x4 acc1 = {0.f, 0.f, 0.f, 0.f};
#pragma unroll
    for (int s = 0; s < 2; ++s) {
      bf16x8 A1 = *(const bf16x8*)&A_s[s][lane][0];
      acc1 = __builtin_amdgcn_mfma_f32_16x16x32_bf16(A1, B1[s][0], acc1, 0, 0, 0);
      acc1 = __builtin_amdgcn_mfma_f32_16x16x32_bf16(A1, B1[s][1], acc1, 0, 0, 0);
    }
    // ---- relu + split -> f1 LDS ----
#pragma unroll
    for (int j = 0; j < 4; ++j) {
      int r = lk * 4 + j;
      float v = fmaxf(acc1[j] + bias1, 0.f);
      bf16_t hvv = (bf16_t)v;
      f1hi_s[r][cc] = hvv;
      f1lo_s[r][cc] = (bf16_t)(v - (float)hvv);
    }
    __syncthreads();  // s2: f1 ready
    // ---- GEMM2 (3-term): 12 MFMA ----
    f32x4 acc2 = {0.f, 0.f, 0.f, 0.f};
#pragma unroll
    for (int s = 0; s < 4; ++s) {
      bf16x8 Ahi = *(const bf16x8*)&f1hi_s[lm][s * 32 + lk * 8];
      bf16x8 Alo = *(const bf16x8*)&f1lo_s[lm][s * 32 + lk * 8];
      acc2 = __builtin_amdgcn_mfma_f32_16x16x32_bf16(Ahi, B2[s][0], acc2, 0, 0, 0);
      acc2 = __builtin_amdgcn_mfma_f32_16x16x32_bf16(Ahi, B2[s][1], acc2, 0, 0, 0);
      acc2 = __builtin_amdgcn_mfma_f32_16x16x32_bf16(Alo, B2[s][0], acc2, 0, 0, 0);
    }
    // ---- epilogue ----
    int dfirst = __shfl(dstreg, 0) - nb;
    int dlast = __shfl(dstreg, nval - 1) - nb;
    if (dfirst == dlast) {
      float v = 0.f;
#pragma unroll
      for (int j = 0; j < 4; ++j) v += (acc2[j] + bias2) * hv[j];
      v += __shfl_xor(v, 16);
      v += __shfl_xor(v, 32);
      if (lk == 0) agg_s[dfirst][cc] += v;
    } else {
      int de[4];
#pragma unroll
      for (int j = 0; j < 4; ++j) de[j] = __shfl(dstreg, lk * 4 + j) - nb;
      float racc = 0.f;
      int cur = -1;
#pragma unroll
      for (int j = 0; j < 4; ++j) {
        int e = lk * 4 + j;
        if (e < nval) {
          float msg = (acc2[j] + bias2) * hv[j];
          if (de[j] != cur) {
            if (cur >= 0) atomicAdd(&agg_s[cur][cc], racc);
            racc = 0.f;
            cur = de[j];
          }
          racc += msg;
        }
      }
      if (cur >= 0) atomicAdd(&agg_s[cur][cc], racc);
    }
  }
  __syncthreads();
  for (int i = tid; i < 16 * 32; i += 512) {
    int le = i >> 5, cj = (i & 31) * 4;
    *(float4*)(agg + (size_t)(nb + le) * HID + cj) = *(const float4*)&agg_s[le][cj];
  }
}

// ================= MFMA node update v3: 8 waves x 16 cols, grid-stride =====
__global__ __launch_bounds__(512) void k_node3(
    const float* __restrict__ agg,
    const bf16_t* __restrict__ Wd1Thi, const bf16_t* __restrict__ Wd1Tlo,
    const bf16_t* __restrict__ Wd2Thi, const bf16_t* __restrict__ Wd2Tlo,
    const float* __restrict__ bd1, const float* __restrict__ bd2,
    float* __restrict__ h) {
  __shared__ __align__(16) bf16_t aghi[16][136];
  __shared__ __align__(16) bf16_t aglo[16][136];
  __shared__ __align__(16) bf16_t t1hi[16][136];
  __shared__ __align__(16) bf16_t t1lo[16][136];

  const int tid = threadIdx.x;
  const int lane = tid & 63;
  const int w = tid >> 6;
  const int lm = lane & 15;
  const int lk = lane >> 4;
  const int cc = w * 16 + lm;

  // register-resident weights (16 frags = 64 VGPR)
  bf16x8 B1[4][2], B2[4][2];
#pragma unroll
  for (int s = 0; s < 4; ++s) {
    int k0 = s * 32 + lk * 8;
    B1[s][0] = *(const bf16x8*)(Wd1Thi + (size_t)cc * 128 + k0);
    B1[s][1] = *(const bf16x8*)(Wd1Tlo + (size_t)cc * 128 + k0);
    B2[s][0] = *(const bf16x8*)(Wd2Thi + (size_t)cc * 128 + k0);
    B2[s][1] = *(const bf16x8*)(Wd2Tlo + (size_t)cc * 128 + k0);
  }
  const float bias1 = bd1[cc];
  const float bias2 = bd2[cc];

  for (int tile = blockIdx.x; tile < NN / 16; tile += gridDim.x) {
    const int nb = tile * 16;
    __syncthreads();  // protect LDS from previous tile's readers
    for (int idx = tid; idx < 16 * 128; idx += 512) {
      int r = idx >> 7, k = idx & 127;
      float v = agg[(size_t)(nb + r) * HID + k];
      bf16_t hv = (bf16_t)v;
      aghi[r][k] = hv;
      aglo[r][k] = (bf16_t)(v - (float)hv);
    }
    __syncthreads();
    f32x4 acc1 = {0.f, 0.f, 0.f, 0.f};
#pragma unroll
    for (int s = 0; s < 4; ++s) {
      bf16x8 Ahi = *(const bf16x8*)&aghi[lm][s * 32 + lk * 8];
      bf16x8 Alo = *(const bf16x8*)&aglo[lm][s * 32 + lk * 8];
      acc1 = __builtin_amdgcn_mfma_f32_16x16x32_bf16(Ahi, B1[s][0], acc1, 0, 0, 0);
      acc1 = __builtin_amdgcn_mfma_f32_16x16x32_bf16(Ahi, B1[s][1], acc1, 0, 0, 0);
      acc1 = __builtin_amdgcn_mfma_f32_16x16x32_bf16(Alo, B1[s][0], acc1, 0, 0, 0);
    }
#pragma unroll
    for (int j = 0; j < 4; ++j) {
      int r = lk * 4 + j;
      float v = fmaxf(acc1[j] + bias1, 0.f);
      bf16_t hv = (bf16_t)v;
      t1hi[r][cc] = hv;
      t1lo[r][cc] = (bf16_t)(v - (float)hv);
    }
    __syncthreads();
    f32x4 acc2 = {0.f, 0.f, 0.f, 0.f};
#pragma unroll
    for (int s = 0; s < 4; ++s) {
      bf16x8 Ahi = *(const bf16x8*)&t1hi[lm][s * 32 + lk * 8];
      bf16x8 Alo = *(const bf16x8*)&t1lo[lm][s * 32 + lk * 8];
      acc2 = __builtin_amdgcn_mfma_f32_16x16x32_bf16(Ahi, B2[s][0], acc2, 0, 0, 0);
      acc2 = __builtin_amdgcn_mfma_f32_16x16x32_bf16(Ahi, B2[s][1], acc2, 0, 0, 0);
      acc2 = __builtin_amdgcn_mfma_f32_16x16x32_bf16(Alo, B2[s][0], acc2, 0, 0, 0);
    }
#pragma unroll
    for (int j = 0; j < 4; ++j)
      h[(size_t)(nb + lk * 4 + j) * HID + cc] += acc2[j] + bias2;
  }
}

// ================= global MLP ==============================================
__global__ __launch_bounds__(128) void k_global(const float* __restrict__ u,
    const float* __restrict__ Wg1, const float* __restrict__ bg1,
    const float* __restrict__ gg1, const float* __restrict__ btg1,
    const float* __restrict__ Wg2, const float* __restrict__ bg2,
    float* __restrict__ u_p) {
  __shared__ float t_s[NGR][HID];
  int c = threadIdx.x;
  for (int g = 0; g < NGR; ++g) {
    float v = bg1[c];
#pragma unroll
    for (int k = 0; k < GD; ++k) v = fmaf(u[(size_t)g * GD + k], Wg1[k * HID + c], v);
    t_s[g][c] = v;
  }
  float sum = 0.f, sq = 0.f;
  for (int g = 0; g < NGR; ++g) { float v = t_s[g][c]; sum += v; sq += v * v; }
  float mean = sum * (1.f / NGR);
  float var = sq * (1.f / NGR) - mean * mean;
  float a = gg1[c] * rsqrtf(var + EPSF);
  float b = btg1[c] - mean * a;
  for (int g = 0; g < NGR; ++g) t_s[g][c] = fmaxf(fmaf(t_s[g][c], a, b), 0.f);
  __syncthreads();
  for (int g = 0; g < NGR; ++g) {
    float acc = bg2[c];
#pragma unroll 8
    for (int k = 0; k < HID; ++k) acc = fmaf(t_s[g][k], Wg2[k * HID + c], acc);
    u_p[(size_t)g * HID + c] = acc;
  }
}

// ================= shift head ==============================================
__global__ __launch_bounds__(256) void k_shift1(
    const float* __restrict__ h, const float* __restrict__ u_p,
    const int* __restrict__ batch, const float* __restrict__ Ws1,
    const float* __restrict__ bs1, float* __restrict__ t1, float* __restrict__ stats) {
  __shared__ float s_in[16][2 * HID];
  const int c = threadIdx.x & 63;
  const int ng = threadIdx.x >> 6;
  float psum = 0.f, psq = 0.f;
  for (int tile = blockIdx.x; tile < NN / 16; tile += gridDim.x) {
    const int nb = tile * 16;
    for (int i = threadIdx.x; i < 16 * HID; i += 256) {
      int ln = i >> 7, k = i & 127;
      s_in[ln][k] = h[(size_t)(nb + ln) * HID + k];
      s_in[ln][HID + k] = u_p[(size_t)batch[nb + ln] * HID + k];
    }
    __syncthreads();
    float acc[4];
#pragma unroll
    for (int j = 0; j < 4; ++j) acc[j] = bs1[c];
    for (int k = 0; k < 2 * HID; ++k) {
      float w = Ws1[k * SH + c];
#pragma unroll
      for (int j = 0; j < 4; ++j) acc[j] = fmaf(s_in[ng * 4 + j][k], w, acc[j]);
    }
#pragma unroll
    for (int j = 0; j < 4; ++j) {
      t1[(size_t)(nb + ng * 4 + j) * SH + c] = acc[j];
      psum += acc[j]; psq += acc[j] * acc[j];
    }
    __syncthreads();
  }
  __shared__ float rs[256], rq[256];
  rs[threadIdx.x] = psum; rq[threadIdx.x] = psq;
  __syncthreads();
  if (threadIdx.x < 64) {
    int c2 = threadIdx.x;
    atomicAdd(&stats[c2], rs[c2] + rs[c2 + 64] + rs[c2 + 128] + rs[c2 + 192]);
    atomicAdd(&stats[128 + c2], rq[c2] + rq[c2 + 64] + rq[c2 + 128] + rq[c2 + 192]);
  }
}

__global__ __launch_bounds__(256) void k_shift2(
    const float* __restrict__ t1, float* __restrict__ stats,
    const float* __restrict__ Ws2, const float* __restrict__ bs2,
    float* __restrict__ t2) {
  __shared__ float r_s[16][SH];
  const int c = threadIdx.x & 63;
  const int ng = threadIdx.x >> 6;
  float psum = 0.f, psq = 0.f;
  for (int tile = blockIdx.x; tile < NN / 16; tile += gridDim.x) {
    const int nb = tile * 16;
    for (int i = threadIdx.x; i < 16 * SH; i += 256) {
      int ln = i >> 6, k = i & 63;
      float v = fmaf(t1[(size_t)(nb + ln) * SH + k], stats[256 + k], stats[384 + k]);
      r_s[ln][k] = fmaxf(v, 0.f);
    }
    __syncthreads();
    float acc[4];
#pragma unroll
    for (int j = 0; j < 4; ++j) acc[j] = bs2[c];
    for (int k = 0; k < SH; ++k) {
      float w = Ws2[k * SH + c];
#pragma unroll
      for (int j = 0; j < 4; ++j) acc[j] = fmaf(r_s[ng * 4 + j][k], w, acc[j]);
    }
#pragma unroll
    for (int j = 0; j < 4; ++j) {
      t2[(size_t)(nb + ng * 4 + j) * SH + c] = acc[j];
      psum += acc[j]; psq += acc[j] * acc[j];
    }
    __syncthreads();
  }
  __shared__ float rs[256], rq[256];
  rs[threadIdx.x] = psum; rq[threadIdx.x] = psq;
  __syncthreads();
  if (threadIdx.x < 64) {
    int c2 = threadIdx.x;
    atomicAdd(&stats[c2], rs[c2] + rs[c2 + 64] + rs[c2 + 128] + rs[c2 + 192]);
    atomicAdd(&stats[128 + c2], rq[c2] + rq[c2 + 64] + rq[c2 + 128] + rq[c2 + 192]);
  }
}

__global__ __launch_bounds__(256) void k_shift3(
    const float* __restrict__ t2, const float* __restrict__ stats,
    const float* __restrict__ Ws3, const float* __restrict__ bs3,
    float* __restrict__ shifts) {
  int lane = threadIdx.x & 63;
  int n = blockIdx.x * 4 + (threadIdx.x >> 6);
  if (n >= NN) return;
  float a = stats[256 + lane], b = stats[384 + lane];
  float r = fmaxf(fmaf(t2[(size_t)n * SH + lane], a, b), 0.f);
  float v = r * Ws3[lane];
#pragma unroll
  for (int off = 32; off; off >>= 1) v += __shfl_down(v, off);
  if (lane == 0) shifts[n] = v + bs3[0];
}

extern "C" void kernel_launch(void* const* d_in, const int* in_sizes, int n_in,
                              void* d_out, int out_size, void* d_ws, size_t ws_size,
                              hipStream_t stream) {
  const float* x     = (const float*)d_in[0];
  const int*   ei    = (const int*)d_in[1];
  const float* eattr = (const float*)d_in[2];
  const int*   batch = (const int*)d_in[3];
  const float* u     = (const float*)d_in[4];
  const float* We1 = (const float*)d_in[5];  const float* be1 = (const float*)d_in[6];
  const float* ge1 = (const float*)d_in[7];  const float* bte1 = (const float*)d_in[8];
  const float* We2 = (const float*)d_in[9];  const float* be2 = (const float*)d_in[10];
  const float* Wf1 = (const float*)d_in[11]; const float* bf1 = (const float*)d_in[12];
  const float* Wf2 = (const float*)d_in[13]; const float* bf2 = (const float*)d_in[14];
  const float* Wd1 = (const float*)d_in[15]; const float* bd1 = (const float*)d_in[16];
  const float* Wd2 = (const float*)d_in[17]; const float* bd2 = (const float*)d_in[18];
  const float* Wg1 = (const float*)d_in[19]; const float* bg1 = (const float*)d_in[20];
  const float* gg1 = (const float*)d_in[21]; const float* btg1 = (const float*)d_in[22];
  const float* Wg2 = (const float*)d_in[23]; const float* bg2 = (const float*)d_in[24];
  const float* Ws1 = (const float*)d_in[25]; const float* bs1 = (const float*)d_in[26];
  const float* gs1 = (const float*)d_in[27]; const float* bts1 = (const float*)d_in[28];
  const float* Ws2 = (const float*)d_in[29]; const float* bs2 = (const float*)d_in[30];
  const float* gs2 = (const float*)d_in[31]; const float* bts2 = (const float*)d_in[32];
  const float* Ws3 = (const float*)d_in[33]; const float* bs3 = (const float*)d_in[34];

  float* out    = (float*)d_out;
  float* shifts = out;                    // [NN]
  float* h      = out + NN;               // [NN,HID]
  float* ea     = out + NN + NN * HID;    // [NE,NG]
  float* u_p    = out + NN + NN * HID + (size_t)NE * NG;  // [NGR,HID]

  // workspace layout
  char* wsb = (char*)d_ws;
  size_t off = 0;
  auto alloc = [&](size_t bytes) { void* p = wsb + off; off = (off + bytes + 255) & ~(size_t)255; return p; };
  float*  stats    = (float*)alloc(512 * sizeof(float));
  int*    hist     = (int*)alloc((size_t)NN * sizeof(int));
  int*    rowptr   = (int*)alloc((size_t)(NN + 1) * sizeof(int));
  int*    perm     = (int*)alloc((size_t)NE * sizeof(int));
  float*  dperm    = (float*)alloc((size_t)NE * sizeof(float));
  int*    rowperm  = (int*)alloc((size_t)NE * sizeof(int));
  int*    destperm = (int*)alloc((size_t)NE * sizeof(int));
  bf16_t* W1Thi    = (bf16_t*)alloc((size_t)NL * 128 * 64 * sizeof(bf16_t));
  bf16_t* W1Tlo    = (bf16_t*)alloc((size_t)NL * 128 * 64 * sizeof(bf16_t));
  bf16_t* W2Thi    = (bf16_t*)alloc((size_t)NL * 128 * 128 * sizeof(bf16_t));
  bf16_t* W2Tlo    = (bf16_t*)alloc((size_t)NL * 128 * 128 * sizeof(bf16_t));
  bf16_t* Wd1Thi   = (bf16_t*)alloc((size_t)NL * 128 * 128 * sizeof(bf16_t));
  bf16_t* Wd1Tlo   = (bf16_t*)alloc((size_t)NL * 128 * 128 * sizeof(bf16_t));
  bf16_t* Wd2Thi   = (bf16_t*)alloc((size_t)NL * 128 * 128 * sizeof(bf16_t));
  bf16_t* Wd2Tlo   = (bf16_t*)alloc((size_t)NL * 128 * 128 * sizeof(bf16_t));
  float*  buf1     = (float*)alloc((size_t)NN * HID * sizeof(float));
  float* t1 = buf1;
  float* t2 = buf1 + (size_t)NN * SH;

  const int* row = ei;        // source j
  const int* col = ei + NE;   // target i

  // ---- CSR build + permuted edge data + weight prep
  hipMemsetAsync(hist, 0, (size_t)NN * sizeof(int), stream);
  k_hist<<<512, 256, 0, stream>>>(col, hist);
  k_scan<<<1, 1024, 0, stream>>>(hist, rowptr);
  k_scatter<<<512, 256, 0, stream>>>(col, hist, perm);
  k_preedge<<<(NE + 255) / 256, 256, 0, stream>>>(perm, eattr, row, col,
                                                  dperm, rowperm, destperm);
  {
    const int total = NL * 128 * 64 + 3 * NL * 128 * 128;
    k_prepw<<<(total + 255) / 256, 256, 0, stream>>>(
        Wf1, Wf2, Wd1, Wd2, W1Thi, W1Tlo, W2Thi, W2Tlo,
        Wd1Thi, Wd1Tlo, Wd2Thi, Wd2Tlo);
  }

  // ---- node encoder
  hipMemsetAsync(stats, 0, 256 * sizeof(float), stream);
  k_enc1<<<512, 256, 0, stream>>>(x, We1, be1, buf1, stats);
  k_bn_fin<<<1, 128, 0, stream>>>(ge1, bte1, stats, 128, 1.f / NN);
  k_enc2<<<2048, 128, 0, stream>>>(buf1, stats, We2, be2, h);

  // ---- gaussian smearing (ea output)
  k_smear<<<(NE * NG + 255) / 256, 256, 0, stream>>>(eattr, ea);

  // ---- interaction layers
  for (int l = 0; l < NL; ++l) {
    k_edge5<<<NN / 16, 512, 0, stream>>>(
        dperm, rowperm, destperm, rowptr, h,
        W1Thi + (size_t)l * 128 * 64, W1Tlo + (size_t)l * 128 * 64,
        W2Thi + (size_t)l * 128 * 128, W2Tlo + (size_t)l * 128 * 128,
        bf1 + (size_t)l * NF, bf2 + (size_t)l * NF, buf1);
    k_node3<<<640, 512, 0, stream>>>(
        buf1,
        Wd1Thi + (size_t)l * 128 * 128, Wd1Tlo + (size_t)l * 128 * 128,
        Wd2Thi + (size_t)l * 128 * 128, Wd2Tlo + (size_t)l * 128 * 128,
        bd1 + (size_t)l * HID, bd2 + (size_t)l * HID, h);
  }

  // ---- global MLP
  k_global<<<1, 128, 0, stream>>>(u, Wg1, bg1, gg1, btg1, Wg2, bg2, u_p);

  // ---- shift head
  hipMemsetAsync(stats, 0, 256 * sizeof(float), stream);
  k_shift1<<<1024, 256, 0, stream>>>(h, u_p, batch, Ws1, bs1, t1, stats);
  k_bn_fin<<<1, 128, 0, stream>>>(gs1, bts1, stats, 64, 1.f / NN);
  hipMemsetAsync(stats, 0, 256 * sizeof(float), stream);
  k_shift2<<<1024, 256, 0, stream>>>(t1, stats, Ws2, bs2, t2);
  k_bn_fin<<<1, 128, 0, stream>>>(gs2, bts2, stats, 64, 1.f / NN);
  k_shift3<<<(NN + 3) / 4, 256, 0, stream>>>(t2, stats, Ws3, bs3, shifts);
}

// Round 6
// 3581.940 us; speedup vs baseline: 1.9476x; 1.1931x over previous
//
#include <hip/hip_runtime.h>

#define NN 50000
#define NE 1600000
#define NGR 64
#define XD 32
#define HID 128
#define NF 128
#define NG 50
#define GD 16
#define NL 6
#define SH 64
#define EPSF 1e-5f
#define TBL 4096          // filter table knots
#define INVSTEP 320.0f    // 1/step; covers d in [0, 12.8]

typedef __bf16 bf16_t;
typedef bf16_t bf16x8 __attribute__((ext_vector_type(8)));
typedef float f32x4 __attribute__((ext_vector_type(4)));

// ================= CSR build (once; col constant across layers) ============
__global__ __launch_bounds__(256) void k_hist(const int* __restrict__ col,
                                              int* __restrict__ hist) {
  for (int e = blockIdx.x * 256 + threadIdx.x; e < NE; e += gridDim.x * 256)
    atomicAdd(&hist[col[e]], 1);
}

__global__ __launch_bounds__(1024) void k_scan(int* __restrict__ hist,
                                               int* __restrict__ rowptr) {
  const int tid = threadIdx.x;
  const int CH = 49;
  const int base = tid * CH;
  int s = 0;
  for (int i = 0; i < CH; ++i) {
    int idx = base + i;
    if (idx < NN) s += hist[idx];
  }
  __shared__ int part[1024];
  part[tid] = s;
  __syncthreads();
  for (int off = 1; off < 1024; off <<= 1) {
    int v = (tid >= off) ? part[tid - off] : 0;
    __syncthreads();
    part[tid] += v;
    __syncthreads();
  }
  int run = part[tid] - s;
  for (int i = 0; i < CH; ++i) {
    int idx = base + i;
    if (idx < NN) {
      int c = hist[idx];
      rowptr[idx] = run;
      hist[idx] = run;
      run += c;
    }
  }
  if (tid == 0) rowptr[NN] = NE;
}

__global__ __launch_bounds__(256) void k_scatter(const int* __restrict__ col,
                                                 int* __restrict__ cursor,
                                                 int* __restrict__ perm) {
  for (int e = blockIdx.x * 256 + threadIdx.x; e < NE; e += gridDim.x * 256) {
    int pos = atomicAdd(&cursor[col[e]], 1);
    perm[pos] = e;
  }
}

// ================= permuted per-edge data (idx/frac for table lerp) ========
__global__ __launch_bounds__(256) void k_preedge(const int* __restrict__ perm,
    const float* __restrict__ eattr, const int* __restrict__ row,
    const int* __restrict__ col, int* __restrict__ idxperm,
    float* __restrict__ fracperm, int* __restrict__ rowperm,
    int* __restrict__ destperm) {
  int p = blockIdx.x * 256 + threadIdx.x;
  if (p < NE) {
    int pe = perm[p];
    float ax = eattr[(size_t)pe * 3], ay = eattr[(size_t)pe * 3 + 1], az = eattr[(size_t)pe * 3 + 2];
    float d = sqrtf(ax * ax + ay * ay + az * az);
    float tt = fminf(d * INVSTEP, (float)(TBL - 2) + 0.999f);
    int id = (int)tt;
    idxperm[p] = id;
    fracperm[p] = tt - (float)id;
    rowperm[p] = row[pe];
    destperm[p] = col[pe];
  }
}

// ================= filter table build: Wtab[l][t][c] = W(d_t) ==============
// one block = one (layer, knot) row; all f32.
__global__ __launch_bounds__(128) void k_tabbuild(
    const float* __restrict__ Wf1, const float* __restrict__ bf1,
    const float* __restrict__ Wf2, const float* __restrict__ bf2,
    float* __restrict__ tab) {
  int bid = blockIdx.x;            // 0 .. NL*TBL-1
  int l = bid / TBL;
  int t = bid - l * TBL;
  int c = threadIdx.x;
  __shared__ float g_s[NG];
  __shared__ float f1_s[NF];
  float d = (float)t * (1.0f / INVSTEP);
  if (c < NG) {
    float z = d - 0.2040816327f * (float)c;  // offset = 10*g/49
    g_s[c] = expf(-12.005f * z * z);
  }
  __syncthreads();
  const float* W1 = Wf1 + (size_t)l * NG * NF;
  float acc = bf1[(size_t)l * NF + c];
  for (int g = 0; g < NG; ++g) acc = fmaf(g_s[g], W1[g * NF + c], acc);
  f1_s[c] = fmaxf(acc, 0.f);
  __syncthreads();
  const float* W2 = Wf2 + (size_t)l * NF * NF;
  float out = bf2[(size_t)l * NF + c];
#pragma unroll 8
  for (int k = 0; k < NF; ++k) out = fmaf(f1_s[k], W2[k * NF + c], out);
  tab[(size_t)bid * NF + c] = out;
}

// ================= weight prep for node MLP (transpose + split hi/lo) ======
__global__ __launch_bounds__(256) void k_prepw(const float* __restrict__ Wd1,
    const float* __restrict__ Wd2,
    bf16_t* __restrict__ Wd1Thi, bf16_t* __restrict__ Wd1Tlo,
    bf16_t* __restrict__ Wd2Thi, bf16_t* __restrict__ Wd2Tlo) {
  const int S1 = NL * 128 * 128;
  int idx = blockIdx.x * 256 + threadIdx.x;
  if (idx < 2 * S1) {
    int which = idx / S1;  // 0: Wd1, 1: Wd2
    int jj = idx - which * S1;
    int l = jj / (128 * 128);
    int r = jj - l * (128 * 128);
    int c = r >> 7, k = r & 127;
    const float* W = (which == 0) ? Wd1 : Wd2;
    float v = W[(size_t)l * 128 * 128 + (size_t)k * 128 + c];
    bf16_t hv = (bf16_t)v;
    bf16_t lv = (bf16_t)(v - (float)hv);
    if (which == 0) { Wd1Thi[jj] = hv; Wd1Tlo[jj] = lv; }
    else            { Wd2Thi[jj] = hv; Wd2Tlo[jj] = lv; }
  }
}

// ================= node encoder ============================================
__global__ __launch_bounds__(256) void k_enc1(const float* __restrict__ x,
    const float* __restrict__ We1, const float* __restrict__ be1,
    float* __restrict__ t, float* __restrict__ stats) {
  int c = threadIdx.x & 127;
  int half = threadIdx.x >> 7;
  float b = be1[c];
  float psum = 0.f, psq = 0.f;
  for (int n = blockIdx.x * 2 + half; n < NN; n += gridDim.x * 2) {
    const float* xr = x + (size_t)n * XD;
    float v = b;
#pragma unroll
    for (int k = 0; k < XD; ++k) v = fmaf(xr[k], We1[k * HID + c], v);
    t[(size_t)n * HID + c] = v;
    psum += v; psq += v * v;
  }
  __shared__ float s0[256], s1[256];
  s0[threadIdx.x] = psum; s1[threadIdx.x] = psq;
  __syncthreads();
  if (threadIdx.x < 128) {
    atomicAdd(&stats[threadIdx.x], s0[threadIdx.x] + s0[threadIdx.x + 128]);
    atomicAdd(&stats[128 + threadIdx.x], s1[threadIdx.x] + s1[threadIdx.x + 128]);
  }
}

__global__ __launch_bounds__(128) void k_bn_fin(const float* __restrict__ gamma,
    const float* __restrict__ beta, float* __restrict__ stats, int C, float invn) {
  int c = threadIdx.x;
  if (c < C) {
    float mean = stats[c] * invn;
    float var = stats[128 + c] * invn - mean * mean;
    float a = gamma[c] * rsqrtf(var + EPSF);
    stats[256 + c] = a;
    stats[384 + c] = beta[c] - mean * a;
  }
}

__global__ __launch_bounds__(128) void k_enc2(const float* __restrict__ t,
    const float* __restrict__ stats, const float* __restrict__ We2,
    const float* __restrict__ be2, float* __restrict__ h) {
  __shared__ float r[HID];
  int c = threadIdx.x;
  float a = stats[256 + c], b = stats[384 + c];
  float bias = be2[c];
  for (int n = blockIdx.x; n < NN; n += gridDim.x) {
    float v = fmaf(t[(size_t)n * HID + c], a, b);
    r[c] = fmaxf(v, 0.f);
    __syncthreads();
    float acc = bias;
#pragma unroll 8
    for (int k = 0; k < HID; ++k) acc = fmaf(r[k], We2[k * HID + c], acc);
    h[(size_t)n * HID + c] = acc;
    __syncthreads();
  }
}

// ================= gaussian smearing (ea output) ===========================
__global__ __launch_bounds__(256) void k_smear(const float* __restrict__ eattr,
    float* __restrict__ ea) {
  int idx = blockIdx.x * 256 + threadIdx.x;
  if (idx >= NE * NG) return;
  int e = idx / NG;
  int g = idx - e * NG;
  float ax = eattr[(size_t)e * 3], ay = eattr[(size_t)e * 3 + 1], az = eattr[(size_t)e * 3 + 2];
  float d = sqrtf(ax * ax + ay * ay + az * az);
  float off = (10.0f / 49.0f) * (float)g;
  float z = d - off;
  ea[idx] = __expf(-12.005f * z * z);
}

// ================= edge kernel v6: table-lerp gather/scatter ===============
// Block = 16 dest nodes, 512 threads = 8 waves; wave w owns cols [16w,16w+16)
// (private agg stripe -> no cross-wave races). Per 4-edge step per wave:
// broadcast meta from LDS, 2 tab loads + 1 h load per lane, lerp, mul,
// single-dst shfl fast path / LDS-atomic fallback.
__global__ __launch_bounds__(512) void k_edge6(
    const int* __restrict__ idxperm, const float* __restrict__ fracperm,
    const int* __restrict__ rowperm, const int* __restrict__ destperm,
    const int* __restrict__ rowptr, const float* __restrict__ h,
    const float* __restrict__ tab, float* __restrict__ agg) {
#define CHK 128
  __shared__ float agg_s[16][HID];
  __shared__ int   idx_s[CHK];
  __shared__ float frac_s[CHK];
  __shared__ int   row_s[CHK];
  __shared__ int   dst_s[CHK];

  const int tid = threadIdx.x;
  const int lane = tid & 63;
  const int w = tid >> 6;
  const int lm = lane & 15;
  const int eg = lane >> 4;
  const int cc = w * 16 + lm;
  const int nb = blockIdx.x * 16;
  const int eS = rowptr[nb], eE = rowptr[nb + 16];

  for (int i = tid; i < 16 * HID; i += 512) ((float*)agg_s)[i] = 0.f;

  for (int ch = eS; ch < eE; ch += CHK) {
    __syncthreads();  // agg init done (first) / prev chunk meta consumed
    const int nval = min(CHK, eE - ch);
    if (tid < CHK) {
      int p = ch + tid;
      if (tid < nval) {
        idx_s[tid] = idxperm[p];
        frac_s[tid] = fracperm[p];
        row_s[tid] = rowperm[p];
        dst_s[tid] = destperm[p] - nb;
      } else {
        idx_s[tid] = 0; frac_s[tid] = 0.f; row_s[tid] = 0; dst_s[tid] = -1;
      }
    }
    __syncthreads();
    for (int i0 = 0; i0 < nval; i0 += 4) {
      const int le = i0 + eg;
      const bool valid = le < nval;
      const int lei = valid ? le : (nval - 1);
      const int id = idx_s[lei];
      const float fr = frac_s[lei];
      const int r = row_s[lei];
      const int dst = valid ? dst_s[lei] : -1;
      const float* tr = tab + (size_t)id * HID + cc;
      float w0 = tr[0];
      float w1 = tr[HID];
      float hvv = h[(size_t)r * HID + cc];
      float msg = valid ? fmaf(fr, w1 - w0, w0) * hvv : 0.f;
      int d0 = __shfl(dst, 0);
      int d3 = __shfl(dst, 48);
      if (d0 == d3 && d0 >= 0) {
        float v = msg;
        v += __shfl_xor(v, 16);
        v += __shfl_xor(v, 32);
        if (eg == 0) agg_s[d0][cc] += v;
      } else if (valid) {
        atomicAdd(&agg_s[dst][cc], msg);
      }
    }
  }
  __syncthreads();
  for (int i = tid; i < 16 * 32; i += 512) {
    int le = i >> 5, cj = (i & 31) * 4;
    *(float4*)(agg + (size_t)(nb + le) * HID + cj) = *(const float4*)&agg_s[le][cj];
  }
#undef CHK
}

// ================= MFMA node update: 8 waves x 16 cols, grid-stride ========
__global__ __launch_bounds__(512) void k_node3(
    const float* __restrict__ agg,
    const bf16_t* __restrict__ Wd1Thi, const bf16_t* __restrict__ Wd1Tlo,
    const bf16_t* __restrict__ Wd2Thi, const bf16_t* __restrict__ Wd2Tlo,
    const float* __restrict__ bd1, const float* __restrict__ bd2,
    float* __restrict__ h) {
  __shared__ __align__(16) bf16_t aghi[16][136];
  __shared__ __align__(16) bf16_t aglo[16][136];
  __shared__ __align__(16) bf16_t t1hi[16][136];
  __shared__ __align__(16) bf16_t t1lo[16][136];

  const int tid = threadIdx.x;
  const int lane = tid & 63;
  const int w = tid >> 6;
  const int lm = lane & 15;
  const int lk = lane >> 4;
  const int cc = w * 16 + lm;

  bf16x8 B1[4][2], B2[4][2];
#pragma unroll
  for (int s = 0; s < 4; ++s) {
    int k0 = s * 32 + lk * 8;
    B1[s][0] = *(const bf16x8*)(Wd1Thi + (size_t)cc * 128 + k0);
    B1[s][1] = *(const bf16x8*)(Wd1Tlo + (size_t)cc * 128 + k0);
    B2[s][0] = *(const bf16x8*)(Wd2Thi + (size_t)cc * 128 + k0);
    B2[s][1] = *(const bf16x8*)(Wd2Tlo + (size_t)cc * 128 + k0);
  }
  const float bias1 = bd1[cc];
  const float bias2 = bd2[cc];

  for (int tile = blockIdx.x; tile < NN / 16; tile += gridDim.x) {
    const int nb = tile * 16;
    __syncthreads();
    for (int idx = tid; idx < 16 * 128; idx += 512) {
      int r = idx >> 7, k = idx & 127;
      float v = agg[(size_t)(nb + r) * HID + k];
      bf16_t hv = (bf16_t)v;
      aghi[r][k] = hv;
      aglo[r][k] = (bf16_t)(v - (float)hv);
    }
    __syncthreads();
    f32x4 acc1 = {0.f, 0.f, 0.f, 0.f};
#pragma unroll
    for (int s = 0; s < 4; ++s) {
      bf16x8 Ahi = *(const bf16x8*)&aghi[lm][s * 32 + lk * 8];
      bf16x8 Alo = *(const bf16x8*)&aglo[lm][s * 32 + lk * 8];
      acc1 = __builtin_amdgcn_mfma_f32_16x16x32_bf16(Ahi, B1[s][0], acc1, 0, 0, 0);
      acc1 = __builtin_amdgcn_mfma_f32_16x16x32_bf16(Ahi, B1[s][1], acc1, 0, 0, 0);
      acc1 = __builtin_amdgcn_mfma_f32_16x16x32_bf16(Alo, B1[s][0], acc1, 0, 0, 0);
    }
#pragma unroll
    for (int j = 0; j < 4; ++j) {
      int r = lk * 4 + j;
      float v = fmaxf(acc1[j] + bias1, 0.f);
      bf16_t hv = (bf16_t)v;
      t1hi[r][cc] = hv;
      t1lo[r][cc] = (bf16_t)(v - (float)hv);
    }
    __syncthreads();
    f32x4 acc2 = {0.f, 0.f, 0.f, 0.f};
#pragma unroll
    for (int s = 0; s < 4; ++s) {
      bf16x8 Ahi = *(const bf16x8*)&t1hi[lm][s * 32 + lk * 8];
      bf16x8 Alo = *(const bf16x8*)&t1lo[lm][s * 32 + lk * 8];
      acc2 = __builtin_amdgcn_mfma_f32_16x16x32_bf16(Ahi, B2[s][0], acc2, 0, 0, 0);
      acc2 = __builtin_amdgcn_mfma_f32_16x16x32_bf16(Ahi, B2[s][1], acc2, 0, 0, 0);
      acc2 = __builtin_amdgcn_mfma_f32_16x16x32_bf16(Alo, B2[s][0], acc2, 0, 0, 0);
    }
#pragma unroll
    for (int j = 0; j < 4; ++j)
      h[(size_t)(nb + lk * 4 + j) * HID + cc] += acc2[j] + bias2;
  }
}

// ================= global MLP ==============================================
__global__ __launch_bounds__(128) void k_global(const float* __restrict__ u,
    const float* __restrict__ Wg1, const float* __restrict__ bg1,
    const float* __restrict__ gg1, const float* __restrict__ btg1,
    const float* __restrict__ Wg2, const float* __restrict__ bg2,
    float* __restrict__ u_p) {
  __shared__ float t_s[NGR][HID];
  int c = threadIdx.x;
  for (int g = 0; g < NGR; ++g) {
    float v = bg1[c];
#pragma unroll
    for (int k = 0; k < GD; ++k) v = fmaf(u[(size_t)g * GD + k], Wg1[k * HID + c], v);
    t_s[g][c] = v;
  }
  float sum = 0.f, sq = 0.f;
  for (int g = 0; g < NGR; ++g) { float v = t_s[g][c]; sum += v; sq += v * v; }
  float mean = sum * (1.f / NGR);
  float var = sq * (1.f / NGR) - mean * mean;
  float a = gg1[c] * rsqrtf(var + EPSF);
  float b = btg1[c] - mean * a;
  for (int g = 0; g < NGR; ++g) t_s[g][c] = fmaxf(fmaf(t_s[g][c], a, b), 0.f);
  __syncthreads();
  for (int g = 0; g < NGR; ++g) {
    float acc = bg2[c];
#pragma unroll 8
    for (int k = 0; k < HID; ++k) acc = fmaf(t_s[g][k], Wg2[k * HID + c], acc);
    u_p[(size_t)g * HID + c] = acc;
  }
}

// ================= shift head ==============================================
__global__ __launch_bounds__(256) void k_shift1(
    const float* __restrict__ h, const float* __restrict__ u_p,
    const int* __restrict__ batch, const float* __restrict__ Ws1,
    const float* __restrict__ bs1, float* __restrict__ t1, float* __restrict__ stats) {
  __shared__ float s_in[16][2 * HID];
  const int c = threadIdx.x & 63;
  const int ng = threadIdx.x >> 6;
  float psum = 0.f, psq = 0.f;
  for (int tile = blockIdx.x; tile < NN / 16; tile += gridDim.x) {
    const int nb = tile * 16;
    for (int i = threadIdx.x; i < 16 * HID; i += 256) {
      int ln = i >> 7, k = i & 127;
      s_in[ln][k] = h[(size_t)(nb + ln) * HID + k];
      s_in[ln][HID + k] = u_p[(size_t)batch[nb + ln] * HID + k];
    }
    __syncthreads();
    float acc[4];
#pragma unroll
    for (int j = 0; j < 4; ++j) acc[j] = bs1[c];
    for (int k = 0; k < 2 * HID; ++k) {
      float w = Ws1[k * SH + c];
#pragma unroll
      for (int j = 0; j < 4; ++j) acc[j] = fmaf(s_in[ng * 4 + j][k], w, acc[j]);
    }
#pragma unroll
    for (int j = 0; j < 4; ++j) {
      t1[(size_t)(nb + ng * 4 + j) * SH + c] = acc[j];
      psum += acc[j]; psq += acc[j] * acc[j];
    }
    __syncthreads();
  }
  __shared__ float rs[256], rq[256];
  rs[threadIdx.x] = psum; rq[threadIdx.x] = psq;
  __syncthreads();
  if (threadIdx.x < 64) {
    int c2 = threadIdx.x;
    atomicAdd(&stats[c2], rs[c2] + rs[c2 + 64] + rs[c2 + 128] + rs[c2 + 192]);
    atomicAdd(&stats[128 + c2], rq[c2] + rq[c2 + 64] + rq[c2 + 128] + rq[c2 + 192]);
  }
}

__global__ __launch_bounds__(256) void k_shift2(
    const float* __restrict__ t1, float* __restrict__ stats,
    const float* __restrict__ Ws2, const float* __restrict__ bs2,
    float* __restrict__ t2) {
  __shared__ float r_s[16][SH];
  const int c = threadIdx.x & 63;
  const int ng = threadIdx.x >> 6;
  float psum = 0.f, psq = 0.f;
  for (int tile = blockIdx.x; tile < NN / 16; tile += gridDim.x) {
    const int nb = tile * 16;
    for (int i = threadIdx.x; i < 16 * SH; i += 256) {
      int ln = i >> 6, k = i & 63;
      float v = fmaf(t1[(size_t)(nb + ln) * SH + k], stats[256 + k], stats[384 + k]);
      r_s[ln][k] = fmaxf(v, 0.f);
    }
    __syncthreads();
    float acc[4];
#pragma unroll
    for (int j = 0; j < 4; ++j) acc[j] = bs2[c];
    for (int k = 0; k < SH; ++k) {
      float w = Ws2[k * SH + c];
#pragma unroll
      for (int j = 0; j < 4; ++j) acc[j] = fmaf(r_s[ng * 4 + j][k], w, acc[j]);
    }
#pragma unroll
    for (int j = 0; j < 4; ++j) {
      t2[(size_t)(nb + ng * 4 + j) * SH + c] = acc[j];
      psum += acc[j]; psq += acc[j] * acc[j];
    }
    __syncthreads();
  }
  __shared__ float rs[256], rq[256];
  rs[threadIdx.x] = psum; rq[threadIdx.x] = psq;
  __syncthreads();
  if (threadIdx.x < 64) {
    int c2 = threadIdx.x;
    atomicAdd(&stats[c2], rs[c2] + rs[c2 + 64] + rs[c2 + 128] + rs[c2 + 192]);
    atomicAdd(&stats[128 + c2], rq[c2] + rq[c2 + 64] + rq[c2 + 128] + rq[c2 + 192]);
  }
}

__global__ __launch_bounds__(256) void k_shift3(
    const float* __restrict__ t2, const float* __restrict__ stats,
    const float* __restrict__ Ws3, const float* __restrict__ bs3,
    float* __restrict__ shifts) {
  int lane = threadIdx.x & 63;
  int n = blockIdx.x * 4 + (threadIdx.x >> 6);
  if (n >= NN) return;
  float a = stats[256 + lane], b = stats[384 + lane];
  float r = fmaxf(fmaf(t2[(size_t)n * SH + lane], a, b), 0.f);
  float v = r * Ws3[lane];
#pragma unroll
  for (int off = 32; off; off >>= 1) v += __shfl_down(v, off);
  if (lane == 0) shifts[n] = v + bs3[0];
}

extern "C" void kernel_launch(void* const* d_in, const int* in_sizes, int n_in,
                              void* d_out, int out_size, void* d_ws, size_t ws_size,
                              hipStream_t stream) {
  const float* x     = (const float*)d_in[0];
  const int*   ei    = (const int*)d_in[1];
  const float* eattr = (const float*)d_in[2];
  const int*   batch = (const int*)d_in[3];
  const float* u     = (const float*)d_in[4];
  const float* We1 = (const float*)d_in[5];  const float* be1 = (const float*)d_in[6];
  const float* ge1 = (const float*)d_in[7];  const float* bte1 = (const float*)d_in[8];
  const float* We2 = (const float*)d_in[9];  const float* be2 = (const float*)d_in[10];
  const float* Wf1 = (const float*)d_in[11]; const float* bf1 = (const float*)d_in[12];
  const float* Wf2 = (const float*)d_in[13]; const float* bf2 = (const float*)d_in[14];
  const float* Wd1 = (const float*)d_in[15]; const float* bd1 = (const float*)d_in[16];
  const float* Wd2 = (const float*)d_in[17]; const float* bd2 = (const float*)d_in[18];
  const float* Wg1 = (const float*)d_in[19]; const float* bg1 = (const float*)d_in[20];
  const float* gg1 = (const float*)d_in[21]; const float* btg1 = (const float*)d_in[22];
  const float* Wg2 = (const float*)d_in[23]; const float* bg2 = (const float*)d_in[24];
  const float* Ws1 = (const float*)d_in[25]; const float* bs1 = (const float*)d_in[26];
  const float* gs1 = (const float*)d_in[27]; const float* bts1 = (const float*)d_in[28];
  const float* Ws2 = (const float*)d_in[29]; const float* bs2 = (const float*)d_in[30];
  const float* gs2 = (const float*)d_in[31]; const float* bts2 = (const float*)d_in[32];
  const float* Ws3 = (const float*)d_in[33]; const float* bs3 = (const float*)d_in[34];

  float* out    = (float*)d_out;
  float* shifts = out;                    // [NN]
  float* h      = out + NN;               // [NN,HID]
  float* ea     = out + NN + NN * HID;    // [NE,NG]
  float* u_p    = out + NN + NN * HID + (size_t)NE * NG;  // [NGR,HID]

  // workspace layout
  char* wsb = (char*)d_ws;
  size_t off = 0;
  auto alloc = [&](size_t bytes) { void* p = wsb + off; off = (off + bytes + 255) & ~(size_t)255; return p; };
  float*  stats    = (float*)alloc(512 * sizeof(float));
  int*    hist     = (int*)alloc((size_t)NN * sizeof(int));
  int*    rowptr   = (int*)alloc((size_t)(NN + 1) * sizeof(int));
  int*    perm     = (int*)alloc((size_t)NE * sizeof(int));
  int*    idxperm  = (int*)alloc((size_t)NE * sizeof(int));
  float*  fracperm = (float*)alloc((size_t)NE * sizeof(float));
  int*    rowperm  = (int*)alloc((size_t)NE * sizeof(int));
  int*    destperm = (int*)alloc((size_t)NE * sizeof(int));
  float*  tab      = (float*)alloc((size_t)NL * TBL * HID * sizeof(float));
  bf16_t* Wd1Thi   = (bf16_t*)alloc((size_t)NL * 128 * 128 * sizeof(bf16_t));
  bf16_t* Wd1Tlo   = (bf16_t*)alloc((size_t)NL * 128 * 128 * sizeof(bf16_t));
  bf16_t* Wd2Thi   = (bf16_t*)alloc((size_t)NL * 128 * 128 * sizeof(bf16_t));
  bf16_t* Wd2Tlo   = (bf16_t*)alloc((size_t)NL * 128 * 128 * sizeof(bf16_t));
  float*  buf1     = (float*)alloc((size_t)NN * HID * sizeof(float));
  float* t1 = buf1;
  float* t2 = buf1 + (size_t)NN * SH;

  const int* row = ei;        // source j
  const int* col = ei + NE;   // target i

  // ---- CSR build + permuted edge data + table + node-weight prep
  hipMemsetAsync(hist, 0, (size_t)NN * sizeof(int), stream);
  k_hist<<<512, 256, 0, stream>>>(col, hist);
  k_scan<<<1, 1024, 0, stream>>>(hist, rowptr);
  k_scatter<<<512, 256, 0, stream>>>(col, hist, perm);
  k_preedge<<<(NE + 255) / 256, 256, 0, stream>>>(perm, eattr, row, col,
                                                  idxperm, fracperm, rowperm, destperm);
  k_tabbuild<<<NL * TBL, 128, 0, stream>>>(Wf1, bf1, Wf2, bf2, tab);
  k_prepw<<<(2 * NL * 128 * 128 + 255) / 256, 256, 0, stream>>>(
      Wd1, Wd2, Wd1Thi, Wd1Tlo, Wd2Thi, Wd2Tlo);

  // ---- node encoder
  hipMemsetAsync(stats, 0, 256 * sizeof(float), stream);
  k_enc1<<<512, 256, 0, stream>>>(x, We1, be1, buf1, stats);
  k_bn_fin<<<1, 128, 0, stream>>>(ge1, bte1, stats, 128, 1.f / NN);
  k_enc2<<<2048, 128, 0, stream>>>(buf1, stats, We2, be2, h);

  // ---- gaussian smearing (ea output)
  k_smear<<<(NE * NG + 255) / 256, 256, 0, stream>>>(eattr, ea);

  // ---- interaction layers
  for (int l = 0; l < NL; ++l) {
    k_edge6<<<NN / 16, 512, 0, stream>>>(
        idxperm, fracperm, rowperm, destperm, rowptr, h,
        tab + (size_t)l * TBL * HID, buf1);
    k_node3<<<640, 512, 0, stream>>>(
        buf1,
        Wd1Thi + (size_t)l * 128 * 128, Wd1Tlo + (size_t)l * 128 * 128,
        Wd2Thi + (size_t)l * 128 * 128, Wd2Tlo + (size_t)l * 128 * 128,
        bd1 + (size_t)l * HID, bd2 + (size_t)l * HID, h);
  }

  // ---- global MLP
  k_global<<<1, 128, 0, stream>>>(u, Wg1, bg1, gg1, btg1, Wg2, bg2, u_p);

  // ---- shift head
  hipMemsetAsync(stats, 0, 256 * sizeof(float), stream);
  k_shift1<<<1024, 256, 0, stream>>>(h, u_p, batch, Ws1, bs1, t1, stats);
  k_bn_fin<<<1, 128, 0, stream>>>(gs1, bts1, stats, 64, 1.f / NN);
  hipMemsetAsync(stats, 0, 256 * sizeof(float), stream);
  k_shift2<<<1024, 256, 0, stream>>>(t1, stats, Ws2, bs2, t2);
  k_bn_fin<<<1, 128, 0, stream>>>(gs2, bts2, stats, 64, 1.f / NN);
  k_shift3<<<(NN + 3) / 4, 256, 0, stream>>>(t2, stats, Ws3, bs3, shifts);
}

// Round 7
// 2248.309 us; speedup vs baseline: 3.1028x; 1.5932x over previous
//
#include <hip/hip_runtime.h>

#define NN 50000
#define NE 1600000
#define NGR 64
#define XD 32
#define HID 128
#define NF 128
#define NG 50
#define GD 16
#define NL 6
#define SH 64
#define EPSF 1e-5f
#define TBL 4096          // filter table knots
#define INVSTEP 320.0f    // 1/step; covers d in [0, 12.8]

typedef __bf16 bf16_t;
typedef bf16_t bf16x8 __attribute__((ext_vector_type(8)));
typedef float f32x4 __attribute__((ext_vector_type(4)));

// ================= CSR build (once; col constant across layers) ============
__global__ __launch_bounds__(256) void k_hist(const int* __restrict__ col,
                                              int* __restrict__ hist) {
  for (int e = blockIdx.x * 256 + threadIdx.x; e < NE; e += gridDim.x * 256)
    atomicAdd(&hist[col[e]], 1);
}

__global__ __launch_bounds__(1024) void k_scan(int* __restrict__ hist,
                                               int* __restrict__ rowptr) {
  const int tid = threadIdx.x;
  const int CH = 49;
  const int base = tid * CH;
  int s = 0;
  for (int i = 0; i < CH; ++i) {
    int idx = base + i;
    if (idx < NN) s += hist[idx];
  }
  __shared__ int part[1024];
  part[tid] = s;
  __syncthreads();
  for (int off = 1; off < 1024; off <<= 1) {
    int v = (tid >= off) ? part[tid - off] : 0;
    __syncthreads();
    part[tid] += v;
    __syncthreads();
  }
  int run = part[tid] - s;
  for (int i = 0; i < CH; ++i) {
    int idx = base + i;
    if (idx < NN) {
      int c = hist[idx];
      rowptr[idx] = run;
      hist[idx] = run;
      run += c;
    }
  }
  if (tid == 0) rowptr[NN] = NE;
}

__global__ __launch_bounds__(256) void k_scatter(const int* __restrict__ col,
                                                 int* __restrict__ cursor,
                                                 int* __restrict__ perm) {
  for (int e = blockIdx.x * 256 + threadIdx.x; e < NE; e += gridDim.x * 256) {
    int pos = atomicAdd(&cursor[col[e]], 1);
    perm[pos] = e;
  }
}

// ================= permuted per-edge meta: (idx, frac, row, dst) ===========
__global__ __launch_bounds__(256) void k_preedge(const int* __restrict__ perm,
    const float* __restrict__ eattr, const int* __restrict__ row,
    const int* __restrict__ col, int4* __restrict__ metap) {
  int p = blockIdx.x * 256 + threadIdx.x;
  if (p < NE) {
    int pe = perm[p];
    float ax = eattr[(size_t)pe * 3], ay = eattr[(size_t)pe * 3 + 1], az = eattr[(size_t)pe * 3 + 2];
    float d = sqrtf(ax * ax + ay * ay + az * az);
    float tt = fminf(d * INVSTEP, (float)(TBL - 2) + 0.999f);
    int id = (int)tt;
    metap[p] = make_int4(id, __float_as_int(tt - (float)id), row[pe], col[pe]);
  }
}

// ================= filter table build: 8 knots / block =====================
__global__ __launch_bounds__(128) void k_tabbuild2(
    const float* __restrict__ Wf1, const float* __restrict__ bf1,
    const float* __restrict__ Wf2, const float* __restrict__ bf2,
    float* __restrict__ tab) {
  const int bid = blockIdx.x;            // 0 .. NL*(TBL/8)-1
  const int l = bid / (TBL / 8);
  const int t0 = (bid - l * (TBL / 8)) * 8;
  const int c = threadIdx.x;
  __shared__ float g_s[8][NG];
  __shared__ float f1_s[8][NF];
  for (int i = c; i < 8 * NG; i += 128) {
    int kk = i / NG, g = i - kk * NG;
    float d = (float)(t0 + kk) * (1.0f / INVSTEP);
    float z = d - 0.2040816327f * (float)g;
    g_s[kk][g] = expf(-12.005f * z * z);
  }
  __syncthreads();
  const float* W1 = Wf1 + (size_t)l * NG * NF;
  float f1r[8];
#pragma unroll
  for (int kk = 0; kk < 8; ++kk) f1r[kk] = bf1[(size_t)l * NF + c];
  for (int g = 0; g < NG; ++g) {
    float w = W1[g * NF + c];
#pragma unroll
    for (int kk = 0; kk < 8; ++kk) f1r[kk] = fmaf(g_s[kk][g], w, f1r[kk]);
  }
#pragma unroll
  for (int kk = 0; kk < 8; ++kk) f1_s[kk][c] = fmaxf(f1r[kk], 0.f);
  __syncthreads();
  const float* W2 = Wf2 + (size_t)l * NF * NF;
  float outr[8];
#pragma unroll
  for (int kk = 0; kk < 8; ++kk) outr[kk] = bf2[(size_t)l * NF + c];
  for (int k = 0; k < NF; ++k) {
    float w = W2[k * NF + c];
#pragma unroll
    for (int kk = 0; kk < 8; ++kk) outr[kk] = fmaf(f1_s[kk][k], w, outr[kk]);
  }
#pragma unroll
  for (int kk = 0; kk < 8; ++kk)
    tab[((size_t)l * TBL + t0 + kk) * NF + c] = outr[kk];
}

// ================= pack table: u32 = (bf16 T[t], bf16 T[t+1]) ==============
__global__ __launch_bounds__(256) void k_tabpack(const float* __restrict__ tab,
    unsigned int* __restrict__ tabp) {
  int idx = blockIdx.x * 256 + threadIdx.x;
  if (idx < NL * TBL * HID) {
    int c = idx & (HID - 1);
    int t = (idx >> 7) & (TBL - 1);
    int l = idx >> 19;
    int tn = min(t + 1, TBL - 1);
    float w0 = tab[idx];
    float w1 = tab[((size_t)l * TBL + tn) * HID + c];
    unsigned short a = __builtin_bit_cast(unsigned short, (bf16_t)w0);
    unsigned short b = __builtin_bit_cast(unsigned short, (bf16_t)w1);
    tabp[idx] = (unsigned int)a | ((unsigned int)b << 16);
  }
}

// ================= weight prep for node MLP (transpose + split hi/lo) ======
__global__ __launch_bounds__(256) void k_prepw(const float* __restrict__ Wd1,
    const float* __restrict__ Wd2,
    bf16_t* __restrict__ Wd1Thi, bf16_t* __restrict__ Wd1Tlo,
    bf16_t* __restrict__ Wd2Thi, bf16_t* __restrict__ Wd2Tlo) {
  const int S1 = NL * 128 * 128;
  int idx = blockIdx.x * 256 + threadIdx.x;
  if (idx < 2 * S1) {
    int which = idx / S1;  // 0: Wd1, 1: Wd2
    int jj = idx - which * S1;
    int l = jj / (128 * 128);
    int r = jj - l * (128 * 128);
    int c = r >> 7, k = r & 127;
    const float* W = (which == 0) ? Wd1 : Wd2;
    float v = W[(size_t)l * 128 * 128 + (size_t)k * 128 + c];
    bf16_t hv = (bf16_t)v;
    bf16_t lv = (bf16_t)(v - (float)hv);
    if (which == 0) { Wd1Thi[jj] = hv; Wd1Tlo[jj] = lv; }
    else            { Wd2Thi[jj] = hv; Wd2Tlo[jj] = lv; }
  }
}

// ================= node encoder ============================================
__global__ __launch_bounds__(256) void k_enc1(const float* __restrict__ x,
    const float* __restrict__ We1, const float* __restrict__ be1,
    float* __restrict__ t, float* __restrict__ stats) {
  int c = threadIdx.x & 127;
  int half = threadIdx.x >> 7;
  float b = be1[c];
  float psum = 0.f, psq = 0.f;
  for (int n = blockIdx.x * 2 + half; n < NN; n += gridDim.x * 2) {
    const float* xr = x + (size_t)n * XD;
    float v = b;
#pragma unroll
    for (int k = 0; k < XD; ++k) v = fmaf(xr[k], We1[k * HID + c], v);
    t[(size_t)n * HID + c] = v;
    psum += v; psq += v * v;
  }
  __shared__ float s0[256], s1[256];
  s0[threadIdx.x] = psum; s1[threadIdx.x] = psq;
  __syncthreads();
  if (threadIdx.x < 128) {
    atomicAdd(&stats[threadIdx.x], s0[threadIdx.x] + s0[threadIdx.x + 128]);
    atomicAdd(&stats[128 + threadIdx.x], s1[threadIdx.x] + s1[threadIdx.x + 128]);
  }
}

__global__ __launch_bounds__(128) void k_bn_fin(const float* __restrict__ gamma,
    const float* __restrict__ beta, float* __restrict__ stats, int C, float invn) {
  int c = threadIdx.x;
  if (c < C) {
    float mean = stats[c] * invn;
    float var = stats[128 + c] * invn - mean * mean;
    float a = gamma[c] * rsqrtf(var + EPSF);
    stats[256 + c] = a;
    stats[384 + c] = beta[c] - mean * a;
  }
}

__global__ __launch_bounds__(128) void k_enc2(const float* __restrict__ t,
    const float* __restrict__ stats, const float* __restrict__ We2,
    const float* __restrict__ be2, float* __restrict__ h) {
  __shared__ float r[HID];
  int c = threadIdx.x;
  float a = stats[256 + c], b = stats[384 + c];
  float bias = be2[c];
  for (int n = blockIdx.x; n < NN; n += gridDim.x) {
    float v = fmaf(t[(size_t)n * HID + c], a, b);
    r[c] = fmaxf(v, 0.f);
    __syncthreads();
    float acc = bias;
#pragma unroll 8
    for (int k = 0; k < HID; ++k) acc = fmaf(r[k], We2[k * HID + c], acc);
    h[(size_t)n * HID + c] = acc;
    __syncthreads();
  }
}

// ================= gaussian smearing (ea output) ===========================
__global__ __launch_bounds__(256) void k_smear(const float* __restrict__ eattr,
    float* __restrict__ ea) {
  int idx = blockIdx.x * 256 + threadIdx.x;
  if (idx >= NE * NG) return;
  int e = idx / NG;
  int g = idx - e * NG;
  float ax = eattr[(size_t)e * 3], ay = eattr[(size_t)e * 3 + 1], az = eattr[(size_t)e * 3 + 2];
  float d = sqrtf(ax * ax + ay * ay + az * az);
  float off = (10.0f / 49.0f) * (float)g;
  float z = d - off;
  ea[idx] = __expf(-12.005f * z * z);
}

// ================= edge kernel v7 ==========================================
// Block = 16 dest nodes, 256 threads = 4 waves. Lane owns cols [2*lane,
// 2*lane+1]; wave covers all 128 cols of one edge; the 4 waves split the
// block's CSR range. Register run-accumulation over dest-sorted edges; rare
// LDS-atomic flush at run/range boundaries. 4x unrolled, loads hoisted.
__global__ __launch_bounds__(256) void k_edge7(
    const int4* __restrict__ metap, const int* __restrict__ rowptr,
    const float* __restrict__ h, const unsigned int* __restrict__ tabp,
    float* __restrict__ agg) {
  __shared__ float agg_s[16][HID];
  const int tid = threadIdx.x;
  const int lane = tid & 63;
  const int w = tid >> 6;
  const int c0 = lane * 2;
  const int nb = blockIdx.x * 16;
  const int eS = rowptr[nb], eE = rowptr[nb + 16];

  for (int i = tid; i < 16 * HID; i += 256) ((float*)agg_s)[i] = 0.f;
  __syncthreads();

  const int Q = (eE - eS + 3) >> 2;
  int e = eS + w * Q;
  const int wE = min(e + Q, eE);

  float acc0 = 0.f, acc1 = 0.f;
  int cur = -1;

  auto body = [&](const int4& m, const float2& hv, const uint2& uv) {
    float fr = __int_as_float(m.y);
    int dst = m.w - nb;
    float w0a = __uint_as_float((uv.x & 0xffffu) << 16);
    float w1a = __uint_as_float(uv.x & 0xffff0000u);
    float w0b = __uint_as_float((uv.y & 0xffffu) << 16);
    float w1b = __uint_as_float(uv.y & 0xffff0000u);
    float ma = fmaf(fr, w1a - w0a, w0a) * hv.x;
    float mb = fmaf(fr, w1b - w0b, w0b) * hv.y;
    if (dst != cur) {
      if (cur >= 0) {
        atomicAdd(&agg_s[cur][c0], acc0);
        atomicAdd(&agg_s[cur][c0 + 1], acc1);
      }
      cur = dst; acc0 = ma; acc1 = mb;
    } else {
      acc0 += ma; acc1 += mb;
    }
  };

  for (; e + 4 <= wE; e += 4) {
    int4 m0 = metap[e], m1 = metap[e + 1], m2 = metap[e + 2], m3 = metap[e + 3];
    float2 h0 = *(const float2*)(h + (size_t)m0.z * HID + c0);
    float2 h1 = *(const float2*)(h + (size_t)m1.z * HID + c0);
    float2 h2 = *(const float2*)(h + (size_t)m2.z * HID + c0);
    float2 h3 = *(const float2*)(h + (size_t)m3.z * HID + c0);
    uint2 t0 = *(const uint2*)(tabp + (size_t)m0.x * HID + c0);
    uint2 t1 = *(const uint2*)(tabp + (size_t)m1.x * HID + c0);
    uint2 t2 = *(const uint2*)(tabp + (size_t)m2.x * HID + c0);
    uint2 t3 = *(const uint2*)(tabp + (size_t)m3.x * HID + c0);
    body(m0, h0, t0); body(m1, h1, t1); body(m2, h2, t2); body(m3, h3, t3);
  }
  for (; e < wE; ++e) {
    int4 m = metap[e];
    float2 hv = *(const float2*)(h + (size_t)m.z * HID + c0);
    uint2 uv = *(const uint2*)(tabp + (size_t)m.x * HID + c0);
    body(m, hv, uv);
  }
  if (cur >= 0) {
    atomicAdd(&agg_s[cur][c0], acc0);
    atomicAdd(&agg_s[cur][c0 + 1], acc1);
  }
  __syncthreads();
  for (int i = tid; i < 16 * 32; i += 256) {
    int le = i >> 5, cj = (i & 31) * 4;
    *(float4*)(agg + (size_t)(nb + le) * HID + cj) = *(const float4*)&agg_s[le][cj];
  }
}

// ================= MFMA node update: 8 waves x 16 cols, grid-stride ========
__global__ __launch_bounds__(512) void k_node3(
    const float* __restrict__ agg,
    const bf16_t* __restrict__ Wd1Thi, const bf16_t* __restrict__ Wd1Tlo,
    const bf16_t* __restrict__ Wd2Thi, const bf16_t* __restrict__ Wd2Tlo,
    const float* __restrict__ bd1, const float* __restrict__ bd2,
    float* __restrict__ h) {
  __shared__ __align__(16) bf16_t aghi[16][136];
  __shared__ __align__(16) bf16_t aglo[16][136];
  __shared__ __align__(16) bf16_t t1hi[16][136];
  __shared__ __align__(16) bf16_t t1lo[16][136];

  const int tid = threadIdx.x;
  const int lane = tid & 63;
  const int w = tid >> 6;
  const int lm = lane & 15;
  const int lk = lane >> 4;
  const int cc = w * 16 + lm;

  bf16x8 B1[4][2], B2[4][2];
#pragma unroll
  for (int s = 0; s < 4; ++s) {
    int k0 = s * 32 + lk * 8;
    B1[s][0] = *(const bf16x8*)(Wd1Thi + (size_t)cc * 128 + k0);
    B1[s][1] = *(const bf16x8*)(Wd1Tlo + (size_t)cc * 128 + k0);
    B2[s][0] = *(const bf16x8*)(Wd2Thi + (size_t)cc * 128 + k0);
    B2[s][1] = *(const bf16x8*)(Wd2Tlo + (size_t)cc * 128 + k0);
  }
  const float bias1 = bd1[cc];
  const float bias2 = bd2[cc];

  for (int tile = blockIdx.x; tile < NN / 16; tile += gridDim.x) {
    const int nb = tile * 16;
    __syncthreads();
    for (int idx = tid; idx < 16 * 128; idx += 512) {
      int r = idx >> 7, k = idx & 127;
      float v = agg[(size_t)(nb + r) * HID + k];
      bf16_t hv = (bf16_t)v;
      aghi[r][k] = hv;
      aglo[r][k] = (bf16_t)(v - (float)hv);
    }
    __syncthreads();
    f32x4 acc1 = {0.f, 0.f, 0.f, 0.f};
#pragma unroll
    for (int s = 0; s < 4; ++s) {
      bf16x8 Ahi = *(const bf16x8*)&aghi[lm][s * 32 + lk * 8];
      bf16x8 Alo = *(const bf16x8*)&aglo[lm][s * 32 + lk * 8];
      acc1 = __builtin_amdgcn_mfma_f32_16x16x32_bf16(Ahi, B1[s][0], acc1, 0, 0, 0);
      acc1 = __builtin_amdgcn_mfma_f32_16x16x32_bf16(Ahi, B1[s][1], acc1, 0, 0, 0);
      acc1 = __builtin_amdgcn_mfma_f32_16x16x32_bf16(Alo, B1[s][0], acc1, 0, 0, 0);
    }
#pragma unroll
    for (int j = 0; j < 4; ++j) {
      int r = lk * 4 + j;
      float v = fmaxf(acc1[j] + bias1, 0.f);
      bf16_t hv = (bf16_t)v;
      t1hi[r][cc] = hv;
      t1lo[r][cc] = (bf16_t)(v - (float)hv);
    }
    __syncthreads();
    f32x4 acc2 = {0.f, 0.f, 0.f, 0.f};
#pragma unroll
    for (int s = 0; s < 4; ++s) {
      bf16x8 Ahi = *(const bf16x8*)&t1hi[lm][s * 32 + lk * 8];
      bf16x8 Alo = *(const bf16x8*)&t1lo[lm][s * 32 + lk * 8];
      acc2 = __builtin_amdgcn_mfma_f32_16x16x32_bf16(Ahi, B2[s][0], acc2, 0, 0, 0);
      acc2 = __builtin_amdgcn_mfma_f32_16x16x32_bf16(Ahi, B2[s][1], acc2, 0, 0, 0);
      acc2 = __builtin_amdgcn_mfma_f32_16x16x32_bf16(Alo, B2[s][0], acc2, 0, 0, 0);
    }
#pragma unroll
    for (int j = 0; j < 4; ++j)
      h[(size_t)(nb + lk * 4 + j) * HID + cc] += acc2[j] + bias2;
  }
}

// ================= global MLP ==============================================
__global__ __launch_bounds__(128) void k_global(const float* __restrict__ u,
    const float* __restrict__ Wg1, const float* __restrict__ bg1,
    const float* __restrict__ gg1, const float* __restrict__ btg1,
    const float* __restrict__ Wg2, const float* __restrict__ bg2,
    float* __restrict__ u_p) {
  __shared__ float t_s[NGR][HID];
  int c = threadIdx.x;
  for (int g = 0; g < NGR; ++g) {
    float v = bg1[c];
#pragma unroll
    for (int k = 0; k < GD; ++k) v = fmaf(u[(size_t)g * GD + k], Wg1[k * HID + c], v);
    t_s[g][c] = v;
  }
  float sum = 0.f, sq = 0.f;
  for (int g = 0; g < NGR; ++g) { float v = t_s[g][c]; sum += v; sq += v * v; }
  float mean = sum * (1.f / NGR);
  float var = sq * (1.f / NGR) - mean * mean;
  float a = gg1[c] * rsqrtf(var + EPSF);
  float b = btg1[c] - mean * a;
  for (int g = 0; g < NGR; ++g) t_s[g][c] = fmaxf(fmaf(t_s[g][c], a, b), 0.f);
  __syncthreads();
  for (int g = 0; g < NGR; ++g) {
    float acc = bg2[c];
#pragma unroll 8
    for (int k = 0; k < HID; ++k) acc = fmaf(t_s[g][k], Wg2[k * HID + c], acc);
    u_p[(size_t)g * HID + c] = acc;
  }
}

// ================= shift head ==============================================
__global__ __launch_bounds__(256) void k_shift1(
    const float* __restrict__ h, const float* __restrict__ u_p,
    const int* __restrict__ batch, const float* __restrict__ Ws1,
    const float* __restrict__ bs1, float* __restrict__ t1, float* __restrict__ stats) {
  __shared__ float s_in[16][2 * HID];
  const int c = threadIdx.x & 63;
  const int ng = threadIdx.x >> 6;
  float psum = 0.f, psq = 0.f;
  for (int tile = blockIdx.x; tile < NN / 16; tile += gridDim.x) {
    const int nb = tile * 16;
    for (int i = threadIdx.x; i < 16 * HID; i += 256) {
      int ln = i >> 7, k = i & 127;
      s_in[ln][k] = h[(size_t)(nb + ln) * HID + k];
      s_in[ln][HID + k] = u_p[(size_t)batch[nb + ln] * HID + k];
    }
    __syncthreads();
    float acc[4];
#pragma unroll
    for (int j = 0; j < 4; ++j) acc[j] = bs1[c];
    for (int k = 0; k < 2 * HID; ++k) {
      float w = Ws1[k * SH + c];
#pragma unroll
      for (int j = 0; j < 4; ++j) acc[j] = fmaf(s_in[ng * 4 + j][k], w, acc[j]);
    }
#pragma unroll
    for (int j = 0; j < 4; ++j) {
      t1[(size_t)(nb + ng * 4 + j) * SH + c] = acc[j];
      psum += acc[j]; psq += acc[j] * acc[j];
    }
    __syncthreads();
  }
  __shared__ float rs[256], rq[256];
  rs[threadIdx.x] = psum; rq[threadIdx.x] = psq;
  __syncthreads();
  if (threadIdx.x < 64) {
    int c2 = threadIdx.x;
    atomicAdd(&stats[c2], rs[c2] + rs[c2 + 64] + rs[c2 + 128] + rs[c2 + 192]);
    atomicAdd(&stats[128 + c2], rq[c2] + rq[c2 + 64] + rq[c2 + 128] + rq[c2 + 192]);
  }
}

__global__ __launch_bounds__(256) void k_shift2(
    const float* __restrict__ t1, float* __restrict__ stats,
    const float* __restrict__ Ws2, const float* __restrict__ bs2,
    float* __restrict__ t2) {
  __shared__ float r_s[16][SH];
  const int c = threadIdx.x & 63;
  const int ng = threadIdx.x >> 6;
  float psum = 0.f, psq = 0.f;
  for (int tile = blockIdx.x; tile < NN / 16; tile += gridDim.x) {
    const int nb = tile * 16;
    for (int i = threadIdx.x; i < 16 * SH; i += 256) {
      int ln = i >> 6, k = i & 63;
      float v = fmaf(t1[(size_t)(nb + ln) * SH + k], stats[256 + k], stats[384 + k]);
      r_s[ln][k] = fmaxf(v, 0.f);
    }
    __syncthreads();
    float acc[4];
#pragma unroll
    for (int j = 0; j < 4; ++j) acc[j] = bs2[c];
    for (int k = 0; k < SH; ++k) {
      float w = Ws2[k * SH + c];
#pragma unroll
      for (int j = 0; j < 4; ++j) acc[j] = fmaf(r_s[ng * 4 + j][k], w, acc[j]);
    }
#pragma unroll
    for (int j = 0; j < 4; ++j) {
      t2[(size_t)(nb + ng * 4 + j) * SH + c] = acc[j];
      psum += acc[j]; psq += acc[j] * acc[j];
    }
    __syncthreads();
  }
  __shared__ float rs[256], rq[256];
  rs[threadIdx.x] = psum; rq[threadIdx.x] = psq;
  __syncthreads();
  if (threadIdx.x < 64) {
    int c2 = threadIdx.x;
    atomicAdd(&stats[c2], rs[c2] + rs[c2 + 64] + rs[c2 + 128] + rs[c2 + 192]);
    atomicAdd(&stats[128 + c2], rq[c2] + rq[c2 + 64] + rq[c2 + 128] + rq[c2 + 192]);
  }
}

__global__ __launch_bounds__(256) void k_shift3(
    const float* __restrict__ t2, const float* __restrict__ stats,
    const float* __restrict__ Ws3, const float* __restrict__ bs3,
    float* __restrict__ shifts) {
  int lane = threadIdx.x & 63;
  int n = blockIdx.x * 4 + (threadIdx.x >> 6);
  if (n >= NN) return;
  float a = stats[256 + lane], b = stats[384 + lane];
  float r = fmaxf(fmaf(t2[(size_t)n * SH + lane], a, b), 0.f);
  float v = r * Ws3[lane];
#pragma unroll
  for (int off = 32; off; off >>= 1) v += __shfl_down(v, off);
  if (lane == 0) shifts[n] = v + bs3[0];
}

extern "C" void kernel_launch(void* const* d_in, const int* in_sizes, int n_in,
                              void* d_out, int out_size, void* d_ws, size_t ws_size,
                              hipStream_t stream) {
  const float* x     = (const float*)d_in[0];
  const int*   ei    = (const int*)d_in[1];
  const float* eattr = (const float*)d_in[2];
  const int*   batch = (const int*)d_in[3];
  const float* u     = (const float*)d_in[4];
  const float* We1 = (const float*)d_in[5];  const float* be1 = (const float*)d_in[6];
  const float* ge1 = (const float*)d_in[7];  const float* bte1 = (const float*)d_in[8];
  const float* We2 = (const float*)d_in[9];  const float* be2 = (const float*)d_in[10];
  const float* Wf1 = (const float*)d_in[11]; const float* bf1 = (const float*)d_in[12];
  const float* Wf2 = (const float*)d_in[13]; const float* bf2 = (const float*)d_in[14];
  const float* Wd1 = (const float*)d_in[15]; const float* bd1 = (const float*)d_in[16];
  const float* Wd2 = (const float*)d_in[17]; const float* bd2 = (const float*)d_in[18];
  const float* Wg1 = (const float*)d_in[19]; const float* bg1 = (const float*)d_in[20];
  const float* gg1 = (const float*)d_in[21]; const float* btg1 = (const float*)d_in[22];
  const float* Wg2 = (const float*)d_in[23]; const float* bg2 = (const float*)d_in[24];
  const float* Ws1 = (const float*)d_in[25]; const float* bs1 = (const float*)d_in[26];
  const float* gs1 = (const float*)d_in[27]; const float* bts1 = (const float*)d_in[28];
  const float* Ws2 = (const float*)d_in[29]; const float* bs2 = (const float*)d_in[30];
  const float* gs2 = (const float*)d_in[31]; const float* bts2 = (const float*)d_in[32];
  const float* Ws3 = (const float*)d_in[33]; const float* bs3 = (const float*)d_in[34];

  float* out    = (float*)d_out;
  float* shifts = out;                    // [NN]
  float* h      = out + NN;               // [NN,HID]
  float* ea     = out + NN + NN * HID;    // [NE,NG]
  float* u_p    = out + NN + NN * HID + (size_t)NE * NG;  // [NGR,HID]

  // workspace layout
  char* wsb = (char*)d_ws;
  size_t off = 0;
  auto alloc = [&](size_t bytes) { void* p = wsb + off; off = (off + bytes + 255) & ~(size_t)255; return p; };
  float*  stats    = (float*)alloc(512 * sizeof(float));
  int*    hist     = (int*)alloc((size_t)NN * sizeof(int));
  int*    rowptr   = (int*)alloc((size_t)(NN + 1) * sizeof(int));
  int*    perm     = (int*)alloc((size_t)NE * sizeof(int));
  int4*   metap    = (int4*)alloc((size_t)NE * sizeof(int4));
  float*  tab      = (float*)alloc((size_t)NL * TBL * HID * sizeof(float));
  unsigned int* tabp = (unsigned int*)alloc((size_t)NL * TBL * HID * sizeof(unsigned int));
  bf16_t* Wd1Thi   = (bf16_t*)alloc((size_t)NL * 128 * 128 * sizeof(bf16_t));
  bf16_t* Wd1Tlo   = (bf16_t*)alloc((size_t)NL * 128 * 128 * sizeof(bf16_t));
  bf16_t* Wd2Thi   = (bf16_t*)alloc((size_t)NL * 128 * 128 * sizeof(bf16_t));
  bf16_t* Wd2Tlo   = (bf16_t*)alloc((size_t)NL * 128 * 128 * sizeof(bf16_t));
  float*  buf1     = (float*)alloc((size_t)NN * HID * sizeof(float));
  float* t1 = buf1;
  float* t2 = buf1 + (size_t)NN * SH;

  const int* row = ei;        // source j
  const int* col = ei + NE;   // target i

  // ---- CSR build + edge meta + table + node-weight prep
  hipMemsetAsync(hist, 0, (size_t)NN * sizeof(int), stream);
  k_hist<<<512, 256, 0, stream>>>(col, hist);
  k_scan<<<1, 1024, 0, stream>>>(hist, rowptr);
  k_scatter<<<512, 256, 0, stream>>>(col, hist, perm);
  k_preedge<<<(NE + 255) / 256, 256, 0, stream>>>(perm, eattr, row, col, metap);
  k_tabbuild2<<<NL * (TBL / 8), 128, 0, stream>>>(Wf1, bf1, Wf2, bf2, tab);
  k_tabpack<<<(NL * TBL * HID + 255) / 256, 256, 0, stream>>>(tab, tabp);
  k_prepw<<<(2 * NL * 128 * 128 + 255) / 256, 256, 0, stream>>>(
      Wd1, Wd2, Wd1Thi, Wd1Tlo, Wd2Thi, Wd2Tlo);

  // ---- node encoder
  hipMemsetAsync(stats, 0, 256 * sizeof(float), stream);
  k_enc1<<<512, 256, 0, stream>>>(x, We1, be1, buf1, stats);
  k_bn_fin<<<1, 128, 0, stream>>>(ge1, bte1, stats, 128, 1.f / NN);
  k_enc2<<<2048, 128, 0, stream>>>(buf1, stats, We2, be2, h);

  // ---- gaussian smearing (ea output)
  k_smear<<<(NE * NG + 255) / 256, 256, 0, stream>>>(eattr, ea);

  // ---- interaction layers
  for (int l = 0; l < NL; ++l) {
    k_edge7<<<NN / 16, 256, 0, stream>>>(
        metap, rowptr, h, tabp + (size_t)l * TBL * HID, buf1);
    k_node3<<<640, 512, 0, stream>>>(
        buf1,
        Wd1Thi + (size_t)l * 128 * 128, Wd1Tlo + (size_t)l * 128 * 128,
        Wd2Thi + (size_t)l * 128 * 128, Wd2Tlo + (size_t)l * 128 * 128,
        bd1 + (size_t)l * HID, bd2 + (size_t)l * HID, h);
  }

  // ---- global MLP
  k_global<<<1, 128, 0, stream>>>(u, Wg1, bg1, gg1, btg1, Wg2, bg2, u_p);

  // ---- shift head
  hipMemsetAsync(stats, 0, 256 * sizeof(float), stream);
  k_shift1<<<1024, 256, 0, stream>>>(h, u_p, batch, Ws1, bs1, t1, stats);
  k_bn_fin<<<1, 128, 0, stream>>>(gs1, bts1, stats, 64, 1.f / NN);
  hipMemsetAsync(stats, 0, 256 * sizeof(float), stream);
  k_shift2<<<1024, 256, 0, stream>>>(t1, stats, Ws2, bs2, t2);
  k_bn_fin<<<1, 128, 0, stream>>>(gs2, bts2, stats, 64, 1.f / NN);
  k_shift3<<<(NN + 3) / 4, 256, 0, stream>>>(t2, stats, Ws3, bs3, shifts);
}

// Round 8
// 2229.209 us; speedup vs baseline: 3.1294x; 1.0086x over previous
//
#include <hip/hip_runtime.h>

#define NN 50000
#define NE 1600000
#define NGR 64
#define XD 32
#define HID 128
#define NF 128
#define NG 50
#define GD 16
#define NL 6
#define SH 64
#define EPSF 1e-5f
#define TBL 4096          // filter table knots
#define INVSTEP 320.0f    // 1/step; covers d in [0, 12.8]

typedef __bf16 bf16_t;
typedef bf16_t bf16x8 __attribute__((ext_vector_type(8)));
typedef float f32x4 __attribute__((ext_vector_type(4)));

// ================= CSR build (once; col constant across layers) ============
__global__ __launch_bounds__(256) void k_hist(const int* __restrict__ col,
                                              int* __restrict__ hist) {
  for (int e = blockIdx.x * 256 + threadIdx.x; e < NE; e += gridDim.x * 256)
    atomicAdd(&hist[col[e]], 1);
}

__global__ __launch_bounds__(1024) void k_scan(int* __restrict__ hist,
                                               int* __restrict__ rowptr) {
  const int tid = threadIdx.x;
  const int CH = 49;
  const int base = tid * CH;
  int s = 0;
  for (int i = 0; i < CH; ++i) {
    int idx = base + i;
    if (idx < NN) s += hist[idx];
  }
  __shared__ int part[1024];
  part[tid] = s;
  __syncthreads();
  for (int off = 1; off < 1024; off <<= 1) {
    int v = (tid >= off) ? part[tid - off] : 0;
    __syncthreads();
    part[tid] += v;
    __syncthreads();
  }
  int run = part[tid] - s;
  for (int i = 0; i < CH; ++i) {
    int idx = base + i;
    if (idx < NN) {
      int c = hist[idx];
      rowptr[idx] = run;
      hist[idx] = run;
      run += c;
    }
  }
  if (tid == 0) rowptr[NN] = NE;
}

__global__ __launch_bounds__(256) void k_scatter(const int* __restrict__ col,
                                                 int* __restrict__ cursor,
                                                 int* __restrict__ perm) {
  for (int e = blockIdx.x * 256 + threadIdx.x; e < NE; e += gridDim.x * 256) {
    int pos = atomicAdd(&cursor[col[e]], 1);
    perm[pos] = e;
  }
}

// ================= permuted per-edge meta: (idx, frac, row, dst) ===========
__global__ __launch_bounds__(256) void k_preedge(const int* __restrict__ perm,
    const float* __restrict__ eattr, const int* __restrict__ row,
    const int* __restrict__ col, int4* __restrict__ metap) {
  int p = blockIdx.x * 256 + threadIdx.x;
  if (p < NE) {
    int pe = perm[p];
    float ax = eattr[(size_t)pe * 3], ay = eattr[(size_t)pe * 3 + 1], az = eattr[(size_t)pe * 3 + 2];
    float d = sqrtf(ax * ax + ay * ay + az * az);
    float tt = fminf(d * INVSTEP, (float)(TBL - 2) + 0.999f);
    int id = (int)tt;
    metap[p] = make_int4(id, __float_as_int(tt - (float)id), row[pe], col[pe]);
  }
}

// ================= filter table build: 8 knots / block =====================
__global__ __launch_bounds__(128) void k_tabbuild2(
    const float* __restrict__ Wf1, const float* __restrict__ bf1,
    const float* __restrict__ Wf2, const float* __restrict__ bf2,
    float* __restrict__ tab) {
  const int bid = blockIdx.x;            // 0 .. NL*(TBL/8)-1
  const int l = bid / (TBL / 8);
  const int t0 = (bid - l * (TBL / 8)) * 8;
  const int c = threadIdx.x;
  __shared__ float g_s[8][NG];
  __shared__ float f1_s[8][NF];
  for (int i = c; i < 8 * NG; i += 128) {
    int kk = i / NG, g = i - kk * NG;
    float d = (float)(t0 + kk) * (1.0f / INVSTEP);
    float z = d - 0.2040816327f * (float)g;
    g_s[kk][g] = expf(-12.005f * z * z);
  }
  __syncthreads();
  const float* W1 = Wf1 + (size_t)l * NG * NF;
  float f1r[8];
#pragma unroll
  for (int kk = 0; kk < 8; ++kk) f1r[kk] = bf1[(size_t)l * NF + c];
  for (int g = 0; g < NG; ++g) {
    float w = W1[g * NF + c];
#pragma unroll
    for (int kk = 0; kk < 8; ++kk) f1r[kk] = fmaf(g_s[kk][g], w, f1r[kk]);
  }
#pragma unroll
  for (int kk = 0; kk < 8; ++kk) f1_s[kk][c] = fmaxf(f1r[kk], 0.f);
  __syncthreads();
  const float* W2 = Wf2 + (size_t)l * NF * NF;
  float outr[8];
#pragma unroll
  for (int kk = 0; kk < 8; ++kk) outr[kk] = bf2[(size_t)l * NF + c];
  for (int k = 0; k < NF; ++k) {
    float w = W2[k * NF + c];
#pragma unroll
    for (int kk = 0; kk < 8; ++kk) outr[kk] = fmaf(f1_s[kk][k], w, outr[kk]);
  }
#pragma unroll
  for (int kk = 0; kk < 8; ++kk)
    tab[((size_t)l * TBL + t0 + kk) * NF + c] = outr[kk];
}

// ================= pack table: u32 = (bf16 T[t], bf16 T[t+1]) ==============
__global__ __launch_bounds__(256) void k_tabpack(const float* __restrict__ tab,
    unsigned int* __restrict__ tabp) {
  int idx = blockIdx.x * 256 + threadIdx.x;
  if (idx < NL * TBL * HID) {
    int c = idx & (HID - 1);
    int t = (idx >> 7) & (TBL - 1);
    int l = idx >> 19;
    int tn = min(t + 1, TBL - 1);
    float w0 = tab[idx];
    float w1 = tab[((size_t)l * TBL + tn) * HID + c];
    unsigned short a = __builtin_bit_cast(unsigned short, (bf16_t)w0);
    unsigned short b = __builtin_bit_cast(unsigned short, (bf16_t)w1);
    tabp[idx] = (unsigned int)a | ((unsigned int)b << 16);
  }
}

// ================= weight prep for node MLP (transpose + split hi/lo) ======
__global__ __launch_bounds__(256) void k_prepw(const float* __restrict__ Wd1,
    const float* __restrict__ Wd2,
    bf16_t* __restrict__ Wd1Thi, bf16_t* __restrict__ Wd1Tlo,
    bf16_t* __restrict__ Wd2Thi, bf16_t* __restrict__ Wd2Tlo) {
  const int S1 = NL * 128 * 128;
  int idx = blockIdx.x * 256 + threadIdx.x;
  if (idx < 2 * S1) {
    int which = idx / S1;  // 0: Wd1, 1: Wd2
    int jj = idx - which * S1;
    int l = jj / (128 * 128);
    int r = jj - l * (128 * 128);
    int c = r >> 7, k = r & 127;
    const float* W = (which == 0) ? Wd1 : Wd2;
    float v = W[(size_t)l * 128 * 128 + (size_t)k * 128 + c];
    bf16_t hv = (bf16_t)v;
    bf16_t lv = (bf16_t)(v - (float)hv);
    if (which == 0) { Wd1Thi[jj] = hv; Wd1Tlo[jj] = lv; }
    else            { Wd2Thi[jj] = hv; Wd2Tlo[jj] = lv; }
  }
}

// ================= node encoder ============================================
__global__ __launch_bounds__(256) void k_enc1(const float* __restrict__ x,
    const float* __restrict__ We1, const float* __restrict__ be1,
    float* __restrict__ t, float* __restrict__ stats) {
  int c = threadIdx.x & 127;
  int half = threadIdx.x >> 7;
  float b = be1[c];
  float psum = 0.f, psq = 0.f;
  for (int n = blockIdx.x * 2 + half; n < NN; n += gridDim.x * 2) {
    const float* xr = x + (size_t)n * XD;
    float v = b;
#pragma unroll
    for (int k = 0; k < XD; ++k) v = fmaf(xr[k], We1[k * HID + c], v);
    t[(size_t)n * HID + c] = v;
    psum += v; psq += v * v;
  }
  __shared__ float s0[256], s1[256];
  s0[threadIdx.x] = psum; s1[threadIdx.x] = psq;
  __syncthreads();
  if (threadIdx.x < 128) {
    atomicAdd(&stats[threadIdx.x], s0[threadIdx.x] + s0[threadIdx.x + 128]);
    atomicAdd(&stats[128 + threadIdx.x], s1[threadIdx.x] + s1[threadIdx.x + 128]);
  }
}

__global__ __launch_bounds__(128) void k_bn_fin(const float* __restrict__ gamma,
    const float* __restrict__ beta, float* __restrict__ stats, int C, float invn) {
  int c = threadIdx.x;
  if (c < C) {
    float mean = stats[c] * invn;
    float var = stats[128 + c] * invn - mean * mean;
    float a = gamma[c] * rsqrtf(var + EPSF);
    stats[256 + c] = a;
    stats[384 + c] = beta[c] - mean * a;
  }
}

__global__ __launch_bounds__(128) void k_enc2(const float* __restrict__ t,
    const float* __restrict__ stats, const float* __restrict__ We2,
    const float* __restrict__ be2, float* __restrict__ h) {
  __shared__ float r[HID];
  int c = threadIdx.x;
  float a = stats[256 + c], b = stats[384 + c];
  float bias = be2[c];
  for (int n = blockIdx.x; n < NN; n += gridDim.x) {
    float v = fmaf(t[(size_t)n * HID + c], a, b);
    r[c] = fmaxf(v, 0.f);
    __syncthreads();
    float acc = bias;
#pragma unroll 8
    for (int k = 0; k < HID; ++k) acc = fmaf(r[k], We2[k * HID + c], acc);
    h[(size_t)n * HID + c] = acc;
    __syncthreads();
  }
}

// ================= gaussian smearing (ea output) ===========================
__global__ __launch_bounds__(256) void k_smear(const float* __restrict__ eattr,
    float* __restrict__ ea) {
  int idx = blockIdx.x * 256 + threadIdx.x;
  if (idx >= NE * NG) return;
  int e = idx / NG;
  int g = idx - e * NG;
  float ax = eattr[(size_t)e * 3], ay = eattr[(size_t)e * 3 + 1], az = eattr[(size_t)e * 3 + 2];
  float d = sqrtf(ax * ax + ay * ay + az * az);
  float off = (10.0f / 49.0f) * (float)g;
  float z = d - off;
  ea[idx] = __expf(-12.005f * z * z);
}

// ================= fused layer kernel ======================================
// Block = 16 dest nodes, 256 threads = 4 waves.
// Phase 1 (edge): lane owns 2 cols; wave covers 128 cols of one edge; waves
//   split the block's CSR range; software-pipelined meta prefetch; register
//   run-accumulation; LDS-atomic flush at run boundaries -> agg_s.
// Phase 2 (node): agg_s -> bf16 hi/lo; 2 MFMA GEMMs (weights streamed from
//   L2-hot global, not register-resident); h_out = h_in + MLP(agg).
__global__ __launch_bounds__(256) void k_layer(
    const int4* __restrict__ metap, const int* __restrict__ rowptr,
    const float* __restrict__ hin, const unsigned int* __restrict__ tabp,
    const bf16_t* __restrict__ Wd1Thi, const bf16_t* __restrict__ Wd1Tlo,
    const bf16_t* __restrict__ Wd2Thi, const bf16_t* __restrict__ Wd2Tlo,
    const float* __restrict__ bd1, const float* __restrict__ bd2,
    float* __restrict__ hout) {
  __shared__ float agg_s[16][HID];
  __shared__ __align__(16) bf16_t ahi_s[16][136];
  __shared__ __align__(16) bf16_t alo_s[16][136];
  __shared__ __align__(16) bf16_t t1hi[16][136];
  __shared__ __align__(16) bf16_t t1lo[16][136];

  const int tid = threadIdx.x;
  const int lane = tid & 63;
  const int w = tid >> 6;
  const int c0 = lane * 2;
  const int nb = blockIdx.x * 16;
  const int eS = rowptr[nb], eE = rowptr[nb + 16];

  for (int i = tid; i < 16 * HID; i += 256) ((float*)agg_s)[i] = 0.f;
  __syncthreads();

  // ---------------- phase 1: edges ----------------
  {
    const int Q = (eE - eS + 3) >> 2;
    int e = eS + w * Q;
    const int wE = min(e + Q, eE);

    float acc0 = 0.f, acc1 = 0.f;
    int cur = -1;

    auto body = [&](const int4& m, const float2& hv, const uint2& uv) {
      float fr = __int_as_float(m.y);
      int dst = m.w - nb;
      float w0a = __uint_as_float((uv.x & 0xffffu) << 16);
      float w1a = __uint_as_float(uv.x & 0xffff0000u);
      float w0b = __uint_as_float((uv.y & 0xffffu) << 16);
      float w1b = __uint_as_float(uv.y & 0xffff0000u);
      float ma = fmaf(fr, w1a - w0a, w0a) * hv.x;
      float mb = fmaf(fr, w1b - w0b, w0b) * hv.y;
      if (dst != cur) {
        if (cur >= 0) {
          atomicAdd(&agg_s[cur][c0], acc0);
          atomicAdd(&agg_s[cur][c0 + 1], acc1);
        }
        cur = dst; acc0 = ma; acc1 = mb;
      } else {
        acc0 += ma; acc1 += mb;
      }
    };

    if (wE - e >= 4) {
      int4 m0 = metap[e], m1 = metap[e + 1], m2 = metap[e + 2], m3 = metap[e + 3];
      int ep = e + 4;
      while (true) {
        float2 h0 = *(const float2*)(hin + (size_t)m0.z * HID + c0);
        float2 h1 = *(const float2*)(hin + (size_t)m1.z * HID + c0);
        float2 h2 = *(const float2*)(hin + (size_t)m2.z * HID + c0);
        float2 h3 = *(const float2*)(hin + (size_t)m3.z * HID + c0);
        uint2 t0 = *(const uint2*)(tabp + (size_t)m0.x * HID + c0);
        uint2 t1 = *(const uint2*)(tabp + (size_t)m1.x * HID + c0);
        uint2 t2 = *(const uint2*)(tabp + (size_t)m2.x * HID + c0);
        uint2 t3 = *(const uint2*)(tabp + (size_t)m3.x * HID + c0);
        const bool more = (ep + 4 <= wE);
        int4 n0, n1, n2, n3;
        if (more) {
          n0 = metap[ep]; n1 = metap[ep + 1]; n2 = metap[ep + 2]; n3 = metap[ep + 3];
        }
        body(m0, h0, t0); body(m1, h1, t1); body(m2, h2, t2); body(m3, h3, t3);
        if (!more) break;
        m0 = n0; m1 = n1; m2 = n2; m3 = n3;
        ep += 4;
      }
      e = ep;
    }
    for (; e < wE; ++e) {
      int4 m = metap[e];
      float2 hv = *(const float2*)(hin + (size_t)m.z * HID + c0);
      uint2 uv = *(const uint2*)(tabp + (size_t)m.x * HID + c0);
      body(m, hv, uv);
    }
    if (cur >= 0) {
      atomicAdd(&agg_s[cur][c0], acc0);
      atomicAdd(&agg_s[cur][c0 + 1], acc1);
    }
  }
  __syncthreads();

  // ---------------- phase 2: node MLP on agg_s ----------------
  // split agg -> bf16 hi/lo
  for (int i = tid; i < 16 * 128; i += 256) {
    int r = i >> 7, k = i & 127;
    float v = agg_s[r][k];
    bf16_t hv = (bf16_t)v;
    ahi_s[r][k] = hv;
    alo_s[r][k] = (bf16_t)(v - (float)hv);
  }
  __syncthreads();

  const int lm = lane & 15;
  const int lk = lane >> 4;
  const int colb = w * 32;
  const int k0base = lk * 8;

  // GEMM1: t1 = relu(agg @ Wd1 + bd1)
  f32x4 acc1g[2];
  acc1g[0] = (f32x4){0.f, 0.f, 0.f, 0.f};
  acc1g[1] = (f32x4){0.f, 0.f, 0.f, 0.f};
#pragma unroll
  for (int s = 0; s < 4; ++s) {
    int k0 = s * 32 + k0base;
    bf16x8 Ahi = *(const bf16x8*)&ahi_s[lm][k0];
    bf16x8 Alo = *(const bf16x8*)&alo_s[lm][k0];
#pragma unroll
    for (int cf = 0; cf < 2; ++cf) {
      int cc = colb + cf * 16 + lm;
      bf16x8 Bh = *(const bf16x8*)(Wd1Thi + (size_t)cc * 128 + k0);
      bf16x8 Bl = *(const bf16x8*)(Wd1Tlo + (size_t)cc * 128 + k0);
      acc1g[cf] = __builtin_amdgcn_mfma_f32_16x16x32_bf16(Ahi, Bh, acc1g[cf], 0, 0, 0);
      acc1g[cf] = __builtin_amdgcn_mfma_f32_16x16x32_bf16(Ahi, Bl, acc1g[cf], 0, 0, 0);
      acc1g[cf] = __builtin_amdgcn_mfma_f32_16x16x32_bf16(Alo, Bh, acc1g[cf], 0, 0, 0);
    }
  }
#pragma unroll
  for (int cf = 0; cf < 2; ++cf) {
    int cc = colb + cf * 16 + lm;
    float bias1 = bd1[cc];
#pragma unroll
    for (int j = 0; j < 4; ++j) {
      int r = lk * 4 + j;
      float v = fmaxf(acc1g[cf][j] + bias1, 0.f);
      bf16_t hv = (bf16_t)v;
      t1hi[r][cc] = hv;
      t1lo[r][cc] = (bf16_t)(v - (float)hv);
    }
  }
  __syncthreads();

  // GEMM2: out = t1 @ Wd2 + bd2;  hout = hin + out
  f32x4 acc2g[2];
  acc2g[0] = (f32x4){0.f, 0.f, 0.f, 0.f};
  acc2g[1] = (f32x4){0.f, 0.f, 0.f, 0.f};
#pragma unroll
  for (int s = 0; s < 4; ++s) {
    int k0 = s * 32 + k0base;
    bf16x8 Ahi = *(const bf16x8*)&t1hi[lm][k0];
    bf16x8 Alo = *(const bf16x8*)&t1lo[lm][k0];
#pragma unroll
    for (int cf = 0; cf < 2; ++cf) {
      int cc = colb + cf * 16 + lm;
      bf16x8 Bh = *(const bf16x8*)(Wd2Thi + (size_t)cc * 128 + k0);
      bf16x8 Bl = *(const bf16x8*)(Wd2Tlo + (size_t)cc * 128 + k0);
      acc2g[cf] = __builtin_amdgcn_mfma_f32_16x16x32_bf16(Ahi, Bh, acc2g[cf], 0, 0, 0);
      acc2g[cf] = __builtin_amdgcn_mfma_f32_16x16x32_bf16(Ahi, Bl, acc2g[cf], 0, 0, 0);
      acc2g[cf] = __builtin_amdgcn_mfma_f32_16x16x32_bf16(Alo, Bh, acc2g[cf], 0, 0, 0);
    }
  }
#pragma unroll
  for (int cf = 0; cf < 2; ++cf) {
    int cc = colb + cf * 16 + lm;
    float bias2 = bd2[cc];
#pragma unroll
    for (int j = 0; j < 4; ++j) {
      int r = nb + lk * 4 + j;
      hout[(size_t)r * HID + cc] = hin[(size_t)r * HID + cc] + acc2g[cf][j] + bias2;
    }
  }
}

// ================= global MLP ==============================================
__global__ __launch_bounds__(128) void k_global(const float* __restrict__ u,
    const float* __restrict__ Wg1, const float* __restrict__ bg1,
    const float* __restrict__ gg1, const float* __restrict__ btg1,
    const float* __restrict__ Wg2, const float* __restrict__ bg2,
    float* __restrict__ u_p) {
  __shared__ float t_s[NGR][HID];
  int c = threadIdx.x;
  for (int g = 0; g < NGR; ++g) {
    float v = bg1[c];
#pragma unroll
    for (int k = 0; k < GD; ++k) v = fmaf(u[(size_t)g * GD + k], Wg1[k * HID + c], v);
    t_s[g][c] = v;
  }
  float sum = 0.f, sq = 0.f;
  for (int g = 0; g < NGR; ++g) { float v = t_s[g][c]; sum += v; sq += v * v; }
  float mean = sum * (1.f / NGR);
  float var = sq * (1.f / NGR) - mean * mean;
  float a = gg1[c] * rsqrtf(var + EPSF);
  float b = btg1[c] - mean * a;
  for (int g = 0; g < NGR; ++g) t_s[g][c] = fmaxf(fmaf(t_s[g][c], a, b), 0.f);
  __syncthreads();
  for (int g = 0; g < NGR; ++g) {
    float acc = bg2[c];
#pragma unroll 8
    for (int k = 0; k < HID; ++k) acc = fmaf(t_s[g][k], Wg2[k * HID + c], acc);
    u_p[(size_t)g * HID + c] = acc;
  }
}

// ================= shift head ==============================================
__global__ __launch_bounds__(256) void k_shift1(
    const float* __restrict__ h, const float* __restrict__ u_p,
    const int* __restrict__ batch, const float* __restrict__ Ws1,
    const float* __restrict__ bs1, float* __restrict__ t1, float* __restrict__ stats) {
  __shared__ float s_in[16][2 * HID];
  const int c = threadIdx.x & 63;
  const int ng = threadIdx.x >> 6;
  float psum = 0.f, psq = 0.f;
  for (int tile = blockIdx.x; tile < NN / 16; tile += gridDim.x) {
    const int nb = tile * 16;
    for (int i = threadIdx.x; i < 16 * HID; i += 256) {
      int ln = i >> 7, k = i & 127;
      s_in[ln][k] = h[(size_t)(nb + ln) * HID + k];
      s_in[ln][HID + k] = u_p[(size_t)batch[nb + ln] * HID + k];
    }
    __syncthreads();
    float acc[4];
#pragma unroll
    for (int j = 0; j < 4; ++j) acc[j] = bs1[c];
    for (int k = 0; k < 2 * HID; ++k) {
      float w = Ws1[k * SH + c];
#pragma unroll
      for (int j = 0; j < 4; ++j) acc[j] = fmaf(s_in[ng * 4 + j][k], w, acc[j]);
    }
#pragma unroll
    for (int j = 0; j < 4; ++j) {
      t1[(size_t)(nb + ng * 4 + j) * SH + c] = acc[j];
      psum += acc[j]; psq += acc[j] * acc[j];
    }
    __syncthreads();
  }
  __shared__ float rs[256], rq[256];
  rs[threadIdx.x] = psum; rq[threadIdx.x] = psq;
  __syncthreads();
  if (threadIdx.x < 64) {
    int c2 = threadIdx.x;
    atomicAdd(&stats[c2], rs[c2] + rs[c2 + 64] + rs[c2 + 128] + rs[c2 + 192]);
    atomicAdd(&stats[128 + c2], rq[c2] + rq[c2 + 64] + rq[c2 + 128] + rq[c2 + 192]);
  }
}

__global__ __launch_bounds__(256) void k_shift2(
    const float* __restrict__ t1, float* __restrict__ stats,
    const float* __restrict__ Ws2, const float* __restrict__ bs2,
    float* __restrict__ t2) {
  __shared__ float r_s[16][SH];
  const int c = threadIdx.x & 63;
  const int ng = threadIdx.x >> 6;
  float psum = 0.f, psq = 0.f;
  for (int tile = blockIdx.x; tile < NN / 16; tile += gridDim.x) {
    const int nb = tile * 16;
    for (int i = threadIdx.x; i < 16 * SH; i += 256) {
      int ln = i >> 6, k = i & 63;
      float v = fmaf(t1[(size_t)(nb + ln) * SH + k], stats[256 + k], stats[384 + k]);
      r_s[ln][k] = fmaxf(v, 0.f);
    }
    __syncthreads();
    float acc[4];
#pragma unroll
    for (int j = 0; j < 4; ++j) acc[j] = bs2[c];
    for (int k = 0; k < SH; ++k) {
      float w = Ws2[k * SH + c];
#pragma unroll
      for (int j = 0; j < 4; ++j) acc[j] = fmaf(r_s[ng * 4 + j][k], w, acc[j]);
    }
#pragma unroll
    for (int j = 0; j < 4; ++j) {
      t2[(size_t)(nb + ng * 4 + j) * SH + c] = acc[j];
      psum += acc[j]; psq += acc[j] * acc[j];
    }
    __syncthreads();
  }
  __shared__ float rs[256], rq[256];
  rs[threadIdx.x] = psum; rq[threadIdx.x] = psq;
  __syncthreads();
  if (threadIdx.x < 64) {
    int c2 = threadIdx.x;
    atomicAdd(&stats[c2], rs[c2] + rs[c2 + 64] + rs[c2 + 128] + rs[c2 + 192]);
    atomicAdd(&stats[128 + c2], rq[c2] + rq[c2 + 64] + rq[c2 + 128] + rq[c2 + 192]);
  }
}

__global__ __launch_bounds__(256) void k_shift3(
    const float* __restrict__ t2, const float* __restrict__ stats,
    const float* __restrict__ Ws3, const float* __restrict__ bs3,
    float* __restrict__ shifts) {
  int lane = threadIdx.x & 63;
  int n = blockIdx.x * 4 + (threadIdx.x >> 6);
  if (n >= NN) return;
  float a = stats[256 + lane], b = stats[384 + lane];
  float r = fmaxf(fmaf(t2[(size_t)n * SH + lane], a, b), 0.f);
  float v = r * Ws3[lane];
#pragma unroll
  for (int off = 32; off; off >>= 1) v += __shfl_down(v, off);
  if (lane == 0) shifts[n] = v + bs3[0];
}

extern "C" void kernel_launch(void* const* d_in, const int* in_sizes, int n_in,
                              void* d_out, int out_size, void* d_ws, size_t ws_size,
                              hipStream_t stream) {
  const float* x     = (const float*)d_in[0];
  const int*   ei    = (const int*)d_in[1];
  const float* eattr = (const float*)d_in[2];
  const int*   batch = (const int*)d_in[3];
  const float* u     = (const float*)d_in[4];
  const float* We1 = (const float*)d_in[5];  const float* be1 = (const float*)d_in[6];
  const float* ge1 = (const float*)d_in[7];  const float* bte1 = (const float*)d_in[8];
  const float* We2 = (const float*)d_in[9];  const float* be2 = (const float*)d_in[10];
  const float* Wf1 = (const float*)d_in[11]; const float* bf1 = (const float*)d_in[12];
  const float* Wf2 = (const float*)d_in[13]; const float* bf2 = (const float*)d_in[14];
  const float* Wd1 = (const float*)d_in[15]; const float* bd1 = (const float*)d_in[16];
  const float* Wd2 = (const float*)d_in[17]; const float* bd2 = (const float*)d_in[18];
  const float* Wg1 = (const float*)d_in[19]; const float* bg1 = (const float*)d_in[20];
  const float* gg1 = (const float*)d_in[21]; const float* btg1 = (const float*)d_in[22];
  const float* Wg2 = (const float*)d_in[23]; const float* bg2 = (const float*)d_in[24];
  const float* Ws1 = (const float*)d_in[25]; const float* bs1 = (const float*)d_in[26];
  const float* gs1 = (const float*)d_in[27]; const float* bts1 = (const float*)d_in[28];
  const float* Ws2 = (const float*)d_in[29]; const float* bs2 = (const float*)d_in[30];
  const float* gs2 = (const float*)d_in[31]; const float* bts2 = (const float*)d_in[32];
  const float* Ws3 = (const float*)d_in[33]; const float* bs3 = (const float*)d_in[34];

  float* out    = (float*)d_out;
  float* shifts = out;                    // [NN]
  float* h      = out + NN;               // [NN,HID]
  float* ea     = out + NN + NN * HID;    // [NE,NG]
  float* u_p    = out + NN + NN * HID + (size_t)NE * NG;  // [NGR,HID]

  // workspace layout
  char* wsb = (char*)d_ws;
  size_t off = 0;
  auto alloc = [&](size_t bytes) { void* p = wsb + off; off = (off + bytes + 255) & ~(size_t)255; return p; };
  float*  stats    = (float*)alloc(512 * sizeof(float));
  int*    hist     = (int*)alloc((size_t)NN * sizeof(int));
  int*    rowptr   = (int*)alloc((size_t)(NN + 1) * sizeof(int));
  int*    perm     = (int*)alloc((size_t)NE * sizeof(int));
  int4*   metap    = (int4*)alloc((size_t)NE * sizeof(int4));
  float*  tab      = (float*)alloc((size_t)NL * TBL * HID * sizeof(float));
  unsigned int* tabp = (unsigned int*)alloc((size_t)NL * TBL * HID * sizeof(unsigned int));
  bf16_t* Wd1Thi   = (bf16_t*)alloc((size_t)NL * 128 * 128 * sizeof(bf16_t));
  bf16_t* Wd1Tlo   = (bf16_t*)alloc((size_t)NL * 128 * 128 * sizeof(bf16_t));
  bf16_t* Wd2Thi   = (bf16_t*)alloc((size_t)NL * 128 * 128 * sizeof(bf16_t));
  bf16_t* Wd2Tlo   = (bf16_t*)alloc((size_t)NL * 128 * 128 * sizeof(bf16_t));
  float*  hwork    = (float*)alloc((size_t)NN * HID * sizeof(float));
  float*  buf1     = (float*)alloc((size_t)NN * HID * sizeof(float));
  float* t1 = buf1;
  float* t2 = buf1 + (size_t)NN * SH;

  const int* row = ei;        // source j
  const int* col = ei + NE;   // target i

  // ---- CSR build + edge meta + table + node-weight prep
  hipMemsetAsync(hist, 0, (size_t)NN * sizeof(int), stream);
  k_hist<<<512, 256, 0, stream>>>(col, hist);
  k_scan<<<1, 1024, 0, stream>>>(hist, rowptr);
  k_scatter<<<512, 256, 0, stream>>>(col, hist, perm);
  k_preedge<<<(NE + 255) / 256, 256, 0, stream>>>(perm, eattr, row, col, metap);
  k_tabbuild2<<<NL * (TBL / 8), 128, 0, stream>>>(Wf1, bf1, Wf2, bf2, tab);
  k_tabpack<<<(NL * TBL * HID + 255) / 256, 256, 0, stream>>>(tab, tabp);
  k_prepw<<<(2 * NL * 128 * 128 + 255) / 256, 256, 0, stream>>>(
      Wd1, Wd2, Wd1Thi, Wd1Tlo, Wd2Thi, Wd2Tlo);

  // ---- node encoder
  hipMemsetAsync(stats, 0, 256 * sizeof(float), stream);
  k_enc1<<<512, 256, 0, stream>>>(x, We1, be1, buf1, stats);
  k_bn_fin<<<1, 128, 0, stream>>>(ge1, bte1, stats, 128, 1.f / NN);
  k_enc2<<<2048, 128, 0, stream>>>(buf1, stats, We2, be2, h);

  // ---- gaussian smearing (ea output)
  k_smear<<<(NE * NG + 255) / 256, 256, 0, stream>>>(eattr, ea);

  // ---- interaction layers (fused edge+node, ping-pong h)
  for (int l = 0; l < NL; ++l) {
    const float* hi = (l & 1) ? hwork : h;
    float*       ho = (l & 1) ? h : hwork;
    k_layer<<<NN / 16, 256, 0, stream>>>(
        metap, rowptr, hi, tabp + (size_t)l * TBL * HID,
        Wd1Thi + (size_t)l * 128 * 128, Wd1Tlo + (size_t)l * 128 * 128,
        Wd2Thi + (size_t)l * 128 * 128, Wd2Tlo + (size_t)l * 128 * 128,
        bd1 + (size_t)l * HID, bd2 + (size_t)l * HID, ho);
  }
  // NL=6 (even) -> final h lands back in the output slot `h`

  // ---- global MLP
  k_global<<<1, 128, 0, stream>>>(u, Wg1, bg1, gg1, btg1, Wg2, bg2, u_p);

  // ---- shift head
  hipMemsetAsync(stats, 0, 256 * sizeof(float), stream);
  k_shift1<<<1024, 256, 0, stream>>>(h, u_p, batch, Ws1, bs1, t1, stats);
  k_bn_fin<<<1, 128, 0, stream>>>(gs1, bts1, stats, 64, 1.f / NN);
  hipMemsetAsync(stats, 0, 256 * sizeof(float), stream);
  k_shift2<<<1024, 256, 0, stream>>>(t1, stats, Ws2, bs2, t2);
  k_bn_fin<<<1, 128, 0, stream>>>(gs2, bts2, stats, 64, 1.f / NN);
  k_shift3<<<(NN + 3) / 4, 256, 0, stream>>>(t2, stats, Ws3, bs3, shifts);
}

// Round 9
// 1903.151 us; speedup vs baseline: 3.6655x; 1.1713x over previous
//
#include <hip/hip_runtime.h>

#define NN 50000
#define NE 1600000
#define NGR 64
#define XD 32
#define HID 128
#define NF 128
#define NG 50
#define GD 16
#define NL 6
#define SH 64
#define EPSF 1e-5f
#define TBL 4096          // filter table knots
#define INVSTEP 320.0f    // 1/step; covers d in [0, 12.8]

typedef __bf16 bf16_t;
typedef bf16_t bf16x8 __attribute__((ext_vector_type(8)));
typedef float f32x4 __attribute__((ext_vector_type(4)));

__device__ __forceinline__ unsigned pack_bf2(float a, float b) {
  unsigned short ua = __builtin_bit_cast(unsigned short, (bf16_t)a);
  unsigned short ub = __builtin_bit_cast(unsigned short, (bf16_t)b);
  return (unsigned)ua | ((unsigned)ub << 16);
}

// ================= CSR build (once; col constant across layers) ============
__global__ __launch_bounds__(256) void k_hist(const int* __restrict__ col,
                                              int* __restrict__ hist) {
  for (int e = blockIdx.x * 256 + threadIdx.x; e < NE; e += gridDim.x * 256)
    atomicAdd(&hist[col[e]], 1);
}

__global__ __launch_bounds__(1024) void k_scan(int* __restrict__ hist,
                                               int* __restrict__ rowptr) {
  const int tid = threadIdx.x;
  const int CH = 49;
  const int base = tid * CH;
  int s = 0;
  for (int i = 0; i < CH; ++i) {
    int idx = base + i;
    if (idx < NN) s += hist[idx];
  }
  __shared__ int part[1024];
  part[tid] = s;
  __syncthreads();
  for (int off = 1; off < 1024; off <<= 1) {
    int v = (tid >= off) ? part[tid - off] : 0;
    __syncthreads();
    part[tid] += v;
    __syncthreads();
  }
  int run = part[tid] - s;
  for (int i = 0; i < CH; ++i) {
    int idx = base + i;
    if (idx < NN) {
      int c = hist[idx];
      rowptr[idx] = run;
      hist[idx] = run;
      run += c;
    }
  }
  if (tid == 0) rowptr[NN] = NE;
}

// scatter + per-edge meta fused: metap[pos] = (idx, frac, row, dst)
__global__ __launch_bounds__(256) void k_scatter2(const int* __restrict__ col,
    const int* __restrict__ row, const float* __restrict__ eattr,
    int* __restrict__ cursor, int4* __restrict__ metap) {
  for (int e = blockIdx.x * 256 + threadIdx.x; e < NE; e += gridDim.x * 256) {
    float ax = eattr[(size_t)e * 3], ay = eattr[(size_t)e * 3 + 1], az = eattr[(size_t)e * 3 + 2];
    float d = sqrtf(ax * ax + ay * ay + az * az);
    float tt = fminf(d * INVSTEP, (float)(TBL - 2) + 0.999f);
    int id = (int)tt;
    int c = col[e];
    int pos = atomicAdd(&cursor[c], 1);
    metap[pos] = make_int4(id, __float_as_int(tt - (float)id), row[e], c);
  }
}

// ================= filter table build (packed bf16 pairs, direct) ==========
// block = 8 output knots (computes 9); tabp[t][c] = (bf16 T[t][c], bf16 T[t+1][c])
__global__ __launch_bounds__(128) void k_tabbuild3(
    const float* __restrict__ Wf1, const float* __restrict__ bf1,
    const float* __restrict__ Wf2, const float* __restrict__ bf2,
    unsigned int* __restrict__ tabp) {
  const int bid = blockIdx.x;            // 0 .. NL*(TBL/8)-1
  const int l = bid / (TBL / 8);
  const int t0 = (bid - l * (TBL / 8)) * 8;
  const int c = threadIdx.x;
  __shared__ float g_s[9][NG];
  __shared__ float f1_s[9][NF];
  for (int i = c; i < 9 * NG; i += 128) {
    int kk = i / NG, g = i - kk * NG;
    int t = min(t0 + kk, TBL - 1);
    float d = (float)t * (1.0f / INVSTEP);
    float z = d - 0.2040816327f * (float)g;
    g_s[kk][g] = expf(-12.005f * z * z);
  }
  __syncthreads();
  const float* W1 = Wf1 + (size_t)l * NG * NF;
  float f1r[9];
#pragma unroll
  for (int kk = 0; kk < 9; ++kk) f1r[kk] = bf1[(size_t)l * NF + c];
  for (int g = 0; g < NG; ++g) {
    float w = W1[g * NF + c];
#pragma unroll
    for (int kk = 0; kk < 9; ++kk) f1r[kk] = fmaf(g_s[kk][g], w, f1r[kk]);
  }
#pragma unroll
  for (int kk = 0; kk < 9; ++kk) f1_s[kk][c] = fmaxf(f1r[kk], 0.f);
  __syncthreads();
  const float* W2 = Wf2 + (size_t)l * NF * NF;
  float outr[9];
#pragma unroll
  for (int kk = 0; kk < 9; ++kk) outr[kk] = bf2[(size_t)l * NF + c];
  for (int k = 0; k < NF; ++k) {
    float w = W2[k * NF + c];
#pragma unroll
    for (int kk = 0; kk < 9; ++kk) outr[kk] = fmaf(f1_s[kk][k], w, outr[kk]);
  }
#pragma unroll
  for (int kk = 0; kk < 8; ++kk)
    tabp[((size_t)l * TBL + t0 + kk) * NF + c] = pack_bf2(outr[kk], outr[kk + 1]);
}

// ================= weight prep for node MLP (transpose + split hi/lo) ======
__global__ __launch_bounds__(256) void k_prepw(const float* __restrict__ Wd1,
    const float* __restrict__ Wd2,
    bf16_t* __restrict__ Wd1Thi, bf16_t* __restrict__ Wd1Tlo,
    bf16_t* __restrict__ Wd2Thi, bf16_t* __restrict__ Wd2Tlo) {
  const int S1 = NL * 128 * 128;
  int idx = blockIdx.x * 256 + threadIdx.x;
  if (idx < 2 * S1) {
    int which = idx / S1;  // 0: Wd1, 1: Wd2
    int jj = idx - which * S1;
    int l = jj / (128 * 128);
    int r = jj - l * (128 * 128);
    int c = r >> 7, k = r & 127;
    const float* W = (which == 0) ? Wd1 : Wd2;
    float v = W[(size_t)l * 128 * 128 + (size_t)k * 128 + c];
    bf16_t hv = (bf16_t)v;
    bf16_t lv = (bf16_t)(v - (float)hv);
    if (which == 0) { Wd1Thi[jj] = hv; Wd1Tlo[jj] = lv; }
    else            { Wd2Thi[jj] = hv; Wd2Tlo[jj] = lv; }
  }
}

// ================= node encoder ============================================
__global__ __launch_bounds__(256) void k_enc1(const float* __restrict__ x,
    const float* __restrict__ We1, const float* __restrict__ be1,
    float* __restrict__ t, float* __restrict__ stats) {
  int c = threadIdx.x & 127;
  int half = threadIdx.x >> 7;
  float b = be1[c];
  float psum = 0.f, psq = 0.f;
  for (int n = blockIdx.x * 2 + half; n < NN; n += gridDim.x * 2) {
    const float* xr = x + (size_t)n * XD;
    float v = b;
#pragma unroll
    for (int k = 0; k < XD; ++k) v = fmaf(xr[k], We1[k * HID + c], v);
    t[(size_t)n * HID + c] = v;
    psum += v; psq += v * v;
  }
  __shared__ float s0[256], s1[256];
  s0[threadIdx.x] = psum; s1[threadIdx.x] = psq;
  __syncthreads();
  if (threadIdx.x < 128) {
    atomicAdd(&stats[threadIdx.x], s0[threadIdx.x] + s0[threadIdx.x + 128]);
    atomicAdd(&stats[128 + threadIdx.x], s1[threadIdx.x] + s1[threadIdx.x + 128]);
  }
}

__global__ __launch_bounds__(128) void k_bn_fin(const float* __restrict__ gamma,
    const float* __restrict__ beta, float* __restrict__ stats, int C, float invn) {
  int c = threadIdx.x;
  if (c < C) {
    float mean = stats[c] * invn;
    float var = stats[128 + c] * invn - mean * mean;
    float a = gamma[c] * rsqrtf(var + EPSF);
    stats[256 + c] = a;
    stats[384 + c] = beta[c] - mean * a;
  }
}

__global__ __launch_bounds__(128) void k_enc2(const float* __restrict__ t,
    const float* __restrict__ stats, const float* __restrict__ We2,
    const float* __restrict__ be2, float* __restrict__ h,
    unsigned int* __restrict__ hbf) {
  __shared__ float r[HID];
  int c = threadIdx.x;
  float a = stats[256 + c], b = stats[384 + c];
  float bias = be2[c];
  for (int n = blockIdx.x; n < NN; n += gridDim.x) {
    float v = fmaf(t[(size_t)n * HID + c], a, b);
    r[c] = fmaxf(v, 0.f);
    __syncthreads();
    float acc = bias;
#pragma unroll 8
    for (int k = 0; k < HID; ++k) acc = fmaf(r[k], We2[k * HID + c], acc);
    h[(size_t)n * HID + c] = acc;
    float o = __shfl_down(acc, 1);
    if ((c & 1) == 0) hbf[(size_t)n * 64 + (c >> 1)] = pack_bf2(acc, o);
    __syncthreads();
  }
}

// ================= gaussian smearing (ea output) ===========================
__global__ __launch_bounds__(256) void k_smear(const float* __restrict__ eattr,
    float* __restrict__ ea) {
  int idx = blockIdx.x * 256 + threadIdx.x;
  if (idx >= NE * NG) return;
  int e = idx / NG;
  int g = idx - e * NG;
  float ax = eattr[(size_t)e * 3], ay = eattr[(size_t)e * 3 + 1], az = eattr[(size_t)e * 3 + 2];
  float d = sqrtf(ax * ax + ay * ay + az * az);
  float off = (10.0f / 49.0f) * (float)g;
  float z = d - off;
  ea[idx] = __expf(-12.005f * z * z);
}

// ================= fused layer kernel ======================================
// Block = 16 dest nodes, 256 threads = 4 waves.
// Phase 1: lane owns 2 cols; bf16-packed h gather (4 B/lane/edge) + packed
//   tab lerp; register run-accumulation; LDS-atomic flush -> agg_s.
// Phase 2: agg_s -> bf16 hi/lo; 2 MFMA GEMMs; hout = hin + MLP(agg); also
//   writes bf16-packed hout for the next layer's gather.
// LDS: t1hi/t1lo alias agg_s (dead after the split) -> 17.4 KB/block.
__global__ __launch_bounds__(256) void k_layer(
    const int4* __restrict__ metap, const int* __restrict__ rowptr,
    const float* __restrict__ hin, const unsigned int* __restrict__ hbf,
    const unsigned int* __restrict__ tabp,
    const bf16_t* __restrict__ Wd1Thi, const bf16_t* __restrict__ Wd1Tlo,
    const bf16_t* __restrict__ Wd2Thi, const bf16_t* __restrict__ Wd2Tlo,
    const float* __restrict__ bd1, const float* __restrict__ bd2,
    float* __restrict__ hout, unsigned int* __restrict__ hbfo) {
  __shared__ __align__(16) char up[8704];          // agg_s  ∪  (t1hi,t1lo)
  float (*agg_s)[HID] = (float(*)[HID])up;
  bf16_t (*t1hi)[136] = (bf16_t(*)[136])up;
  bf16_t (*t1lo)[136] = (bf16_t(*)[136])(up + 4352);
  __shared__ __align__(16) bf16_t ahi_s[16][136];
  __shared__ __align__(16) bf16_t alo_s[16][136];

  const int tid = threadIdx.x;
  const int lane = tid & 63;
  const int w = tid >> 6;
  const int c0 = lane * 2;
  const int nb = blockIdx.x * 16;
  const int eS = rowptr[nb], eE = rowptr[nb + 16];

  for (int i = tid; i < 16 * HID; i += 256) ((float*)agg_s)[i] = 0.f;
  __syncthreads();

  // ---------------- phase 1: edges ----------------
  {
    const int Q = (eE - eS + 3) >> 2;
    int e = eS + w * Q;
    const int wE = min(e + Q, eE);

    float acc0 = 0.f, acc1 = 0.f;
    int cur = -1;

    auto body = [&](const int4& m, unsigned hv, const uint2& uv) {
      float fr = __int_as_float(m.y);
      int dst = m.w - nb;
      float ha = __uint_as_float(hv << 16);
      float hb = __uint_as_float(hv & 0xffff0000u);
      float w0a = __uint_as_float((uv.x & 0xffffu) << 16);
      float w1a = __uint_as_float(uv.x & 0xffff0000u);
      float w0b = __uint_as_float((uv.y & 0xffffu) << 16);
      float w1b = __uint_as_float(uv.y & 0xffff0000u);
      float ma = fmaf(fr, w1a - w0a, w0a) * ha;
      float mb = fmaf(fr, w1b - w0b, w0b) * hb;
      if (dst != cur) {
        if (cur >= 0) {
          atomicAdd(&agg_s[cur][c0], acc0);
          atomicAdd(&agg_s[cur][c0 + 1], acc1);
        }
        cur = dst; acc0 = ma; acc1 = mb;
      } else {
        acc0 += ma; acc1 += mb;
      }
    };

    if (wE - e >= 4) {
      int4 m0 = metap[e], m1 = metap[e + 1], m2 = metap[e + 2], m3 = metap[e + 3];
      int ep = e + 4;
      while (true) {
        unsigned h0 = hbf[(size_t)m0.z * 64 + lane];
        unsigned h1 = hbf[(size_t)m1.z * 64 + lane];
        unsigned h2 = hbf[(size_t)m2.z * 64 + lane];
        unsigned h3 = hbf[(size_t)m3.z * 64 + lane];
        uint2 t0 = *(const uint2*)(tabp + (size_t)m0.x * HID + c0);
        uint2 t1 = *(const uint2*)(tabp + (size_t)m1.x * HID + c0);
        uint2 t2 = *(const uint2*)(tabp + (size_t)m2.x * HID + c0);
        uint2 t3 = *(const uint2*)(tabp + (size_t)m3.x * HID + c0);
        const bool more = (ep + 4 <= wE);
        int4 n0, n1, n2, n3;
        if (more) {
          n0 = metap[ep]; n1 = metap[ep + 1]; n2 = metap[ep + 2]; n3 = metap[ep + 3];
        }
        body(m0, h0, t0); body(m1, h1, t1); body(m2, h2, t2); body(m3, h3, t3);
        if (!more) break;
        m0 = n0; m1 = n1; m2 = n2; m3 = n3;
        ep += 4;
      }
      e = ep;
    }
    for (; e < wE; ++e) {
      int4 m = metap[e];
      unsigned hv = hbf[(size_t)m.z * 64 + lane];
      uint2 uv = *(const uint2*)(tabp + (size_t)m.x * HID + c0);
      body(m, hv, uv);
    }
    if (cur >= 0) {
      atomicAdd(&agg_s[cur][c0], acc0);
      atomicAdd(&agg_s[cur][c0 + 1], acc1);
    }
  }
  __syncthreads();

  // ---------------- phase 2: node MLP on agg_s ----------------
  for (int i = tid; i < 16 * 128; i += 256) {
    int r = i >> 7, k = i & 127;
    float v = agg_s[r][k];
    bf16_t hv = (bf16_t)v;
    ahi_s[r][k] = hv;
    alo_s[r][k] = (bf16_t)(v - (float)hv);
  }
  __syncthreads();  // agg_s dead; t1hi/t1lo may now overwrite it

  const int lm = lane & 15;
  const int lk = lane >> 4;
  const int colb = w * 32;
  const int k0base = lk * 8;

  // GEMM1: t1 = relu(agg @ Wd1 + bd1)
  f32x4 acc1g[2];
  acc1g[0] = (f32x4){0.f, 0.f, 0.f, 0.f};
  acc1g[1] = (f32x4){0.f, 0.f, 0.f, 0.f};
#pragma unroll
  for (int s = 0; s < 4; ++s) {
    int k0 = s * 32 + k0base;
    bf16x8 Ahi = *(const bf16x8*)&ahi_s[lm][k0];
    bf16x8 Alo = *(const bf16x8*)&alo_s[lm][k0];
#pragma unroll
    for (int cf = 0; cf < 2; ++cf) {
      int cc = colb + cf * 16 + lm;
      bf16x8 Bh = *(const bf16x8*)(Wd1Thi + (size_t)cc * 128 + k0);
      bf16x8 Bl = *(const bf16x8*)(Wd1Tlo + (size_t)cc * 128 + k0);
      acc1g[cf] = __builtin_amdgcn_mfma_f32_16x16x32_bf16(Ahi, Bh, acc1g[cf], 0, 0, 0);
      acc1g[cf] = __builtin_amdgcn_mfma_f32_16x16x32_bf16(Ahi, Bl, acc1g[cf], 0, 0, 0);
      acc1g[cf] = __builtin_amdgcn_mfma_f32_16x16x32_bf16(Alo, Bh, acc1g[cf], 0, 0, 0);
    }
  }
#pragma unroll
  for (int cf = 0; cf < 2; ++cf) {
    int cc = colb + cf * 16 + lm;
    float bias1 = bd1[cc];
#pragma unroll
    for (int j = 0; j < 4; ++j) {
      int r = lk * 4 + j;
      float v = fmaxf(acc1g[cf][j] + bias1, 0.f);
      bf16_t hv = (bf16_t)v;
      t1hi[r][cc] = hv;
      t1lo[r][cc] = (bf16_t)(v - (float)hv);
    }
  }
  __syncthreads();

  // GEMM2: out = t1 @ Wd2 + bd2;  hout = hin + out (+ packed bf16 copy)
  f32x4 acc2g[2];
  acc2g[0] = (f32x4){0.f, 0.f, 0.f, 0.f};
  acc2g[1] = (f32x4){0.f, 0.f, 0.f, 0.f};
#pragma unroll
  for (int s = 0; s < 4; ++s) {
    int k0 = s * 32 + k0base;
    bf16x8 Ahi = *(const bf16x8*)&t1hi[lm][k0];
    bf16x8 Alo = *(const bf16x8*)&t1lo[lm][k0];
#pragma unroll
    for (int cf = 0; cf < 2; ++cf) {
      int cc = colb + cf * 16 + lm;
      bf16x8 Bh = *(const bf16x8*)(Wd2Thi + (size_t)cc * 128 + k0);
      bf16x8 Bl = *(const bf16x8*)(Wd2Tlo + (size_t)cc * 128 + k0);
      acc2g[cf] = __builtin_amdgcn_mfma_f32_16x16x32_bf16(Ahi, Bh, acc2g[cf], 0, 0, 0);
      acc2g[cf] = __builtin_amdgcn_mfma_f32_16x16x32_bf16(Ahi, Bl, acc2g[cf], 0, 0, 0);
      acc2g[cf] = __builtin_amdgcn_mfma_f32_16x16x32_bf16(Alo, Bh, acc2g[cf], 0, 0, 0);
    }
  }
#pragma unroll
  for (int cf = 0; cf < 2; ++cf) {
    int cc = colb + cf * 16 + lm;
    float bias2 = bd2[cf ? cc : cc];  // keep simple
#pragma unroll
    for (int j = 0; j < 4; ++j) {
      int r = nb + lk * 4 + j;
      float val = hin[(size_t)r * HID + cc] + acc2g[cf][j] + bias2;
      hout[(size_t)r * HID + cc] = val;
      float o = __shfl_xor(val, 1);
      if ((lm & 1) == 0) hbfo[(size_t)r * 64 + (cc >> 1)] = pack_bf2(val, o);
    }
  }
}

// ================= global MLP ==============================================
__global__ __launch_bounds__(128) void k_global(const float* __restrict__ u,
    const float* __restrict__ Wg1, const float* __restrict__ bg1,
    const float* __restrict__ gg1, const float* __restrict__ btg1,
    const float* __restrict__ Wg2, const float* __restrict__ bg2,
    float* __restrict__ u_p) {
  __shared__ float t_s[NGR][HID];
  int c = threadIdx.x;
  for (int g = 0; g < NGR; ++g) {
    float v = bg1[c];
#pragma unroll
    for (int k = 0; k < GD; ++k) v = fmaf(u[(size_t)g * GD + k], Wg1[k * HID + c], v);
    t_s[g][c] = v;
  }
  float sum = 0.f, sq = 0.f;
  for (int g = 0; g < NGR; ++g) { float v = t_s[g][c]; sum += v; sq += v * v; }
  float mean = sum * (1.f / NGR);
  float var = sq * (1.f / NGR) - mean * mean;
  float a = gg1[c] * rsqrtf(var + EPSF);
  float b = btg1[c] - mean * a;
  for (int g = 0; g < NGR; ++g) t_s[g][c] = fmaxf(fmaf(t_s[g][c], a, b), 0.f);
  __syncthreads();
  for (int g = 0; g < NGR; ++g) {
    float acc = bg2[c];
#pragma unroll 8
    for (int k = 0; k < HID; ++k) acc = fmaf(t_s[g][k], Wg2[k * HID + c], acc);
    u_p[(size_t)g * HID + c] = acc;
  }
}

// ================= shift head ==============================================
__global__ __launch_bounds__(256) void k_shift1(
    const float* __restrict__ h, const float* __restrict__ u_p,
    const int* __restrict__ batch, const float* __restrict__ Ws1,
    const float* __restrict__ bs1, float* __restrict__ t1, float* __restrict__ stats) {
  __shared__ float s_in[16][2 * HID];
  const int c = threadIdx.x & 63;
  const int ng = threadIdx.x >> 6;
  float psum = 0.f, psq = 0.f;
  for (int tile = blockIdx.x; tile < NN / 16; tile += gridDim.x) {
    const int nb = tile * 16;
    for (int i = threadIdx.x; i < 16 * HID; i += 256) {
      int ln = i >> 7, k = i & 127;
      s_in[ln][k] = h[(size_t)(nb + ln) * HID + k];
      s_in[ln][HID + k] = u_p[(size_t)batch[nb + ln] * HID + k];
    }
    __syncthreads();
    float acc[4];
#pragma unroll
    for (int j = 0; j < 4; ++j) acc[j] = bs1[c];
    for (int k = 0; k < 2 * HID; ++k) {
      float w = Ws1[k * SH + c];
#pragma unroll
      for (int j = 0; j < 4; ++j) acc[j] = fmaf(s_in[ng * 4 + j][k], w, acc[j]);
    }
#pragma unroll
    for (int j = 0; j < 4; ++j) {
      t1[(size_t)(nb + ng * 4 + j) * SH + c] = acc[j];
      psum += acc[j]; psq += acc[j] * acc[j];
    }
    __syncthreads();
  }
  __shared__ float rs[256], rq[256];
  rs[threadIdx.x] = psum; rq[threadIdx.x] = psq;
  __syncthreads();
  if (threadIdx.x < 64) {
    int c2 = threadIdx.x;
    atomicAdd(&stats[c2], rs[c2] + rs[c2 + 64] + rs[c2 + 128] + rs[c2 + 192]);
    atomicAdd(&stats[128 + c2], rq[c2] + rq[c2 + 64] + rq[c2 + 128] + rq[c2 + 192]);
  }
}

__global__ __launch_bounds__(256) void k_shift2(
    const float* __restrict__ t1, float* __restrict__ stats,
    const float* __restrict__ Ws2, const float* __restrict__ bs2,
    float* __restrict__ t2) {
  __shared__ float r_s[16][SH];
  const int c = threadIdx.x & 63;
  const int ng = threadIdx.x >> 6;
  float psum = 0.f, psq = 0.f;
  for (int tile = blockIdx.x; tile < NN / 16; tile += gridDim.x) {
    const int nb = tile * 16;
    for (int i = threadIdx.x; i < 16 * SH; i += 256) {
      int ln = i >> 6, k = i & 63;
      float v = fmaf(t1[(size_t)(nb + ln) * SH + k], stats[256 + k], stats[384 + k]);
      r_s[ln][k] = fmaxf(v, 0.f);
    }
    __syncthreads();
    float acc[4];
#pragma unroll
    for (int j = 0; j < 4; ++j) acc[j] = bs2[c];
    for (int k = 0; k < SH; ++k) {
      float w = Ws2[k * SH + c];
#pragma unroll
      for (int j = 0; j < 4; ++j) acc[j] = fmaf(r_s[ng * 4 + j][k], w, acc[j]);
    }
#pragma unroll
    for (int j = 0; j < 4; ++j) {
      t2[(size_t)(nb + ng * 4 + j) * SH + c] = acc[j];
      psum += acc[j]; psq += acc[j] * acc[j];
    }
    __syncthreads();
  }
  __shared__ float rs[256], rq[256];
  rs[threadIdx.x] = psum; rq[threadIdx.x] = psq;
  __syncthreads();
  if (threadIdx.x < 64) {
    int c2 = threadIdx.x;
    atomicAdd(&stats[c2], rs[c2] + rs[c2 + 64] + rs[c2 + 128] + rs[c2 + 192]);
    atomicAdd(&stats[128 + c2], rq[c2] + rq[c2 + 64] + rq[c2 + 128] + rq[c2 + 192]);
  }
}

__global__ __launch_bounds__(256) void k_shift3(
    const float* __restrict__ t2, const float* __restrict__ stats,
    const float* __restrict__ Ws3, const float* __restrict__ bs3,
    float* __restrict__ shifts) {
  int lane = threadIdx.x & 63;
  int n = blockIdx.x * 4 + (threadIdx.x >> 6);
  if (n >= NN) return;
  float a = stats[256 + lane], b = stats[384 + lane];
  float r = fmaxf(fmaf(t2[(size_t)n * SH + lane], a, b), 0.f);
  float v = r * Ws3[lane];
#pragma unroll
  for (int off = 32; off; off >>= 1) v += __shfl_down(v, off);
  if (lane == 0) shifts[n] = v + bs3[0];
}

extern "C" void kernel_launch(void* const* d_in, const int* in_sizes, int n_in,
                              void* d_out, int out_size, void* d_ws, size_t ws_size,
                              hipStream_t stream) {
  const float* x     = (const float*)d_in[0];
  const int*   ei    = (const int*)d_in[1];
  const float* eattr = (const float*)d_in[2];
  const int*   batch = (const int*)d_in[3];
  const float* u     = (const float*)d_in[4];
  const float* We1 = (const float*)d_in[5];  const float* be1 = (const float*)d_in[6];
  const float* ge1 = (const float*)d_in[7];  const float* bte1 = (const float*)d_in[8];
  const float* We2 = (const float*)d_in[9];  const float* be2 = (const float*)d_in[10];
  const float* Wf1 = (const float*)d_in[11]; const float* bf1 = (const float*)d_in[12];
  const float* Wf2 = (const float*)d_in[13]; const float* bf2 = (const float*)d_in[14];
  const float* Wd1 = (const float*)d_in[15]; const float* bd1 = (const float*)d_in[16];
  const float* Wd2 = (const float*)d_in[17]; const float* bd2 = (const float*)d_in[18];
  const float* Wg1 = (const float*)d_in[19]; const float* bg1 = (const float*)d_in[20];
  const float* gg1 = (const float*)d_in[21]; const float* btg1 = (const float*)d_in[22];
  const float* Wg2 = (const float*)d_in[23]; const float* bg2 = (const float*)d_in[24];
  const float* Ws1 = (const float*)d_in[25]; const float* bs1 = (const float*)d_in[26];
  const float* gs1 = (const float*)d_in[27]; const float* bts1 = (const float*)d_in[28];
  const float* Ws2 = (const float*)d_in[29]; const float* bs2 = (const float*)d_in[30];
  const float* gs2 = (const float*)d_in[31]; const float* bts2 = (const float*)d_in[32];
  const float* Ws3 = (const float*)d_in[33]; const float* bs3 = (const float*)d_in[34];

  float* out    = (float*)d_out;
  float* shifts = out;                    // [NN]
  float* h      = out + NN;               // [NN,HID]
  float* ea     = out + NN + NN * HID;    // [NE,NG]
  float* u_p    = out + NN + NN * HID + (size_t)NE * NG;  // [NGR,HID]

  // workspace layout
  char* wsb = (char*)d_ws;
  size_t off = 0;
  auto alloc = [&](size_t bytes) { void* p = wsb + off; off = (off + bytes + 255) & ~(size_t)255; return p; };
  float*  stats    = (float*)alloc(512 * sizeof(float));
  int*    hist     = (int*)alloc((size_t)NN * sizeof(int));
  int*    rowptr   = (int*)alloc((size_t)(NN + 1) * sizeof(int));
  int4*   metap    = (int4*)alloc((size_t)NE * sizeof(int4));
  unsigned int* tabp = (unsigned int*)alloc((size_t)NL * TBL * HID * sizeof(unsigned int));
  bf16_t* Wd1Thi   = (bf16_t*)alloc((size_t)NL * 128 * 128 * sizeof(bf16_t));
  bf16_t* Wd1Tlo   = (bf16_t*)alloc((size_t)NL * 128 * 128 * sizeof(bf16_t));
  bf16_t* Wd2Thi   = (bf16_t*)alloc((size_t)NL * 128 * 128 * sizeof(bf16_t));
  bf16_t* Wd2Tlo   = (bf16_t*)alloc((size_t)NL * 128 * 128 * sizeof(bf16_t));
  float*  hwork    = (float*)alloc((size_t)NN * HID * sizeof(float));
  unsigned int* hbfA = (unsigned int*)alloc((size_t)NN * 64 * sizeof(unsigned int));
  unsigned int* hbfB = (unsigned int*)alloc((size_t)NN * 64 * sizeof(unsigned int));
  float*  buf1     = (float*)alloc((size_t)NN * HID * sizeof(float));
  float* t1 = buf1;
  float* t2 = buf1 + (size_t)NN * SH;

  const int* row = ei;        // source j
  const int* col = ei + NE;   // target i

  // ---- CSR build + edge meta + table + node-weight prep
  hipMemsetAsync(hist, 0, (size_t)NN * sizeof(int), stream);
  k_hist<<<512, 256, 0, stream>>>(col, hist);
  k_scan<<<1, 1024, 0, stream>>>(hist, rowptr);
  k_scatter2<<<512, 256, 0, stream>>>(col, row, eattr, hist, metap);
  k_tabbuild3<<<NL * (TBL / 8), 128, 0, stream>>>(Wf1, bf1, Wf2, bf2, tabp);
  k_prepw<<<(2 * NL * 128 * 128 + 255) / 256, 256, 0, stream>>>(
      Wd1, Wd2, Wd1Thi, Wd1Tlo, Wd2Thi, Wd2Tlo);

  // ---- node encoder
  hipMemsetAsync(stats, 0, 256 * sizeof(float), stream);
  k_enc1<<<512, 256, 0, stream>>>(x, We1, be1, buf1, stats);
  k_bn_fin<<<1, 128, 0, stream>>>(ge1, bte1, stats, 128, 1.f / NN);
  k_enc2<<<2048, 128, 0, stream>>>(buf1, stats, We2, be2, h, hbfA);

  // ---- gaussian smearing (ea output)
  k_smear<<<(NE * NG + 255) / 256, 256, 0, stream>>>(eattr, ea);

  // ---- interaction layers (fused edge+node, ping-pong h and hbf)
  for (int l = 0; l < NL; ++l) {
    const float* hi = (l & 1) ? hwork : h;
    float*       ho = (l & 1) ? h : hwork;
    const unsigned int* bi = (l & 1) ? hbfB : hbfA;
    unsigned int*       bo = (l & 1) ? hbfA : hbfB;
    k_layer<<<NN / 16, 256, 0, stream>>>(
        metap, rowptr, hi, bi, tabp + (size_t)l * TBL * HID,
        Wd1Thi + (size_t)l * 128 * 128, Wd1Tlo + (size_t)l * 128 * 128,
        Wd2Thi + (size_t)l * 128 * 128, Wd2Tlo + (size_t)l * 128 * 128,
        bd1 + (size_t)l * HID, bd2 + (size_t)l * HID, ho, bo);
  }
  // NL=6 (even) -> final h lands back in the output slot `h`

  // ---- global MLP
  k_global<<<1, 128, 0, stream>>>(u, Wg1, bg1, gg1, btg1, Wg2, bg2, u_p);

  // ---- shift head
  hipMemsetAsync(stats, 0, 256 * sizeof(float), stream);
  k_shift1<<<1024, 256, 0, stream>>>(h, u_p, batch, Ws1, bs1, t1, stats);
  k_bn_fin<<<1, 128, 0, stream>>>(gs1, bts1, stats, 64, 1.f / NN);
  hipMemsetAsync(stats, 0, 256 * sizeof(float), stream);
  k_shift2<<<1024, 256, 0, stream>>>(t1, stats, Ws2, bs2, t2);
  k_bn_fin<<<1, 128, 0, stream>>>(gs2, bts2, stats, 64, 1.f / NN);
  k_shift3<<<(NN + 3) / 4, 256, 0, stream>>>(t2, stats, Ws3, bs3, shifts);
}

// Round 10
// 1751.548 us; speedup vs baseline: 3.9828x; 1.0866x over previous
//
#include <hip/hip_runtime.h>

#define NN 50000
#define NE 1600000
#define NGR 64
#define XD 32
#define HID 128
#define NF 128
#define NG 50
#define GD 16
#define NL 6
#define SH 64
#define EPSF 1e-5f
#define TBL 4096          // filter table knots
#define INVSTEP 320.0f    // 1/step; covers d in [0, 12.8]

typedef __bf16 bf16_t;
typedef bf16_t bf16x8 __attribute__((ext_vector_type(8)));
typedef float f32x4 __attribute__((ext_vector_type(4)));

__device__ __forceinline__ unsigned pack_bf2(float a, float b) {
  unsigned short ua = __builtin_bit_cast(unsigned short, (bf16_t)a);
  unsigned short ub = __builtin_bit_cast(unsigned short, (bf16_t)b);
  return (unsigned)ua | ((unsigned)ub << 16);
}
__device__ __forceinline__ float bflo(unsigned u) { return __uint_as_float(u << 16); }
__device__ __forceinline__ float bfhi(unsigned u) { return __uint_as_float(u & 0xffff0000u); }
__device__ __forceinline__ float blerp(unsigned u, float fr) {
  float w0 = bflo(u), w1 = bfhi(u);
  return fmaf(fr, w1 - w0, w0);
}

// ================= CSR build (once; col constant across layers) ============
__global__ __launch_bounds__(256) void k_hist(const int* __restrict__ col,
                                              int* __restrict__ hist) {
  for (int e = blockIdx.x * 256 + threadIdx.x; e < NE; e += gridDim.x * 256)
    atomicAdd(&hist[col[e]], 1);
}

__global__ __launch_bounds__(1024) void k_scan(int* __restrict__ hist,
                                               int* __restrict__ rowptr) {
  const int tid = threadIdx.x;
  const int CH = 49;
  const int base = tid * CH;
  int s = 0;
  for (int i = 0; i < CH; ++i) {
    int idx = base + i;
    if (idx < NN) s += hist[idx];
  }
  __shared__ int part[1024];
  part[tid] = s;
  __syncthreads();
  for (int off = 1; off < 1024; off <<= 1) {
    int v = (tid >= off) ? part[tid - off] : 0;
    __syncthreads();
    part[tid] += v;
    __syncthreads();
  }
  int run = part[tid] - s;
  for (int i = 0; i < CH; ++i) {
    int idx = base + i;
    if (idx < NN) {
      int c = hist[idx];
      rowptr[idx] = run;
      hist[idx] = run;
      run += c;
    }
  }
  if (tid == 0) rowptr[NN] = NE;
}

// scatter + per-edge packed meta: metap[pos] = (row<<16 | idx<<4 | dst&15, frac)
__global__ __launch_bounds__(256) void k_scatter2(const int* __restrict__ col,
    const int* __restrict__ row, const float* __restrict__ eattr,
    int* __restrict__ cursor, uint2* __restrict__ metap) {
  for (int e = blockIdx.x * 256 + threadIdx.x; e < NE; e += gridDim.x * 256) {
    float ax = eattr[(size_t)e * 3], ay = eattr[(size_t)e * 3 + 1], az = eattr[(size_t)e * 3 + 2];
    float d = sqrtf(ax * ax + ay * ay + az * az);
    float tt = fminf(d * INVSTEP, (float)(TBL - 2) + 0.999f);
    int id = (int)tt;
    int c = col[e];
    int pos = atomicAdd(&cursor[c], 1);
    unsigned mw = ((unsigned)row[e] << 16) | ((unsigned)id << 4) | (unsigned)(c & 15);
    metap[pos] = make_uint2(mw, __float_as_uint(tt - (float)id));
  }
}

// ================= filter table build (packed bf16 pairs, direct) ==========
__global__ __launch_bounds__(128) void k_tabbuild3(
    const float* __restrict__ Wf1, const float* __restrict__ bf1,
    const float* __restrict__ Wf2, const float* __restrict__ bf2,
    unsigned int* __restrict__ tabp) {
  const int bid = blockIdx.x;            // 0 .. NL*(TBL/8)-1
  const int l = bid / (TBL / 8);
  const int t0 = (bid - l * (TBL / 8)) * 8;
  const int c = threadIdx.x;
  __shared__ float g_s[9][NG];
  __shared__ float f1_s[9][NF];
  for (int i = c; i < 9 * NG; i += 128) {
    int kk = i / NG, g = i - kk * NG;
    int t = min(t0 + kk, TBL - 1);
    float d = (float)t * (1.0f / INVSTEP);
    float z = d - 0.2040816327f * (float)g;
    g_s[kk][g] = expf(-12.005f * z * z);
  }
  __syncthreads();
  const float* W1 = Wf1 + (size_t)l * NG * NF;
  float f1r[9];
#pragma unroll
  for (int kk = 0; kk < 9; ++kk) f1r[kk] = bf1[(size_t)l * NF + c];
  for (int g = 0; g < NG; ++g) {
    float w = W1[g * NF + c];
#pragma unroll
    for (int kk = 0; kk < 9; ++kk) f1r[kk] = fmaf(g_s[kk][g], w, f1r[kk]);
  }
#pragma unroll
  for (int kk = 0; kk < 9; ++kk) f1_s[kk][c] = fmaxf(f1r[kk], 0.f);
  __syncthreads();
  const float* W2 = Wf2 + (size_t)l * NF * NF;
  float outr[9];
#pragma unroll
  for (int kk = 0; kk < 9; ++kk) outr[kk] = bf2[(size_t)l * NF + c];
  for (int k = 0; k < NF; ++k) {
    float w = W2[k * NF + c];
#pragma unroll
    for (int kk = 0; kk < 9; ++kk) outr[kk] = fmaf(f1_s[kk][k], w, outr[kk]);
  }
#pragma unroll
  for (int kk = 0; kk < 8; ++kk)
    tabp[((size_t)l * TBL + t0 + kk) * NF + c] = pack_bf2(outr[kk], outr[kk + 1]);
}

// ================= weight prep for node MLP (transpose + split hi/lo) ======
__global__ __launch_bounds__(256) void k_prepw(const float* __restrict__ Wd1,
    const float* __restrict__ Wd2,
    bf16_t* __restrict__ Wd1Thi, bf16_t* __restrict__ Wd1Tlo,
    bf16_t* __restrict__ Wd2Thi, bf16_t* __restrict__ Wd2Tlo) {
  const int S1 = NL * 128 * 128;
  int idx = blockIdx.x * 256 + threadIdx.x;
  if (idx < 2 * S1) {
    int which = idx / S1;  // 0: Wd1, 1: Wd2
    int jj = idx - which * S1;
    int l = jj / (128 * 128);
    int r = jj - l * (128 * 128);
    int c = r >> 7, k = r & 127;
    const float* W = (which == 0) ? Wd1 : Wd2;
    float v = W[(size_t)l * 128 * 128 + (size_t)k * 128 + c];
    bf16_t hv = (bf16_t)v;
    bf16_t lv = (bf16_t)(v - (float)hv);
    if (which == 0) { Wd1Thi[jj] = hv; Wd1Tlo[jj] = lv; }
    else            { Wd2Thi[jj] = hv; Wd2Tlo[jj] = lv; }
  }
}

// ================= node encoder ============================================
__global__ __launch_bounds__(256) void k_enc1(const float* __restrict__ x,
    const float* __restrict__ We1, const float* __restrict__ be1,
    float* __restrict__ t, float* __restrict__ stats) {
  int c = threadIdx.x & 127;
  int half = threadIdx.x >> 7;
  float b = be1[c];
  float psum = 0.f, psq = 0.f;
  for (int n = blockIdx.x * 2 + half; n < NN; n += gridDim.x * 2) {
    const float* xr = x + (size_t)n * XD;
    float v = b;
#pragma unroll
    for (int k = 0; k < XD; ++k) v = fmaf(xr[k], We1[k * HID + c], v);
    t[(size_t)n * HID + c] = v;
    psum += v; psq += v * v;
  }
  __shared__ float s0[256], s1[256];
  s0[threadIdx.x] = psum; s1[threadIdx.x] = psq;
  __syncthreads();
  if (threadIdx.x < 128) {
    atomicAdd(&stats[threadIdx.x], s0[threadIdx.x] + s0[threadIdx.x + 128]);
    atomicAdd(&stats[128 + threadIdx.x], s1[threadIdx.x] + s1[threadIdx.x + 128]);
  }
}

__global__ __launch_bounds__(128) void k_bn_fin(const float* __restrict__ gamma,
    const float* __restrict__ beta, float* __restrict__ stats, int C, float invn) {
  int c = threadIdx.x;
  if (c < C) {
    float mean = stats[c] * invn;
    float var = stats[128 + c] * invn - mean * mean;
    float a = gamma[c] * rsqrtf(var + EPSF);
    stats[256 + c] = a;
    stats[384 + c] = beta[c] - mean * a;
  }
}

__global__ __launch_bounds__(128) void k_enc2(const float* __restrict__ t,
    const float* __restrict__ stats, const float* __restrict__ We2,
    const float* __restrict__ be2, float* __restrict__ h,
    unsigned int* __restrict__ hbf) {
  __shared__ float r[HID];
  int c = threadIdx.x;
  float a = stats[256 + c], b = stats[384 + c];
  float bias = be2[c];
  for (int n = blockIdx.x; n < NN; n += gridDim.x) {
    float v = fmaf(t[(size_t)n * HID + c], a, b);
    r[c] = fmaxf(v, 0.f);
    __syncthreads();
    float acc = bias;
#pragma unroll 8
    for (int k = 0; k < HID; ++k) acc = fmaf(r[k], We2[k * HID + c], acc);
    h[(size_t)n * HID + c] = acc;
    float o = __shfl_down(acc, 1);
    if ((c & 1) == 0) hbf[(size_t)n * 64 + (c >> 1)] = pack_bf2(acc, o);
    __syncthreads();
  }
}

// ================= gaussian smearing (ea output) ===========================
__global__ __launch_bounds__(256) void k_smear(const float* __restrict__ eattr,
    float* __restrict__ ea) {
  int idx = blockIdx.x * 256 + threadIdx.x;
  if (idx >= NE * NG) return;
  int e = idx / NG;
  int g = idx - e * NG;
  float ax = eattr[(size_t)e * 3], ay = eattr[(size_t)e * 3 + 1], az = eattr[(size_t)e * 3 + 2];
  float d = sqrtf(ax * ax + ay * ay + az * az);
  float off = (10.0f / 49.0f) * (float)g;
  float z = d - off;
  ea[idx] = __expf(-12.005f * z * z);
}

// ================= fused layer kernel ======================================
// Block = 16 dest nodes, 256 threads = 4 waves.
// Phase 1 (edge): HALF-WAVE per edge — lane owns 4 cols (lane&31)*4; each
//   wave processes 2 edges per step (1 mem-inst serves 2 edges). Packed 8B
//   meta; register run-accumulation; LDS-atomic flush -> agg_s.
// Phase 2 (node): agg_s -> bf16 hi/lo; 2 MFMA GEMMs; hout = hin + MLP(agg);
//   writes bf16-packed hout for the next layer's gather.
__global__ __launch_bounds__(256) void k_layer(
    const uint2* __restrict__ metap, const int* __restrict__ rowptr,
    const float* __restrict__ hin, const unsigned int* __restrict__ hbf,
    const unsigned int* __restrict__ tabp,
    const bf16_t* __restrict__ Wd1Thi, const bf16_t* __restrict__ Wd1Tlo,
    const bf16_t* __restrict__ Wd2Thi, const bf16_t* __restrict__ Wd2Tlo,
    const float* __restrict__ bd1, const float* __restrict__ bd2,
    float* __restrict__ hout, unsigned int* __restrict__ hbfo) {
  __shared__ __align__(16) char up[8704];          // agg_s  ∪  (t1hi,t1lo)
  float (*agg_s)[HID] = (float(*)[HID])up;
  bf16_t (*t1hi)[136] = (bf16_t(*)[136])up;
  bf16_t (*t1lo)[136] = (bf16_t(*)[136])(up + 4352);
  __shared__ __align__(16) bf16_t ahi_s[16][136];
  __shared__ __align__(16) bf16_t alo_s[16][136];

  const int tid = threadIdx.x;
  const int lane = tid & 63;
  const int w = tid >> 6;
  const int half = lane >> 5;          // which edge of the pair
  const int c0 = (lane & 31) * 4;      // 4 owned cols
  const int hoff = c0 >> 1;            // u32 index into hbf row
  const int nb = blockIdx.x * 16;
  const int eS = rowptr[nb], eE = rowptr[nb + 16];

  for (int i = tid; i < 16 * HID; i += 256) ((float*)agg_s)[i] = 0.f;
  __syncthreads();

  // ---------------- phase 1: edges (pairs) ----------------
  {
    const int Q = (eE - eS + 3) >> 2;
    int e = eS + w * Q;
    const int wE = min(e + Q, eE);

    float a0 = 0.f, a1 = 0.f, a2 = 0.f, a3 = 0.f;
    int cur = -1;

    auto flush = [&]() {
      if (cur >= 0) {
        atomicAdd(&agg_s[cur][c0], a0);
        atomicAdd(&agg_s[cur][c0 + 1], a1);
        atomicAdd(&agg_s[cur][c0 + 2], a2);
        atomicAdd(&agg_s[cur][c0 + 3], a3);
      }
    };
    auto pbody = [&](unsigned mw, float fr, const uint2& hv, const uint4& tv,
                     bool valid) {
      if (valid) {
        int dst = mw & 0xF;
        float m0 = blerp(tv.x, fr) * bflo(hv.x);
        float m1 = blerp(tv.y, fr) * bfhi(hv.x);
        float m2 = blerp(tv.z, fr) * bflo(hv.y);
        float m3 = blerp(tv.w, fr) * bfhi(hv.y);
        if (dst != cur) {
          flush();
          cur = dst; a0 = m0; a1 = m1; a2 = m2; a3 = m3;
        } else {
          a0 += m0; a1 += m1; a2 += m2; a3 += m3;
        }
      }
    };

    if (wE - e >= 4) {
      uint2 mA0 = metap[e], mB0 = metap[e + 1];
      uint2 mA1 = metap[e + 2], mB1 = metap[e + 3];
      int ep = e + 4;
      while (true) {
        unsigned mw0 = half ? mB0.x : mA0.x;
        float fr0 = __uint_as_float(half ? mB0.y : mA0.y);
        unsigned mw1 = half ? mB1.x : mA1.x;
        float fr1 = __uint_as_float(half ? mB1.y : mA1.y);
        uint2 hv0 = *(const uint2*)(hbf + (size_t)(mw0 >> 16) * 64 + hoff);
        uint4 tv0 = *(const uint4*)(tabp + (size_t)((mw0 >> 4) & 0xFFFu) * HID + c0);
        uint2 hv1 = *(const uint2*)(hbf + (size_t)(mw1 >> 16) * 64 + hoff);
        uint4 tv1 = *(const uint4*)(tabp + (size_t)((mw1 >> 4) & 0xFFFu) * HID + c0);
        const bool more = (ep + 4 <= wE);
        uint2 nA0, nB0, nA1, nB1;
        if (more) {
          nA0 = metap[ep]; nB0 = metap[ep + 1];
          nA1 = metap[ep + 2]; nB1 = metap[ep + 3];
        }
        pbody(mw0, fr0, hv0, tv0, true);
        pbody(mw1, fr1, hv1, tv1, true);
        if (!more) break;
        mA0 = nA0; mB0 = nB0; mA1 = nA1; mB1 = nB1;
        ep += 4;
      }
      e = ep;
    }
    for (; e < wE; e += 2) {
      bool v1 = (e + 1 < wE);
      uint2 mA = metap[e];
      uint2 mB = v1 ? metap[e + 1] : mA;
      unsigned mw = half ? mB.x : mA.x;
      float fr = __uint_as_float(half ? mB.y : mA.y);
      bool valid = (half == 0) || v1;
      uint2 hv = *(const uint2*)(hbf + (size_t)(mw >> 16) * 64 + hoff);
      uint4 tv = *(const uint4*)(tabp + (size_t)((mw >> 4) & 0xFFFu) * HID + c0);
      pbody(mw, fr, hv, tv, valid);
    }
    flush();
  }
  __syncthreads();

  // ---------------- phase 2: node MLP on agg_s ----------------
  for (int i = tid; i < 16 * 128; i += 256) {
    int r = i >> 7, k = i & 127;
    float v = agg_s[r][k];
    bf16_t hv = (bf16_t)v;
    ahi_s[r][k] = hv;
    alo_s[r][k] = (bf16_t)(v - (float)hv);
  }
  __syncthreads();  // agg_s dead; t1hi/t1lo may now overwrite it

  const int lm = lane & 15;
  const int lk = lane >> 4;
  const int colb = w * 32;
  const int k0base = lk * 8;

  // GEMM1: t1 = relu(agg @ Wd1 + bd1)
  f32x4 acc1g[2];
  acc1g[0] = (f32x4){0.f, 0.f, 0.f, 0.f};
  acc1g[1] = (f32x4){0.f, 0.f, 0.f, 0.f};
#pragma unroll
  for (int s = 0; s < 4; ++s) {
    int k0 = s * 32 + k0base;
    bf16x8 Ahi = *(const bf16x8*)&ahi_s[lm][k0];
    bf16x8 Alo = *(const bf16x8*)&alo_s[lm][k0];
#pragma unroll
    for (int cf = 0; cf < 2; ++cf) {
      int cc = colb + cf * 16 + lm;
      bf16x8 Bh = *(const bf16x8*)(Wd1Thi + (size_t)cc * 128 + k0);
      bf16x8 Bl = *(const bf16x8*)(Wd1Tlo + (size_t)cc * 128 + k0);
      acc1g[cf] = __builtin_amdgcn_mfma_f32_16x16x32_bf16(Ahi, Bh, acc1g[cf], 0, 0, 0);
      acc1g[cf] = __builtin_amdgcn_mfma_f32_16x16x32_bf16(Ahi, Bl, acc1g[cf], 0, 0, 0);
      acc1g[cf] = __builtin_amdgcn_mfma_f32_16x16x32_bf16(Alo, Bh, acc1g[cf], 0, 0, 0);
    }
  }
#pragma unroll
  for (int cf = 0; cf < 2; ++cf) {
    int cc = colb + cf * 16 + lm;
    float bias1 = bd1[cc];
#pragma unroll
    for (int j = 0; j < 4; ++j) {
      int r = lk * 4 + j;
      float v = fmaxf(acc1g[cf][j] + bias1, 0.f);
      bf16_t hv = (bf16_t)v;
      t1hi[r][cc] = hv;
      t1lo[r][cc] = (bf16_t)(v - (float)hv);
    }
  }
  __syncthreads();

  // GEMM2: out = t1 @ Wd2 + bd2;  hout = hin + out (+ packed bf16 copy)
  f32x4 acc2g[2];
  acc2g[0] = (f32x4){0.f, 0.f, 0.f, 0.f};
  acc2g[1] = (f32x4){0.f, 0.f, 0.f, 0.f};
#pragma unroll
  for (int s = 0; s < 4; ++s) {
    int k0 = s * 32 + k0base;
    bf16x8 Ahi = *(const bf16x8*)&t1hi[lm][k0];
    bf16x8 Alo = *(const bf16x8*)&t1lo[lm][k0];
#pragma unroll
    for (int cf = 0; cf < 2; ++cf) {
      int cc = colb + cf * 16 + lm;
      bf16x8 Bh = *(const bf16x8*)(Wd2Thi + (size_t)cc * 128 + k0);
      bf16x8 Bl = *(const bf16x8*)(Wd2Tlo + (size_t)cc * 128 + k0);
      acc2g[cf] = __builtin_amdgcn_mfma_f32_16x16x32_bf16(Ahi, Bh, acc2g[cf], 0, 0, 0);
      acc2g[cf] = __builtin_amdgcn_mfma_f32_16x16x32_bf16(Ahi, Bl, acc2g[cf], 0, 0, 0);
      acc2g[cf] = __builtin_amdgcn_mfma_f32_16x16x32_bf16(Alo, Bh, acc2g[cf], 0, 0, 0);
    }
  }
#pragma unroll
  for (int cf = 0; cf < 2; ++cf) {
    int cc = colb + cf * 16 + lm;
    float bias2 = bd2[cc];
#pragma unroll
    for (int j = 0; j < 4; ++j) {
      int r = nb + lk * 4 + j;
      float val = hin[(size_t)r * HID + cc] + acc2g[cf][j] + bias2;
      hout[(size_t)r * HID + cc] = val;
      float o = __shfl_xor(val, 1);
      if ((lm & 1) == 0) hbfo[(size_t)r * 64 + (cc >> 1)] = pack_bf2(val, o);
    }
  }
}

// ================= global MLP ==============================================
__global__ __launch_bounds__(128) void k_global(const float* __restrict__ u,
    const float* __restrict__ Wg1, const float* __restrict__ bg1,
    const float* __restrict__ gg1, const float* __restrict__ btg1,
    const float* __restrict__ Wg2, const float* __restrict__ bg2,
    float* __restrict__ u_p) {
  __shared__ float t_s[NGR][HID];
  int c = threadIdx.x;
  for (int g = 0; g < NGR; ++g) {
    float v = bg1[c];
#pragma unroll
    for (int k = 0; k < GD; ++k) v = fmaf(u[(size_t)g * GD + k], Wg1[k * HID + c], v);
    t_s[g][c] = v;
  }
  float sum = 0.f, sq = 0.f;
  for (int g = 0; g < NGR; ++g) { float v = t_s[g][c]; sum += v; sq += v * v; }
  float mean = sum * (1.f / NGR);
  float var = sq * (1.f / NGR) - mean * mean;
  float a = gg1[c] * rsqrtf(var + EPSF);
  float b = btg1[c] - mean * a;
  for (int g = 0; g < NGR; ++g) t_s[g][c] = fmaxf(fmaf(t_s[g][c], a, b), 0.f);
  __syncthreads();
  for (int g = 0; g < NGR; ++g) {
    float acc = bg2[c];
#pragma unroll 8
    for (int k = 0; k < HID; ++k) acc = fmaf(t_s[g][k], Wg2[k * HID + c], acc);
    u_p[(size_t)g * HID + c] = acc;
  }
}

// ================= shift head ==============================================
__global__ __launch_bounds__(256) void k_shift1(
    const float* __restrict__ h, const float* __restrict__ u_p,
    const int* __restrict__ batch, const float* __restrict__ Ws1,
    const float* __restrict__ bs1, float* __restrict__ t1, float* __restrict__ stats) {
  __shared__ float s_in[16][2 * HID];
  const int c = threadIdx.x & 63;
  const int ng = threadIdx.x >> 6;
  float psum = 0.f, psq = 0.f;
  for (int tile = blockIdx.x; tile < NN / 16; tile += gridDim.x) {
    const int nb = tile * 16;
    for (int i = threadIdx.x; i < 16 * HID; i += 256) {
      int ln = i >> 7, k = i & 127;
      s_in[ln][k] = h[(size_t)(nb + ln) * HID + k];
      s_in[ln][HID + k] = u_p[(size_t)batch[nb + ln] * HID + k];
    }
    __syncthreads();
    float acc[4];
#pragma unroll
    for (int j = 0; j < 4; ++j) acc[j] = bs1[c];
    for (int k = 0; k < 2 * HID; ++k) {
      float w = Ws1[k * SH + c];
#pragma unroll
      for (int j = 0; j < 4; ++j) acc[j] = fmaf(s_in[ng * 4 + j][k], w, acc[j]);
    }
#pragma unroll
    for (int j = 0; j < 4; ++j) {
      t1[(size_t)(nb + ng * 4 + j) * SH + c] = acc[j];
      psum += acc[j]; psq += acc[j] * acc[j];
    }
    __syncthreads();
  }
  __shared__ float rs[256], rq[256];
  rs[threadIdx.x] = psum; rq[threadIdx.x] = psq;
  __syncthreads();
  if (threadIdx.x < 64) {
    int c2 = threadIdx.x;
    atomicAdd(&stats[c2], rs[c2] + rs[c2 + 64] + rs[c2 + 128] + rs[c2 + 192]);
    atomicAdd(&stats[128 + c2], rq[c2] + rq[c2 + 64] + rq[c2 + 128] + rq[c2 + 192]);
  }
}

__global__ __launch_bounds__(256) void k_shift2(
    const float* __restrict__ t1, float* __restrict__ stats,
    const float* __restrict__ Ws2, const float* __restrict__ bs2,
    float* __restrict__ t2) {
  __shared__ float r_s[16][SH];
  const int c = threadIdx.x & 63;
  const int ng = threadIdx.x >> 6;
  float psum = 0.f, psq = 0.f;
  for (int tile = blockIdx.x; tile < NN / 16; tile += gridDim.x) {
    const int nb = tile * 16;
    for (int i = threadIdx.x; i < 16 * SH; i += 256) {
      int ln = i >> 6, k = i & 63;
      float v = fmaf(t1[(size_t)(nb + ln) * SH + k], stats[256 + k], stats[384 + k]);
      r_s[ln][k] = fmaxf(v, 0.f);
    }
    __syncthreads();
    float acc[4];
#pragma unroll
    for (int j = 0; j < 4; ++j) acc[j] = bs2[c];
    for (int k = 0; k < SH; ++k) {
      float w = Ws2[k * SH + c];
#pragma unroll
      for (int j = 0; j < 4; ++j) acc[j] = fmaf(r_s[ng * 4 + j][k], w, acc[j]);
    }
#pragma unroll
    for (int j = 0; j < 4; ++j) {
      t2[(size_t)(nb + ng * 4 + j) * SH + c] = acc[j];
      psum += acc[j]; psq += acc[j] * acc[j];
    }
    __syncthreads();
  }
  __shared__ float rs[256], rq[256];
  rs[threadIdx.x] = psum; rq[threadIdx.x] = psq;
  __syncthreads();
  if (threadIdx.x < 64) {
    int c2 = threadIdx.x;
    atomicAdd(&stats[c2], rs[c2] + rs[c2 + 64] + rs[c2 + 128] + rs[c2 + 192]);
    atomicAdd(&stats[128 + c2], rq[c2] + rq[c2 + 64] + rq[c2 + 128] + rq[c2 + 192]);
  }
}

__global__ __launch_bounds__(256) void k_shift3(
    const float* __restrict__ t2, const float* __restrict__ stats,
    const float* __restrict__ Ws3, const float* __restrict__ bs3,
    float* __restrict__ shifts) {
  int lane = threadIdx.x & 63;
  int n = blockIdx.x * 4 + (threadIdx.x >> 6);
  if (n >= NN) return;
  float a = stats[256 + lane], b = stats[384 + lane];
  float r = fmaxf(fmaf(t2[(size_t)n * SH + lane], a, b), 0.f);
  float v = r * Ws3[lane];
#pragma unroll
  for (int off = 32; off; off >>= 1) v += __shfl_down(v, off);
  if (lane == 0) shifts[n] = v + bs3[0];
}

extern "C" void kernel_launch(void* const* d_in, const int* in_sizes, int n_in,
                              void* d_out, int out_size, void* d_ws, size_t ws_size,
                              hipStream_t stream) {
  const float* x     = (const float*)d_in[0];
  const int*   ei    = (const int*)d_in[1];
  const float* eattr = (const float*)d_in[2];
  const int*   batch = (const int*)d_in[3];
  const float* u     = (const float*)d_in[4];
  const float* We1 = (const float*)d_in[5];  const float* be1 = (const float*)d_in[6];
  const float* ge1 = (const float*)d_in[7];  const float* bte1 = (const float*)d_in[8];
  const float* We2 = (const float*)d_in[9];  const float* be2 = (const float*)d_in[10];
  const float* Wf1 = (const float*)d_in[11]; const float* bf1 = (const float*)d_in[12];
  const float* Wf2 = (const float*)d_in[13]; const float* bf2 = (const float*)d_in[14];
  const float* Wd1 = (const float*)d_in[15]; const float* bd1 = (const float*)d_in[16];
  const float* Wd2 = (const float*)d_in[17]; const float* bd2 = (const float*)d_in[18];
  const float* Wg1 = (const float*)d_in[19]; const float* bg1 = (const float*)d_in[20];
  const float* gg1 = (const float*)d_in[21]; const float* btg1 = (const float*)d_in[22];
  const float* Wg2 = (const float*)d_in[23]; const float* bg2 = (const float*)d_in[24];
  const float* Ws1 = (const float*)d_in[25]; const float* bs1 = (const float*)d_in[26];
  const float* gs1 = (const float*)d_in[27]; const float* bts1 = (const float*)d_in[28];
  const float* Ws2 = (const float*)d_in[29]; const float* bs2 = (const float*)d_in[30];
  const float* gs2 = (const float*)d_in[31]; const float* bts2 = (const float*)d_in[32];
  const float* Ws3 = (const float*)d_in[33]; const float* bs3 = (const float*)d_in[34];

  float* out    = (float*)d_out;
  float* shifts = out;                    // [NN]
  float* h      = out + NN;               // [NN,HID]
  float* ea     = out + NN + NN * HID;    // [NE,NG]
  float* u_p    = out + NN + NN * HID + (size_t)NE * NG;  // [NGR,HID]

  // workspace layout
  char* wsb = (char*)d_ws;
  size_t off = 0;
  auto alloc = [&](size_t bytes) { void* p = wsb + off; off = (off + bytes + 255) & ~(size_t)255; return p; };
  float*  stats    = (float*)alloc(512 * sizeof(float));
  int*    hist     = (int*)alloc((size_t)NN * sizeof(int));
  int*    rowptr   = (int*)alloc((size_t)(NN + 1) * sizeof(int));
  uint2*  metap    = (uint2*)alloc((size_t)NE * sizeof(uint2));
  unsigned int* tabp = (unsigned int*)alloc((size_t)NL * TBL * HID * sizeof(unsigned int));
  bf16_t* Wd1Thi   = (bf16_t*)alloc((size_t)NL * 128 * 128 * sizeof(bf16_t));
  bf16_t* Wd1Tlo   = (bf16_t*)alloc((size_t)NL * 128 * 128 * sizeof(bf16_t));
  bf16_t* Wd2Thi   = (bf16_t*)alloc((size_t)NL * 128 * 128 * sizeof(bf16_t));
  bf16_t* Wd2Tlo   = (bf16_t*)alloc((size_t)NL * 128 * 128 * sizeof(bf16_t));
  float*  hwork    = (float*)alloc((size_t)NN * HID * sizeof(float));
  unsigned int* hbfA = (unsigned int*)alloc((size_t)NN * 64 * sizeof(unsigned int));
  unsigned int* hbfB = (unsigned int*)alloc((size_t)NN * 64 * sizeof(unsigned int));
  float*  buf1     = (float*)alloc((size_t)NN * HID * sizeof(float));
  float* t1 = buf1;
  float* t2 = buf1 + (size_t)NN * SH;

  const int* row = ei;        // source j
  const int* col = ei + NE;   // target i

  // ---- CSR build + packed edge meta + table + node-weight prep
  hipMemsetAsync(hist, 0, (size_t)NN * sizeof(int), stream);
  k_hist<<<512, 256, 0, stream>>>(col, hist);
  k_scan<<<1, 1024, 0, stream>>>(hist, rowptr);
  k_scatter2<<<512, 256, 0, stream>>>(col, row, eattr, hist, metap);
  k_tabbuild3<<<NL * (TBL / 8), 128, 0, stream>>>(Wf1, bf1, Wf2, bf2, tabp);
  k_prepw<<<(2 * NL * 128 * 128 + 255) / 256, 256, 0, stream>>>(
      Wd1, Wd2, Wd1Thi, Wd1Tlo, Wd2Thi, Wd2Tlo);

  // ---- node encoder
  hipMemsetAsync(stats, 0, 256 * sizeof(float), stream);
  k_enc1<<<512, 256, 0, stream>>>(x, We1, be1, buf1, stats);
  k_bn_fin<<<1, 128, 0, stream>>>(ge1, bte1, stats, 128, 1.f / NN);
  k_enc2<<<2048, 128, 0, stream>>>(buf1, stats, We2, be2, h, hbfA);

  // ---- gaussian smearing (ea output)
  k_smear<<<(NE * NG + 255) / 256, 256, 0, stream>>>(eattr, ea);

  // ---- interaction layers (fused edge+node, ping-pong h and hbf)
  for (int l = 0; l < NL; ++l) {
    const float* hi = (l & 1) ? hwork : h;
    float*       ho = (l & 1) ? h : hwork;
    const unsigned int* bi = (l & 1) ? hbfB : hbfA;
    unsigned int*       bo = (l & 1) ? hbfA : hbfB;
    k_layer<<<NN / 16, 256, 0, stream>>>(
        metap, rowptr, hi, bi, tabp + (size_t)l * TBL * HID,
        Wd1Thi + (size_t)l * 128 * 128, Wd1Tlo + (size_t)l * 128 * 128,
        Wd2Thi + (size_t)l * 128 * 128, Wd2Tlo + (size_t)l * 128 * 128,
        bd1 + (size_t)l * HID, bd2 + (size_t)l * HID, ho, bo);
  }
  // NL=6 (even) -> final h lands back in the output slot `h`

  // ---- global MLP
  k_global<<<1, 128, 0, stream>>>(u, Wg1, bg1, gg1, btg1, Wg2, bg2, u_p);

  // ---- shift head
  hipMemsetAsync(stats, 0, 256 * sizeof(float), stream);
  k_shift1<<<1024, 256, 0, stream>>>(h, u_p, batch, Ws1, bs1, t1, stats);
  k_bn_fin<<<1, 128, 0, stream>>>(gs1, bts1, stats, 64, 1.f / NN);
  hipMemsetAsync(stats, 0, 256 * sizeof(float), stream);
  k_shift2<<<1024, 256, 0, stream>>>(t1, stats, Ws2, bs2, t2);
  k_bn_fin<<<1, 128, 0, stream>>>(gs2, bts2, stats, 64, 1.f / NN);
  k_shift3<<<(NN + 3) / 4, 256, 0, stream>>>(t2, stats, Ws3, bs3, shifts);
}